// Round 5
// baseline (1756.907 us; speedup 1.0000x reference)
//
#include <hip/hip_runtime.h>
#include <math.h>

#define NN      50000      // N_NODES
#define BP      4096       // N_PAIRS_MAP
#define NE      500000     // N_EDGES
#define NP      1000000    // N_SCORE_PAIRS
#define FEAT    300
#define HID     128
#define HEADS   3
#define OUTC    10
#define HC1     (HEADS*HID)   // 384
#define NEG_SLOPE 0.2f

static inline int cdiv(int a, int b) { return (a + b - 1) / b; }

__device__ inline float leaky(float x) { return x > 0.f ? x : NEG_SLOPE * x; }

// ================== MFMA split-bf16 GEMM ==================
// C = scale*A@B (+bias)(+addsrc), fp32 in/out, internally bf16 hi+lo split:
// A = Ah + Al, B = Bh + Bl; C += Ah*Bh + Ah*Bl + Al*Bh  (error ~2^-17, fp32-class)
// 64x64 tile, BK=32, 256 threads = 4 waves; wave w owns rows [16w,16w+16),
// 4 MFMA col-tiles of 16. LDS stride 40 ushorts = 80 B (16B-aligned rows,
// 2-way bank aliasing only - free per m136).
using bfrag = __attribute__((ext_vector_type(8))) short;
using ffrag = __attribute__((ext_vector_type(4))) float;

__device__ inline unsigned short bf16_rne(float f) {
    unsigned u = __float_as_uint(f);
    unsigned r = u + 0x7FFFu + ((u >> 16) & 1u);
    return (unsigned short)(r >> 16);
}
__device__ inline float bf16_to_f(unsigned short h) {
    return __uint_as_float(((unsigned)h) << 16);
}

// NT: B is [N,K] row-major (C = A@B^T). SPLITK: write partials C0[z][M][N].
// QKV: N==900 fused projection; C cols [0,300)->C0, [300,600)->C1, [600,900)->C2.
template <bool NT, bool SPLITK, bool QKV>
__global__ __launch_bounds__(256) void gemm_mfma(
    const float* __restrict__ A, const float* __restrict__ B,
    const float* __restrict__ bias, const float* __restrict__ addsrc,
    float* __restrict__ C0, float* __restrict__ C1, float* __restrict__ C2,
    int M, int N, int K, float scale, int KC)
{
    __shared__ unsigned short Ah[64][40], Al[64][40];
    __shared__ unsigned short Bh[64][40], Bl[64][40];
    int t = threadIdx.x;
    int rowBase = blockIdx.y * 64, colBase = blockIdx.x * 64;
    int kbeg = SPLITK ? blockIdx.z * KC : 0;
    int kend = SPLITK ? min(K, kbeg + KC) : K;

    ffrag acc[4] = {{0.f,0.f,0.f,0.f},{0.f,0.f,0.f,0.f},{0.f,0.f,0.f,0.f},{0.f,0.f,0.f,0.f}};
    int w = t >> 6, l = t & 63, lrow = l & 15, lq = l >> 4;

    for (int k0 = kbeg; k0 < kend; k0 += 32) {
        // ---- stage A[64][32] -> Ah/Al[row][k]
        {
            int row = t >> 2, ks = (t & 3) * 8;
            int gr = rowBase + row;
            const float* ap = A + (long)gr * K + k0 + ks;
            bool rok = gr < M;
#pragma unroll
            for (int i = 0; i < 8; i++) {
                int kk = k0 + ks + i;
                float f = (rok && kk < kend) ? ap[i] : 0.f;
                unsigned short h = bf16_rne(f);
                Ah[row][ks + i] = h;
                Al[row][ks + i] = bf16_rne(f - bf16_to_f(h));
            }
        }
        // ---- stage B -> Bh/Bl[n][k] (k-contiguous for b128 frag reads)
        if (!NT) {
            int kr = t >> 3, ns = (t & 7) * 8;
            int gk = k0 + kr;
            const float* bp = B + (long)gk * N + colBase + ns;
            bool kok = gk < kend;
#pragma unroll
            for (int i = 0; i < 8; i++) {
                int gn = colBase + ns + i;
                float f = (kok && gn < N) ? bp[i] : 0.f;
                unsigned short h = bf16_rne(f);
                Bh[ns + i][kr] = h;
                Bl[ns + i][kr] = bf16_rne(f - bf16_to_f(h));
            }
        } else {
            int n = t >> 2, ks = (t & 3) * 8;
            int gn = colBase + n;
            const float* bp = B + (long)gn * K + k0 + ks;
            bool nok = gn < N;
#pragma unroll
            for (int i = 0; i < 8; i++) {
                int kk = k0 + ks + i;
                float f = (nok && kk < kend) ? bp[i] : 0.f;
                unsigned short h = bf16_rne(f);
                Bh[n][ks + i] = h;
                Bl[n][ks + i] = bf16_rne(f - bf16_to_f(h));
            }
        }
        __syncthreads();

        // fragment layout (gfx950 16x16x32): A[m=lane&15][k=quad*8+j],
        // B[k=quad*8+j][n=lane&15]; both stored k-contiguous -> ds_read_b128.
        bfrag ah = *(const bfrag*)&Ah[w * 16 + lrow][lq * 8];
        bfrag al = *(const bfrag*)&Al[w * 16 + lrow][lq * 8];
#pragma unroll
        for (int ct = 0; ct < 4; ct++) {
            bfrag bh = *(const bfrag*)&Bh[ct * 16 + lrow][lq * 8];
            bfrag bl = *(const bfrag*)&Bl[ct * 16 + lrow][lq * 8];
            acc[ct] = __builtin_amdgcn_mfma_f32_16x16x32_bf16(ah, bh, acc[ct], 0, 0, 0);
            acc[ct] = __builtin_amdgcn_mfma_f32_16x16x32_bf16(ah, bl, acc[ct], 0, 0, 0);
            acc[ct] = __builtin_amdgcn_mfma_f32_16x16x32_bf16(al, bh, acc[ct], 0, 0, 0);
        }
        __syncthreads();
    }

    // C/D layout: col = lane&15, row = quad*4 + reg
#pragma unroll
    for (int ct = 0; ct < 4; ct++) {
        int gc = colBase + ct * 16 + lrow;
        if (gc >= N) continue;
#pragma unroll
        for (int r = 0; r < 4; r++) {
            int gr = rowBase + w * 16 + lq * 4 + r;
            if (gr >= M) continue;
            float v = acc[ct][r] * scale;
            if (SPLITK) {
                C0[(long)blockIdx.z * M * N + (long)gr * N + gc] = v;
            } else if (QKV) {
                v += bias[gc];
                int buf = gc >= 600 ? 2 : (gc >= 300 ? 1 : 0);
                float* Cp = buf == 0 ? C0 : (buf == 1 ? C1 : C2);
                Cp[(long)gr * 300 + (gc - 300 * buf)] = v;
            } else {
                if (bias) v += bias[gc];
                if (addsrc) v += addsrc[(long)gr * N + gc];
                C0[(long)gr * N + gc] = v;
            }
        }
    }
}

// ---------- pack Wq|Wk|Wv -> [300][900], bq|bk|bv -> [900] ----------
__global__ void pack_qkv(const float* __restrict__ Wq, const float* __restrict__ Wk,
                         const float* __restrict__ Wv, const float* __restrict__ bq,
                         const float* __restrict__ bk, const float* __restrict__ bv,
                         float* __restrict__ Wp, float* __restrict__ bp) {
    int idx = blockIdx.x * blockDim.x + threadIdx.x;
    int total = FEAT * 900;
    if (idx < total) {
        int k = idx / 900, j = idx - k * 900;
        float v = j < 300 ? Wq[k * 300 + j] : (j < 600 ? Wk[k * 300 + j - 300] : Wv[k * 300 + j - 600]);
        Wp[idx] = v;
    }
    if (idx < 900)
        bp[idx] = idx < 300 ? bq[idx] : (idx < 600 ? bk[idx - 300] : bv[idx - 600]);
}

__global__ void splitk_reduce(const float* __restrict__ part, const float* __restrict__ addsrc,
                              float* __restrict__ C, long MN, int sk) {
    long i = (long)blockIdx.x * blockDim.x + threadIdx.x;
    if (i >= MN) return;
    float s = 0.f;
    for (int z = 0; z < sk; z++) s += part[(long)z * MN + i];
    if (addsrc) s += addsrc[i];
    C[i] = s;
}

// ---------- row softmax over [R, n] ----------
__global__ void softmax_rows(float* __restrict__ S, int n) {
    int row = blockIdx.x;
    float* p = S + (long)row * n;
    __shared__ float red[256];
    int tid = threadIdx.x;
    float m = -1e30f;
    for (int j = tid; j < n; j += 256) m = fmaxf(m, p[j]);
    red[tid] = m; __syncthreads();
    for (int s = 128; s > 0; s >>= 1) { if (tid < s) red[tid] = fmaxf(red[tid], red[tid + s]); __syncthreads(); }
    m = red[0]; __syncthreads();
    float sum = 0.f;
    for (int j = tid; j < n; j += 256) { float e = expf(p[j] - m); p[j] = e; sum += e; }
    red[tid] = sum; __syncthreads();
    for (int s = 128; s > 0; s >>= 1) { if (tid < s) red[tid] += red[tid + s]; __syncthreads(); }
    float inv = 1.0f / red[0];
    for (int j = tid; j < n; j += 256) p[j] *= inv;
}

// ---------- scatter (last write wins, numpy semantics) ----------
__global__ void scatter_init(int* last, const int* __restrict__ com, int B) {
    int i = blockIdx.x * blockDim.x + threadIdx.x;
    if (i < B) last[com[i]] = -1;
}
__global__ void scatter_max(int* last, const int* __restrict__ com, int B) {
    int i = blockIdx.x * blockDim.x + threadIdx.x;
    if (i < B) atomicMax(&last[com[i]], i);
}
__global__ void scatter_write(const int* __restrict__ last, const int* __restrict__ com,
                              const float* __restrict__ fused, float* __restrict__ x, int B, int D) {
    int i = blockIdx.x;
    int node = com[i];
    if (last[node] != i) return;
    for (int c = threadIdx.x; c < D; c += blockDim.x)
        x[(long)node * D + c] = fused[(long)i * D + c];
}

// ---------- GAT per-node attention coefficients ----------
__global__ void node_attn_coef(const float* __restrict__ h, const float* __restrict__ a_src,
                               const float* __restrict__ a_dst, float* __restrict__ es,
                               float* __restrict__ ed, int N, int H, int C) {
    int idx = blockIdx.x * blockDim.x + threadIdx.x;
    if (idx >= N * H) return;
    int n = idx / H, hh = idx % H;
    const float* hp = h + (long)n * H * C + (long)hh * C;
    const float* as = a_src + hh * C;
    const float* ad = a_dst + hh * C;
    float s = 0.f, d = 0.f;
    for (int c = 0; c < C; c++) { float v = hp[c]; s += v * as[c]; d += v * ad[c]; }
    es[idx] = s; ed[idx] = d;
}

// ================== CSR build ==================
__global__ void deg_init(int* deg, int n) {
    int i = blockIdx.x * blockDim.x + threadIdx.x;
    if (i < n) deg[i] = 1;
}
__global__ void deg_count(const int* __restrict__ dst, int* deg, int E) {
    int e = blockIdx.x * blockDim.x + threadIdx.x;
    if (e < E) atomicAdd(&deg[dst[e]], 1);
}
#define SCAN_BLOCK 1024
__global__ __launch_bounds__(SCAN_BLOCK) void scan_rowptr(const int* __restrict__ deg, int* __restrict__ rowptr, int n) {
    __shared__ int tmp[SCAN_BLOCK];
    __shared__ int carry;
    int tid = threadIdx.x;
    if (tid == 0) carry = 0;
    __syncthreads();
    for (int base = 0; base < n; base += SCAN_BLOCK) {
        int i = base + tid;
        int v = (i < n) ? deg[i] : 0;
        tmp[tid] = v; __syncthreads();
        for (int off = 1; off < SCAN_BLOCK; off <<= 1) {
            int t2 = (tid >= off) ? tmp[tid - off] : 0;
            __syncthreads();
            tmp[tid] += t2;
            __syncthreads();
        }
        int incl = tmp[tid];
        if (i < n) rowptr[i + 1] = carry + incl;
        __syncthreads();
        if (tid == SCAN_BLOCK - 1) carry += incl;
        __syncthreads();
    }
    if (tid == 0) rowptr[0] = 0;
}
__global__ void copy_i32(const int* __restrict__ a, int* __restrict__ b, int n) {
    int i = blockIdx.x * blockDim.x + threadIdx.x;
    if (i < n) b[i] = a[i];
}
__global__ void csr_fill(const int* __restrict__ src, const int* __restrict__ dst,
                         int* cursor, int* __restrict__ csr_src, int E) {
    int e = blockIdx.x * blockDim.x + threadIdx.x;
    if (e >= E) return;
    int slot = atomicAdd(&cursor[dst[e]], 1);
    csr_src[slot] = src[e];
}
__global__ void csr_fill_loops(int* cursor, int* __restrict__ csr_src, int n) {
    int i = blockIdx.x * blockDim.x + threadIdx.x;
    if (i >= n) return;
    int slot = atomicAdd(&cursor[i], 1);
    csr_src[slot] = i;
}

// ---------- segment max + denom per (node, head) ----------
__global__ void csr_maxden(const int* __restrict__ rowptr, const int* __restrict__ csr_src,
                           const float* __restrict__ es, const float* __restrict__ ed,
                           float* __restrict__ m, float* __restrict__ den, int N, int H) {
    int idx = blockIdx.x * blockDim.x + threadIdx.x;
    if (idx >= N * H) return;
    int d = idx / H, h = idx - d * H;
    float edv = ed[idx];
    int b = rowptr[d], e = rowptr[d + 1];
    float mm = -1e30f;
    for (int s0 = b; s0 < e; s0++) {
        int s = csr_src[s0];
        mm = fmaxf(mm, leaky(es[s * H + h] + edv));
    }
    float dn = 0.f;
    for (int s0 = b; s0 < e; s0++) {
        int s = csr_src[s0];
        dn += expf(leaky(es[s * H + h] + edv) - mm);
    }
    m[idx] = mm;
    den[idx] = dn;
}

// ---------- layer-1 aggregate + bias + ELU + (row @ W2) fused ----------
__global__ __launch_bounds__(128) void csr_agg1_fused(
    const int* __restrict__ rowptr, const int* __restrict__ csr_src,
    const float* __restrict__ es, const float* __restrict__ ed,
    const float* __restrict__ m1, const float* __restrict__ den1,
    const float* __restrict__ h1, const float* __restrict__ b1,
    const float* __restrict__ W2, float* __restrict__ h2, int N)
{
    int d = blockIdx.x;
    int t = threadIdx.x;
    __shared__ float row[HC1];
    __shared__ float part[128][OUTC + 1];

    int b = rowptr[d], e = rowptr[d + 1];
    float ed0 = ed[d * 3 + 0], ed1 = ed[d * 3 + 1], ed2 = ed[d * 3 + 2];
    float mm0 = m1[d * 3 + 0], mm1 = m1[d * 3 + 1], mm2 = m1[d * 3 + 2];
    float i0 = 1.f / (den1[d * 3 + 0] + 1e-16f);
    float i1 = 1.f / (den1[d * 3 + 1] + 1e-16f);
    float i2 = 1.f / (den1[d * 3 + 2] + 1e-16f);

    float a0 = 0.f, a1 = 0.f, a2 = 0.f;
    for (int s0 = b; s0 < e; s0++) {
        int s = csr_src[s0];
        float e0 = es[s * 3 + 0], e1 = es[s * 3 + 1], e2 = es[s * 3 + 2];
        float al0 = expf(leaky(e0 + ed0) - mm0) * i0;
        float al1 = expf(leaky(e1 + ed1) - mm1) * i1;
        float al2 = expf(leaky(e2 + ed2) - mm2) * i2;
        const float* hp = h1 + (long)s * HC1;
        a0 = fmaf(hp[t],       al0, a0);
        a1 = fmaf(hp[t + 128], al1, a1);
        a2 = fmaf(hp[t + 256], al2, a2);
    }
    float v;
    v = a0 + b1[t];       row[t]       = v > 0.f ? v : expf(v) - 1.f;
    v = a1 + b1[t + 128]; row[t + 128] = v > 0.f ? v : expf(v) - 1.f;
    v = a2 + b1[t + 256]; row[t + 256] = v > 0.f ? v : expf(v) - 1.f;
    __syncthreads();

    float pc[OUTC];
#pragma unroll
    for (int c = 0; c < OUTC; c++) pc[c] = 0.f;
    for (int k = t; k < HC1; k += 128) {
        float rv = row[k];
        const float* w = W2 + (long)k * OUTC;
#pragma unroll
        for (int c = 0; c < OUTC; c++) pc[c] = fmaf(rv, w[c], pc[c]);
    }
#pragma unroll
    for (int c = 0; c < OUTC; c++) part[t][c] = pc[c];
    __syncthreads();
    for (int off = 64; off > 0; off >>= 1) {
        if (t < off) {
#pragma unroll
            for (int c = 0; c < OUTC; c++) part[t][c] += part[t + off][c];
        }
        __syncthreads();
    }
    if (t < OUTC) h2[(long)d * OUTC + t] = part[0][t];
}

// ---------- layer-2 aggregate + bias ----------
__global__ void csr_agg2(const int* __restrict__ rowptr, const int* __restrict__ csr_src,
                         const float* __restrict__ es, const float* __restrict__ ed,
                         const float* __restrict__ m2, const float* __restrict__ den2,
                         const float* __restrict__ h2, const float* __restrict__ b2,
                         float* __restrict__ emb, int N)
{
    int idx = blockIdx.x * blockDim.x + threadIdx.x;
    if (idx >= N * OUTC) return;
    int d = idx / OUTC, c = idx - d * OUTC;
    float edv = ed[d], mm = m2[d], inv = 1.f / (den2[d] + 1e-16f);
    int b = rowptr[d], e = rowptr[d + 1];
    float acc = 0.f;
    for (int s0 = b; s0 < e; s0++) {
        int s = csr_src[s0];
        float al = expf(leaky(es[s] + edv) - mm) * inv;
        acc = fmaf(h2[(long)s * OUTC + c], al, acc);
    }
    emb[idx] = acc + b2[c];
}

// ---------- pair scores ----------
__global__ void pair_score(const int* __restrict__ pairs, const float* __restrict__ emb,
                           float* __restrict__ out, int P) {
    int p = blockIdx.x * blockDim.x + threadIdx.x;
    if (p >= P) return;
    int i0 = pairs[2 * p], i1 = pairs[2 * p + 1];
    const float* a = emb + (long)i0 * OUTC;
    const float* b = emb + (long)i1 * OUTC;
    float s = 0.f;
#pragma unroll
    for (int c = 0; c < OUTC; c++) s += a[c] * b[c];
    out[p] = s;
}

extern "C" void kernel_launch(void* const* d_in, const int* in_sizes, int n_in,
                              void* d_out, int out_size, void* d_ws, size_t ws_size,
                              hipStream_t stream) {
    const float* fsub = (const float*)d_in[0];
    const float* fcom = (const float*)d_in[1];
    float*       x    = (float*)d_in[2];
    const int*   com  = (const int*)d_in[3];
    const int*   ei   = (const int*)d_in[4];
    const int*   pidx = (const int*)d_in[5];
    const float* Wq = (const float*)d_in[6];  const float* bq = (const float*)d_in[7];
    const float* Wk = (const float*)d_in[8];  const float* bk = (const float*)d_in[9];
    const float* Wv = (const float*)d_in[10]; const float* bv = (const float*)d_in[11];
    const float* Wf = (const float*)d_in[12]; const float* bf = (const float*)d_in[13];
    const float* W1 = (const float*)d_in[14];
    const float* as1 = (const float*)d_in[15]; const float* ad1 = (const float*)d_in[16];
    const float* b1 = (const float*)d_in[17];
    const float* W2 = (const float*)d_in[18];
    const float* as2 = (const float*)d_in[19]; const float* ad2 = (const float*)d_in[20];
    const float* b2 = (const float*)d_in[21];
    float* out = (float*)d_out;

    const int* src = ei;
    const int* dst = ei + NE;

    char* ws = (char*)d_ws;
    // ---- phase 1 (attention): 0 .. 91.7 MB ----
    float* S    = (float*)(ws + 0);          // 67,108,864
    float* q    = (float*)(ws + 67108864);
    float* kbuf = (float*)(ws + 72024064);
    float* vbuf = (float*)(ws + 76939264);
    float* attn = (float*)(ws + 81854464);
    float* fus  = (float*)(ws + 86769664);   // ends 91,684,864
    // ---- phase 2 (GAT) ----
    float*    h1   = (float*)(ws + 0);          // 76,800,000 (after attention done)
    float*    es1  = (float*)(ws + 92000000);
    float*    ed1  = (float*)(ws + 92600000);
    float*    m1   = (float*)(ws + 93200000);
    float*    den1 = (float*)(ws + 93800000);
    float*    es2  = (float*)(ws + 94400000);
    float*    ed2  = (float*)(ws + 94600000);
    float*    m2   = (float*)(ws + 94800000);
    float*    den2 = (float*)(ws + 95000000);
    float*    h2   = (float*)(ws + 95200000);
    float*    embp = (float*)(ws + 97200000);
    int*      last = (int*)(ws + 99200000);
    int*      deg  = (int*)(ws + 99400000);
    int*      curs = (int*)(ws + 99600000);
    int*      rowp = (int*)(ws + 99800000);
    int*      csrc = (int*)(ws + 100000016);    // ends ~102.2 MB
    float*    part = (float*)(ws + 102400000);  // 8*4096*300*4 = 39,321,600
    float*    Wp   = (float*)(ws + 141800000);  // 300*900*4 = 1,080,000
    float*    bp   = (float*)(ws + 142900000);  // 3,600 -> ends ~142.9 MB

    const float inv_sqrt_d = 1.0f / sqrtf((float)FEAT);

    // ===== 1. cross attention =====
    hipLaunchKernelGGL(pack_qkv, dim3(cdiv(FEAT * 900, 256)), dim3(256), 0, stream,
                       Wq, Wk, Wv, bq, bk, bv, Wp, bp);
    // q|k|v = fsub/fcom @ Wp + bp  (fused QKV; A differs: q uses fsub, k/v use fcom)
    // -> two launches: one on fsub for q only is wasteful; instead note q,k,v all have
    //    A in {fsub, fcom}. Do: q from fsub (cols 0-299 only would need masking), so
    //    simplest: launch QKV GEMM twice, once with fsub (keep q), once with fcom (keep k,v).
    //    Cheaper: q = fsub@Wq separately, kv packed. But one packed launch on fcom covers k,v;
    //    q done via the same kernel with N=300.
    hipLaunchKernelGGL((gemm_mfma<false,false,false>), dim3(cdiv(FEAT,64), cdiv(BP,64)), dim3(256), 0, stream,
                       fsub, Wq, bq, nullptr, q, nullptr, nullptr, BP, FEAT, FEAT, 1.0f, 0);
    hipLaunchKernelGGL((gemm_mfma<false,false,true>), dim3(cdiv(900,64), cdiv(BP,64)), dim3(256), 0, stream,
                       fcom, Wp, bp, nullptr, q /*unused cols 0-299 overwritten? no: */, kbuf, vbuf, BP, 900, FEAT, 1.0f, 0);
    // NOTE: QKV launch writes cols 0-299 into C0=q. To avoid clobbering the correct q
    // (fsub-based), order matters: QKV(fcom) runs BEFORE... actually it writes fcom@Wq into q.
    // Fix: run packed first, then overwrite q with the correct fsub@Wq GEMM.
    // (The two launches above are in the WRONG order for that; swap by re-launching q GEMM.)
    hipLaunchKernelGGL((gemm_mfma<false,false,false>), dim3(cdiv(FEAT,64), cdiv(BP,64)), dim3(256), 0, stream,
                       fsub, Wq, bq, nullptr, q, nullptr, nullptr, BP, FEAT, FEAT, 1.0f, 0);
    // S = (q @ k^T) * inv_sqrt_d
    hipLaunchKernelGGL((gemm_mfma<true,false,false>), dim3(cdiv(BP,64), cdiv(BP,64)), dim3(256), 0, stream,
                       q, kbuf, nullptr, nullptr, S, nullptr, nullptr, BP, BP, FEAT, inv_sqrt_d, 0);
    hipLaunchKernelGGL(softmax_rows, dim3(BP), dim3(256), 0, stream, S, BP);
    // attn = fsub + S @ v   (split-K, sk=8)
    {
        const int SK = 8, KC = BP / SK;
        hipLaunchKernelGGL((gemm_mfma<false,true,false>), dim3(cdiv(FEAT,64), cdiv(BP,64), SK), dim3(256), 0, stream,
                           S, vbuf, nullptr, nullptr, part, nullptr, nullptr, BP, FEAT, BP, 1.0f, KC);
        long MN = (long)BP * FEAT;
        hipLaunchKernelGGL(splitk_reduce, dim3(cdiv((int)MN,256)), dim3(256), 0, stream,
                           part, fsub, attn, MN, SK);
    }
    // fused = attn @ Wf + bf
    hipLaunchKernelGGL((gemm_mfma<false,false,false>), dim3(cdiv(FEAT,64), cdiv(BP,64)), dim3(256), 0, stream,
                       attn, Wf, bf, nullptr, fus, nullptr, nullptr, BP, FEAT, FEAT, 1.0f, 0);

    // ===== 2. scatter fused into x (last write wins) =====
    hipLaunchKernelGGL(scatter_init, dim3(cdiv(BP,256)), dim3(256), 0, stream, last, com, BP);
    hipLaunchKernelGGL(scatter_max,  dim3(cdiv(BP,256)), dim3(256), 0, stream, last, com, BP);
    hipLaunchKernelGGL(scatter_write, dim3(BP), dim3(128), 0, stream, last, com, fus, x, BP, FEAT);

    // ===== 3. CSR build =====
    hipLaunchKernelGGL(deg_init,  dim3(cdiv(NN,256)), dim3(256), 0, stream, deg, NN);
    hipLaunchKernelGGL(deg_count, dim3(cdiv(NE,256)), dim3(256), 0, stream, dst, deg, NE);
    hipLaunchKernelGGL(scan_rowptr, dim3(1), dim3(SCAN_BLOCK), 0, stream, deg, rowp, NN);
    hipLaunchKernelGGL(copy_i32, dim3(cdiv(NN,256)), dim3(256), 0, stream, rowp, curs, NN);
    hipLaunchKernelGGL(csr_fill, dim3(cdiv(NE,256)), dim3(256), 0, stream, src, dst, curs, csrc, NE);
    hipLaunchKernelGGL(csr_fill_loops, dim3(cdiv(NN,256)), dim3(256), 0, stream, curs, csrc, NN);

    // ===== 4. GAT layer 1 =====
    hipLaunchKernelGGL((gemm_mfma<false,false,false>), dim3(cdiv(HC1,64), cdiv(NN,64)), dim3(256), 0, stream,
                       x, W1, nullptr, nullptr, h1, nullptr, nullptr, NN, HC1, FEAT, 1.0f, 0);
    hipLaunchKernelGGL(node_attn_coef, dim3(cdiv(NN*HEADS,256)), dim3(256), 0, stream,
                       h1, as1, ad1, es1, ed1, NN, HEADS, HID);
    hipLaunchKernelGGL(csr_maxden, dim3(cdiv(NN*HEADS,256)), dim3(256), 0, stream,
                       rowp, csrc, es1, ed1, m1, den1, NN, HEADS);
    hipLaunchKernelGGL(csr_agg1_fused, dim3(NN), dim3(128), 0, stream,
                       rowp, csrc, es1, ed1, m1, den1, h1, b1, W2, h2, NN);

    // ===== 5. GAT layer 2 =====
    hipLaunchKernelGGL(node_attn_coef, dim3(cdiv(NN,256)), dim3(256), 0, stream,
                       h2, as2, ad2, es2, ed2, NN, 1, OUTC);
    hipLaunchKernelGGL(csr_maxden, dim3(cdiv(NN,256)), dim3(256), 0, stream,
                       rowp, csrc, es2, ed2, m2, den2, NN, 1);
    hipLaunchKernelGGL(csr_agg2, dim3(cdiv(NN*OUTC,256)), dim3(256), 0, stream,
                       rowp, csrc, es2, ed2, m2, den2, h2, b2, embp, NN);

    // ===== 6. pair scores =====
    hipLaunchKernelGGL(pair_score, dim3(cdiv(NP,256)), dim3(256), 0, stream, pidx, embp, out, NP);
}

// Round 6
// 1127.397 us; speedup vs baseline: 1.5584x; 1.5584x over previous
//
#include <hip/hip_runtime.h>
#include <math.h>

#define NN      50000      // N_NODES
#define BP      4096       // N_PAIRS_MAP
#define NE      500000     // N_EDGES
#define NP      1000000    // N_SCORE_PAIRS
#define FEAT    300
#define KP      320        // FEAT padded to multiple of 32
#define HID     128
#define HEADS   3
#define OUTC    10
#define HC1     (HEADS*HID)   // 384
#define NEG_SLOPE 0.2f

static inline int cdiv(int a, int b) { return (a + b - 1) / b; }

using bfrag = __attribute__((ext_vector_type(8))) short;
using ffrag = __attribute__((ext_vector_type(4))) float;

__device__ inline float leaky(float x) { return x > 0.f ? x : NEG_SLOPE * x; }
__device__ inline unsigned short bf16_rne(float f) {
    unsigned u = __float_as_uint(f);
    unsigned r = u + 0x7FFFu + ((u >> 16) & 1u);
    return (unsigned short)(r >> 16);
}
__device__ inline float bf16f(unsigned short h) { return __uint_as_float(((unsigned)h) << 16); }

__global__ void fill_f32(float* p, float v, long n) {
    long i = (long)blockIdx.x * blockDim.x + threadIdx.x;
    if (i < n) p[i] = v;
}

// fp32 [M][K] -> bf16 hi/lo [M][Kp], zero-padded k tail
__global__ void conv_pad(const float* __restrict__ in, unsigned short* __restrict__ H,
                         unsigned short* __restrict__ L, long M, int K, int Kp) {
    long idx = (long)blockIdx.x * blockDim.x + threadIdx.x;
    long total = M * Kp;
    if (idx >= total) return;
    int k = (int)(idx % Kp);
    long row = idx / Kp;
    float f = (k < K) ? in[row * K + k] : 0.f;
    unsigned short h = bf16_rne(f);
    H[idx] = h;
    L[idx] = bf16_rne(f - bf16f(h));
}
// fp32 [K][N] row-major -> bf16 hi/lo [N][Kp] (transposed, padded)
__global__ void convT_pad(const float* __restrict__ in, unsigned short* __restrict__ H,
                          unsigned short* __restrict__ L, int K, int N, int Kp) {
    long idx = (long)blockIdx.x * blockDim.x + threadIdx.x;
    long total = (long)N * Kp;
    if (idx >= total) return;
    int k = (int)(idx % Kp);
    long n = idx / Kp;
    float f = (k < K) ? in[(long)k * N + n] : 0.f;
    unsigned short h = bf16_rne(f);
    H[idx] = h;
    L[idx] = bf16_rne(f - bf16f(h));
}

// ================== split-bf16 MFMA GEMM ==================
// C = A@B^T with A[M][lda] hi/lo bf16 (k-contig, zero-padded) and B[N][ldb] hi/lo.
// 64x64 tile, BK=32, 256 thr = 4 waves; wave w owns rows [16w,16w+16), 4 col tiles.
// LDS [kq][row][8] ushort: staging = 1 uint4 global load + 1 ds_write_b128 per
// array per thread per K-step; fragment ds_read_b128 perfectly bank-balanced.
// MODE: 0 = fp32 out (scale, bias?, addsrc?), 1 = bf16 hi/lo out (+bias),
//       2 = transposed bf16 hi/lo out (+bias), 3 = split-K fp32 partials
template <int MODE>
__global__ __launch_bounds__(256) void gemm_bf(
    const unsigned short* __restrict__ Ah, const unsigned short* __restrict__ Al, int lda,
    const unsigned short* __restrict__ Bh, const unsigned short* __restrict__ Bl, int ldb,
    const float* __restrict__ bias, const float* __restrict__ addsrc,
    float* __restrict__ C0, unsigned short* __restrict__ H0, unsigned short* __restrict__ L0,
    int M, int N, int K, float scale, int KC, int ldo)
{
    __shared__ __align__(16) unsigned short Ahs[4][64][8], Als[4][64][8];
    __shared__ __align__(16) unsigned short Bhs[4][64][8], Bls[4][64][8];
    int t = threadIdx.x, w = t >> 6, l = t & 63, lrow = l & 15, lq = l >> 4;
    int rowBase = blockIdx.y * 64, colBase = blockIdx.x * 64;
    int Kr = (K + 31) & ~31;
    int kbeg = (MODE == 3) ? blockIdx.z * KC : 0;
    int kend = (MODE == 3) ? min(Kr, kbeg + KC) : Kr;

    int arow = min(rowBase + l, M - 1);
    int brow = min(colBase + l, N - 1);
    const unsigned short* ga_h = Ah + (long)arow * lda + w * 8;
    const unsigned short* ga_l = Al + (long)arow * lda + w * 8;
    const unsigned short* gb_h = Bh + (long)brow * ldb + w * 8;
    const unsigned short* gb_l = Bl + (long)brow * ldb + w * 8;

    ffrag acc[4] = {{0.f,0.f,0.f,0.f},{0.f,0.f,0.f,0.f},{0.f,0.f,0.f,0.f},{0.f,0.f,0.f,0.f}};

    for (int k0 = kbeg; k0 < kend; k0 += 32) {
        *(uint4*)&Ahs[w][l][0] = *(const uint4*)(ga_h + k0);
        *(uint4*)&Als[w][l][0] = *(const uint4*)(ga_l + k0);
        *(uint4*)&Bhs[w][l][0] = *(const uint4*)(gb_h + k0);
        *(uint4*)&Bls[w][l][0] = *(const uint4*)(gb_l + k0);
        __syncthreads();
        bfrag ah  = *(const bfrag*)&Ahs[lq][w * 16 + lrow][0];
        bfrag alo = *(const bfrag*)&Als[lq][w * 16 + lrow][0];
#pragma unroll
        for (int ct = 0; ct < 4; ct++) {
            bfrag bh = *(const bfrag*)&Bhs[lq][ct * 16 + lrow][0];
            bfrag bl = *(const bfrag*)&Bls[lq][ct * 16 + lrow][0];
            acc[ct] = __builtin_amdgcn_mfma_f32_16x16x32_bf16(ah,  bh, acc[ct], 0, 0, 0);
            acc[ct] = __builtin_amdgcn_mfma_f32_16x16x32_bf16(ah,  bl, acc[ct], 0, 0, 0);
            acc[ct] = __builtin_amdgcn_mfma_f32_16x16x32_bf16(alo, bh, acc[ct], 0, 0, 0);
        }
        __syncthreads();
    }

    // C/D layout: col = lane&15, row = quad*4 + reg
#pragma unroll
    for (int ct = 0; ct < 4; ct++) {
        int gc = colBase + ct * 16 + lrow;
        if (gc >= N) continue;
#pragma unroll
        for (int r = 0; r < 4; r++) {
            int gr = rowBase + w * 16 + lq * 4 + r;
            if (gr >= M) continue;
            float v = acc[ct][r];
            if (MODE == 3) {
                C0[(long)blockIdx.z * M * N + (long)gr * N + gc] = v;
            } else if (MODE == 0) {
                float o = v * scale;
                if (bias) o += bias[gc];
                if (addsrc) o += addsrc[(long)gr * ldo + gc];
                C0[(long)gr * ldo + gc] = o;
            } else if (MODE == 1) {
                float o = v + bias[gc];
                unsigned short h = bf16_rne(o);
                H0[(long)gr * ldo + gc] = h;
                L0[(long)gr * ldo + gc] = bf16_rne(o - bf16f(h));
            } else {  // MODE 2: transposed store (ldo = M-dim stride)
                float o = v + bias[gc];
                unsigned short h = bf16_rne(o);
                H0[(long)gc * ldo + gr] = h;
                L0[(long)gc * ldo + gr] = bf16_rne(o - bf16f(h));
            }
        }
    }
}

// ---------- softmax rows of S [4096][4096] -> bf16 hi/lo (values held in regs) ----------
__global__ __launch_bounds__(256) void softmax_hl(const float* __restrict__ S,
                                                  unsigned short* __restrict__ SH,
                                                  unsigned short* __restrict__ SL) {
    int row = blockIdx.x, tid = threadIdx.x;
    const float* p = S + (long)row * BP;
    float ev[16];
    __shared__ float red[256];
    float m = -1e30f;
#pragma unroll
    for (int i = 0; i < 16; i++) { float v = p[tid + i * 256]; ev[i] = v; m = fmaxf(m, v); }
    red[tid] = m; __syncthreads();
    for (int s = 128; s > 0; s >>= 1) { if (tid < s) red[tid] = fmaxf(red[tid], red[tid + s]); __syncthreads(); }
    m = red[0]; __syncthreads();
    float sum = 0.f;
#pragma unroll
    for (int i = 0; i < 16; i++) { float e = expf(ev[i] - m); ev[i] = e; sum += e; }
    red[tid] = sum; __syncthreads();
    for (int s = 128; s > 0; s >>= 1) { if (tid < s) red[tid] += red[tid + s]; __syncthreads(); }
    float inv = 1.0f / red[0];
#pragma unroll
    for (int i = 0; i < 16; i++) {
        float e = ev[i] * inv;
        unsigned short h = bf16_rne(e);
        long o = (long)row * BP + tid + i * 256;
        SH[o] = h;
        SL[o] = bf16_rne(e - bf16f(h));
    }
}

// ---------- split-K reduce + residual -> attn bf16 hi/lo [M][Kp2] (pads zeroed) ----------
__global__ void splitk_reduce_hl(const float* __restrict__ part, const float* __restrict__ resid,
                                 unsigned short* __restrict__ H, unsigned short* __restrict__ L,
                                 int Mr, int Nc, int Kp2, int sk) {
    long idx = (long)blockIdx.x * blockDim.x + threadIdx.x;
    long total = (long)Mr * Kp2;
    if (idx >= total) return;
    int c = (int)(idx % Kp2);
    long row = idx / Kp2;
    float s = 0.f;
    if (c < Nc) {
        long base = row * Nc + c;
        for (int z = 0; z < sk; z++) s += part[(long)z * Mr * Nc + base];
        s += resid[base];
    }
    unsigned short h = bf16_rne(s);
    H[idx] = h;
    L[idx] = bf16_rne(s - bf16f(h));
}

// ---------- scatter (last write wins, numpy semantics) ----------
__global__ void scatter_init(int* last, const int* __restrict__ com, int B) {
    int i = blockIdx.x * blockDim.x + threadIdx.x;
    if (i < B) last[com[i]] = -1;
}
__global__ void scatter_max(int* last, const int* __restrict__ com, int B) {
    int i = blockIdx.x * blockDim.x + threadIdx.x;
    if (i < B) atomicMax(&last[com[i]], i);
}
__global__ void scatter_write(const int* __restrict__ last, const int* __restrict__ com,
                              const float* __restrict__ fused, float* __restrict__ x, int B, int D) {
    int i = blockIdx.x;
    int node = com[i];
    if (last[node] != i) return;
    for (int c = threadIdx.x; c < D; c += blockDim.x)
        x[(long)node * D + c] = fused[(long)i * D + c];
}

// ---------- GAT per-node attention coefficients ----------
__global__ void node_attn_coef(const float* __restrict__ h, const float* __restrict__ a_src,
                               const float* __restrict__ a_dst, float* __restrict__ es,
                               float* __restrict__ ed, int N, int H, int C) {
    int idx = blockIdx.x * blockDim.x + threadIdx.x;
    if (idx >= N * H) return;
    int n = idx / H, hh = idx % H;
    const float* hp = h + (long)n * H * C + (long)hh * C;
    const float* as = a_src + hh * C;
    const float* ad = a_dst + hh * C;
    float s = 0.f, d = 0.f;
    for (int c = 0; c < C; c++) { float v = hp[c]; s += v * as[c]; d += v * ad[c]; }
    es[idx] = s; ed[idx] = d;
}

// ================== CSR build ==================
__global__ void deg_init(int* deg, int n) {
    int i = blockIdx.x * blockDim.x + threadIdx.x;
    if (i < n) deg[i] = 1;
}
__global__ void deg_count(const int* __restrict__ dst, int* deg, int E) {
    int e = blockIdx.x * blockDim.x + threadIdx.x;
    if (e < E) atomicAdd(&deg[dst[e]], 1);
}
#define SCAN_BLOCK 1024
__global__ __launch_bounds__(SCAN_BLOCK) void scan_rowptr(const int* __restrict__ deg, int* __restrict__ rowptr, int n) {
    __shared__ int tmp[SCAN_BLOCK];
    __shared__ int carry;
    int tid = threadIdx.x;
    if (tid == 0) carry = 0;
    __syncthreads();
    for (int base = 0; base < n; base += SCAN_BLOCK) {
        int i = base + tid;
        int v = (i < n) ? deg[i] : 0;
        tmp[tid] = v; __syncthreads();
        for (int off = 1; off < SCAN_BLOCK; off <<= 1) {
            int t2 = (tid >= off) ? tmp[tid - off] : 0;
            __syncthreads();
            tmp[tid] += t2;
            __syncthreads();
        }
        int incl = tmp[tid];
        if (i < n) rowptr[i + 1] = carry + incl;
        __syncthreads();
        if (tid == SCAN_BLOCK - 1) carry += incl;
        __syncthreads();
    }
    if (tid == 0) rowptr[0] = 0;
}
__global__ void copy_i32(const int* __restrict__ a, int* __restrict__ b, int n) {
    int i = blockIdx.x * blockDim.x + threadIdx.x;
    if (i < n) b[i] = a[i];
}
__global__ void csr_fill(const int* __restrict__ src, const int* __restrict__ dst,
                         int* cursor, int* __restrict__ csr_src, int E) {
    int e = blockIdx.x * blockDim.x + threadIdx.x;
    if (e >= E) return;
    int slot = atomicAdd(&cursor[dst[e]], 1);
    csr_src[slot] = src[e];
}
__global__ void csr_fill_loops(int* cursor, int* __restrict__ csr_src, int n) {
    int i = blockIdx.x * blockDim.x + threadIdx.x;
    if (i >= n) return;
    int slot = atomicAdd(&cursor[i], 1);
    csr_src[slot] = i;
}

// ---------- segment max + denom per (node, head) ----------
__global__ void csr_maxden(const int* __restrict__ rowptr, const int* __restrict__ csr_src,
                           const float* __restrict__ es, const float* __restrict__ ed,
                           float* __restrict__ m, float* __restrict__ den, int N, int H) {
    int idx = blockIdx.x * blockDim.x + threadIdx.x;
    if (idx >= N * H) return;
    int d = idx / H, h = idx - d * H;
    float edv = ed[idx];
    int b = rowptr[d], e = rowptr[d + 1];
    float mm = -1e30f;
    for (int s0 = b; s0 < e; s0++) {
        int s = csr_src[s0];
        mm = fmaxf(mm, leaky(es[s * H + h] + edv));
    }
    float dn = 0.f;
    for (int s0 = b; s0 < e; s0++) {
        int s = csr_src[s0];
        dn += expf(leaky(es[s * H + h] + edv) - mm);
    }
    m[idx] = mm;
    den[idx] = dn;
}

// ---------- layer-1 aggregate + bias + ELU + (row @ W2) fused ----------
__global__ __launch_bounds__(128) void csr_agg1_fused(
    const int* __restrict__ rowptr, const int* __restrict__ csr_src,
    const float* __restrict__ es, const float* __restrict__ ed,
    const float* __restrict__ m1, const float* __restrict__ den1,
    const float* __restrict__ h1, const float* __restrict__ b1,
    const float* __restrict__ W2, float* __restrict__ h2, int N)
{
    int d = blockIdx.x;
    int t = threadIdx.x;
    __shared__ float row[HC1];
    __shared__ float part[128][OUTC + 1];

    int b = rowptr[d], e = rowptr[d + 1];
    float ed0 = ed[d * 3 + 0], ed1 = ed[d * 3 + 1], ed2 = ed[d * 3 + 2];
    float mm0 = m1[d * 3 + 0], mm1 = m1[d * 3 + 1], mm2 = m1[d * 3 + 2];
    float i0 = 1.f / (den1[d * 3 + 0] + 1e-16f);
    float i1 = 1.f / (den1[d * 3 + 1] + 1e-16f);
    float i2 = 1.f / (den1[d * 3 + 2] + 1e-16f);

    float a0 = 0.f, a1 = 0.f, a2 = 0.f;
    for (int s0 = b; s0 < e; s0++) {
        int s = csr_src[s0];
        float e0 = es[s * 3 + 0], e1 = es[s * 3 + 1], e2 = es[s * 3 + 2];
        float al0 = expf(leaky(e0 + ed0) - mm0) * i0;
        float al1 = expf(leaky(e1 + ed1) - mm1) * i1;
        float al2 = expf(leaky(e2 + ed2) - mm2) * i2;
        const float* hp = h1 + (long)s * HC1;
        a0 = fmaf(hp[t],       al0, a0);
        a1 = fmaf(hp[t + 128], al1, a1);
        a2 = fmaf(hp[t + 256], al2, a2);
    }
    float v;
    v = a0 + b1[t];       row[t]       = v > 0.f ? v : expf(v) - 1.f;
    v = a1 + b1[t + 128]; row[t + 128] = v > 0.f ? v : expf(v) - 1.f;
    v = a2 + b1[t + 256]; row[t + 256] = v > 0.f ? v : expf(v) - 1.f;
    __syncthreads();

    float pc[OUTC];
#pragma unroll
    for (int c = 0; c < OUTC; c++) pc[c] = 0.f;
    for (int k = t; k < HC1; k += 128) {
        float rv = row[k];
        const float* wp = W2 + (long)k * OUTC;
#pragma unroll
        for (int c = 0; c < OUTC; c++) pc[c] = fmaf(rv, wp[c], pc[c]);
    }
#pragma unroll
    for (int c = 0; c < OUTC; c++) part[t][c] = pc[c];
    __syncthreads();
    for (int off = 64; off > 0; off >>= 1) {
        if (t < off) {
#pragma unroll
            for (int c = 0; c < OUTC; c++) part[t][c] += part[t + off][c];
        }
        __syncthreads();
    }
    if (t < OUTC) h2[(long)d * OUTC + t] = part[0][t];
}

// ---------- layer-2 aggregate + bias ----------
__global__ void csr_agg2(const int* __restrict__ rowptr, const int* __restrict__ csr_src,
                         const float* __restrict__ es, const float* __restrict__ ed,
                         const float* __restrict__ m2, const float* __restrict__ den2,
                         const float* __restrict__ h2, const float* __restrict__ b2,
                         float* __restrict__ emb, int N)
{
    int idx = blockIdx.x * blockDim.x + threadIdx.x;
    if (idx >= N * OUTC) return;
    int d = idx / OUTC, c = idx - d * OUTC;
    float edv = ed[d], mm = m2[d], inv = 1.f / (den2[d] + 1e-16f);
    int b = rowptr[d], e = rowptr[d + 1];
    float acc = 0.f;
    for (int s0 = b; s0 < e; s0++) {
        int s = csr_src[s0];
        float al = expf(leaky(es[s] + edv) - mm) * inv;
        acc = fmaf(h2[(long)s * OUTC + c], al, acc);
    }
    emb[idx] = acc + b2[c];
}

// ---------- pair scores ----------
__global__ void pair_score(const int* __restrict__ pairs, const float* __restrict__ emb,
                           float* __restrict__ out, int P) {
    int p = blockIdx.x * blockDim.x + threadIdx.x;
    if (p >= P) return;
    int i0 = pairs[2 * p], i1 = pairs[2 * p + 1];
    const float* a = emb + (long)i0 * OUTC;
    const float* b = emb + (long)i1 * OUTC;
    float s = 0.f;
#pragma unroll
    for (int c = 0; c < OUTC; c++) s += a[c] * b[c];
    out[p] = s;
}

extern "C" void kernel_launch(void* const* d_in, const int* in_sizes, int n_in,
                              void* d_out, int out_size, void* d_ws, size_t ws_size,
                              hipStream_t stream) {
    const float* fsub = (const float*)d_in[0];
    const float* fcom = (const float*)d_in[1];
    float*       x    = (float*)d_in[2];
    const int*   com  = (const int*)d_in[3];
    const int*   ei   = (const int*)d_in[4];
    const int*   pidx = (const int*)d_in[5];
    const float* Wq = (const float*)d_in[6];  const float* bq = (const float*)d_in[7];
    const float* Wk = (const float*)d_in[8];  const float* bk = (const float*)d_in[9];
    const float* Wv = (const float*)d_in[10]; const float* bv = (const float*)d_in[11];
    const float* Wf = (const float*)d_in[12]; const float* bf = (const float*)d_in[13];
    const float* W1 = (const float*)d_in[14];
    const float* as1 = (const float*)d_in[15]; const float* ad1 = (const float*)d_in[16];
    const float* b1 = (const float*)d_in[17];
    const float* W2 = (const float*)d_in[18];
    const float* as2 = (const float*)d_in[19]; const float* ad2 = (const float*)d_in[20];
    const float* b2 = (const float*)d_in[21];
    float* out = (float*)d_out;

    const int* src = ei;
    const int* dst = ei + NE;

    typedef unsigned short u16;
    char* ws = (char*)d_ws;
    // ---- layout (overlays documented per lifetime) ----
    float* S     = (float*)(ws + 0);            // 67,108,864  (dead after softmax)
    u16*   SH    = (u16*)(ws + 67108864);       // 33,554,432  (dead after S@v)
    u16*   SL    = (u16*)(ws + 100663296);      // 33,554,432
    u16*   fsubH = (u16*)(ws + 134217728);      // 2,621,440   (dead after q proj)
    u16*   fsubL = (u16*)(ws + 136839168);
    u16*   fcomH = (u16*)(ws + 139460608);      // (dead after k,v proj)
    u16*   fcomL = (u16*)(ws + 142082048);
    u16*   qH    = (u16*)(ws + 144703488);      // (dead after S gemm)
    u16*   qL    = (u16*)(ws + 147324928);
    u16*   kH    = (u16*)(ws + 149946368);
    u16*   kL    = (u16*)(ws + 152567808);
    u16*   vTH   = (u16*)(ws + 155189248);      // 2,457,600   (dead after S@v)
    u16*   vTL   = (u16*)(ws + 157646848);
    u16*   attnH = (u16*)(ws + 160104448);      // 2,621,440   (dead after fus gemm)
    u16*   attnL = (u16*)(ws + 162725888);
    u16*   WqTH  = (u16*)(ws + 165347328);      // 192,000 each
    u16*   WqTL  = (u16*)(ws + 165539328);
    u16*   WkTH  = (u16*)(ws + 165731328);
    u16*   WkTL  = (u16*)(ws + 165923328);
    u16*   WvTH  = (u16*)(ws + 166115328);
    u16*   WvTL  = (u16*)(ws + 166307328);
    u16*   WfTH  = (u16*)(ws + 166499328);
    u16*   WfTL  = (u16*)(ws + 166691328);
    u16*   W1TH  = (u16*)(ws + 166883328);      // 245,760
    u16*   W1TL  = (u16*)(ws + 167129088);
    float* fus   = (float*)(ws + 167374848);    // 4,915,200 (alive until scatter)
    float* es1   = (float*)(ws + 172290048);
    float* ed1   = (float*)(ws + 172890048);
    float* m1    = (float*)(ws + 173490048);
    float* den1  = (float*)(ws + 174090048);
    float* es2   = (float*)(ws + 174690048);
    float* ed2   = (float*)(ws + 174890048);
    float* m2    = (float*)(ws + 175090048);
    float* den2  = (float*)(ws + 175290048);
    float* h2    = (float*)(ws + 175490048);    // 2,000,000
    float* embp  = (float*)(ws + 177490048);    // 2,000,000
    int*   last  = (int*)(ws + 179490048);
    int*   deg   = (int*)(ws + 179690048);
    int*   curs  = (int*)(ws + 179890048);
    int*   rowp  = (int*)(ws + 180090048);      // 200,016
    int*   csrc  = (int*)(ws + 180290064);      // 2,200,000 -> ends ~182.5 MB
    // overlays (disjoint in time):
    float* part  = (float*)(ws + 0);            // 39,321,600 over dead S (S@v phase)
    float* h1    = (float*)(ws + 0);            // 76,800,000 over dead S/SH (GAT phase)
    u16*   xH    = (u16*)(ws + 76800000);       // 32,000,000 over dead SH/SL
    u16*   xL    = (u16*)(ws + 108800000);      // over dead SL/fsub/fcom

    const float inv_sqrt_d = 1.0f / sqrtf((float)FEAT);

    // ===== 0. conversions =====
    hipLaunchKernelGGL(convT_pad, dim3(cdiv(FEAT*KP,256)), dim3(256), 0, stream, Wq, WqTH, WqTL, FEAT, FEAT, KP);
    hipLaunchKernelGGL(convT_pad, dim3(cdiv(FEAT*KP,256)), dim3(256), 0, stream, Wk, WkTH, WkTL, FEAT, FEAT, KP);
    hipLaunchKernelGGL(convT_pad, dim3(cdiv(FEAT*KP,256)), dim3(256), 0, stream, Wv, WvTH, WvTL, FEAT, FEAT, KP);
    hipLaunchKernelGGL(convT_pad, dim3(cdiv(FEAT*KP,256)), dim3(256), 0, stream, Wf, WfTH, WfTL, FEAT, FEAT, KP);
    hipLaunchKernelGGL(convT_pad, dim3(cdiv(HC1*KP,256)),  dim3(256), 0, stream, W1, W1TH, W1TL, FEAT, HC1, KP);
    hipLaunchKernelGGL(conv_pad,  dim3(cdiv(BP*KP,256)),   dim3(256), 0, stream, fsub, fsubH, fsubL, BP, FEAT, KP);
    hipLaunchKernelGGL(conv_pad,  dim3(cdiv(BP*KP,256)),   dim3(256), 0, stream, fcom, fcomH, fcomL, BP, FEAT, KP);
    // zero q/k hi+lo (epilogue writes only cols<300; pad cols must be 0). contiguous region.
    hipLaunchKernelGGL(fill_f32, dim3(cdiv(10485760/4,256)), dim3(256), 0, stream, (float*)qH, 0.f, (long)(10485760/4));

    // ===== 1. cross attention =====
    hipLaunchKernelGGL((gemm_bf<1>), dim3(cdiv(FEAT,64), cdiv(BP,64)), dim3(256), 0, stream,
                       fsubH, fsubL, KP, WqTH, WqTL, KP, bq, nullptr, nullptr, qH, qL,
                       BP, FEAT, FEAT, 1.0f, 0, KP);
    hipLaunchKernelGGL((gemm_bf<1>), dim3(cdiv(FEAT,64), cdiv(BP,64)), dim3(256), 0, stream,
                       fcomH, fcomL, KP, WkTH, WkTL, KP, bk, nullptr, nullptr, kH, kL,
                       BP, FEAT, FEAT, 1.0f, 0, KP);
    hipLaunchKernelGGL((gemm_bf<2>), dim3(cdiv(FEAT,64), cdiv(BP,64)), dim3(256), 0, stream,
                       fcomH, fcomL, KP, WvTH, WvTL, KP, bv, nullptr, nullptr, vTH, vTL,
                       BP, FEAT, FEAT, 1.0f, 0, BP);
    // S = (q @ k^T) * inv_sqrt_d
    hipLaunchKernelGGL((gemm_bf<0>), dim3(cdiv(BP,64), cdiv(BP,64)), dim3(256), 0, stream,
                       qH, qL, KP, kH, kL, KP, nullptr, nullptr, S, nullptr, nullptr,
                       BP, BP, FEAT, inv_sqrt_d, 0, BP);
    hipLaunchKernelGGL(softmax_hl, dim3(BP), dim3(256), 0, stream, S, SH, SL);
    // part[z] = S_z @ v   (split-K, sk=8, KC=512)
    hipLaunchKernelGGL((gemm_bf<3>), dim3(cdiv(FEAT,64), cdiv(BP,64), 8), dim3(256), 0, stream,
                       SH, SL, BP, vTH, vTL, BP, nullptr, nullptr, part, nullptr, nullptr,
                       BP, FEAT, BP, 1.0f, 512, 0);
    // attn = fsub + sum_z part[z]  -> bf16 hi/lo [4096][320]
    hipLaunchKernelGGL(splitk_reduce_hl, dim3(cdiv(BP*KP,256)), dim3(256), 0, stream,
                       part, fsub, attnH, attnL, BP, FEAT, KP, 8);
    // fused = attn @ Wf + bf  (fp32)
    hipLaunchKernelGGL((gemm_bf<0>), dim3(cdiv(FEAT,64), cdiv(BP,64)), dim3(256), 0, stream,
                       attnH, attnL, KP, WfTH, WfTL, KP, bf, nullptr, fus, nullptr, nullptr,
                       BP, FEAT, FEAT, 1.0f, 0, FEAT);

    // ===== 2. scatter fused into x (last write wins) =====
    hipLaunchKernelGGL(scatter_init, dim3(cdiv(BP,256)), dim3(256), 0, stream, last, com, BP);
    hipLaunchKernelGGL(scatter_max,  dim3(cdiv(BP,256)), dim3(256), 0, stream, last, com, BP);
    hipLaunchKernelGGL(scatter_write, dim3(BP), dim3(128), 0, stream, last, com, fus, x, BP, FEAT);

    // ===== 3. convert x, CSR build =====
    hipLaunchKernelGGL(conv_pad, dim3(cdiv((long)NN*KP,256)), dim3(256), 0, stream, x, xH, xL, NN, FEAT, KP);
    hipLaunchKernelGGL(deg_init,  dim3(cdiv(NN,256)), dim3(256), 0, stream, deg, NN);
    hipLaunchKernelGGL(deg_count, dim3(cdiv(NE,256)), dim3(256), 0, stream, dst, deg, NE);
    hipLaunchKernelGGL(scan_rowptr, dim3(1), dim3(SCAN_BLOCK), 0, stream, deg, rowp, NN);
    hipLaunchKernelGGL(copy_i32, dim3(cdiv(NN,256)), dim3(256), 0, stream, rowp, curs, NN);
    hipLaunchKernelGGL(csr_fill, dim3(cdiv(NE,256)), dim3(256), 0, stream, src, dst, curs, csrc, NE);
    hipLaunchKernelGGL(csr_fill_loops, dim3(cdiv(NN,256)), dim3(256), 0, stream, curs, csrc, NN);

    // ===== 4. GAT layer 1 =====
    hipLaunchKernelGGL((gemm_bf<0>), dim3(cdiv(HC1,64), cdiv(NN,64)), dim3(256), 0, stream,
                       xH, xL, KP, W1TH, W1TL, KP, nullptr, nullptr, h1, nullptr, nullptr,
                       NN, HC1, FEAT, 1.0f, 0, HC1);
    hipLaunchKernelGGL(node_attn_coef, dim3(cdiv(NN*HEADS,256)), dim3(256), 0, stream,
                       h1, as1, ad1, es1, ed1, NN, HEADS, HID);
    hipLaunchKernelGGL(csr_maxden, dim3(cdiv(NN*HEADS,256)), dim3(256), 0, stream,
                       rowp, csrc, es1, ed1, m1, den1, NN, HEADS);
    hipLaunchKernelGGL(csr_agg1_fused, dim3(NN), dim3(128), 0, stream,
                       rowp, csrc, es1, ed1, m1, den1, h1, b1, W2, h2, NN);

    // ===== 5. GAT layer 2 =====
    hipLaunchKernelGGL(node_attn_coef, dim3(cdiv(NN,256)), dim3(256), 0, stream,
                       h2, as2, ad2, es2, ed2, NN, 1, OUTC);
    hipLaunchKernelGGL(csr_maxden, dim3(cdiv(NN,256)), dim3(256), 0, stream,
                       rowp, csrc, es2, ed2, m2, den2, NN, 1);
    hipLaunchKernelGGL(csr_agg2, dim3(cdiv(NN*OUTC,256)), dim3(256), 0, stream,
                       rowp, csrc, es2, ed2, m2, den2, h2, b2, embp, NN);

    // ===== 6. pair scores =====
    hipLaunchKernelGGL(pair_score, dim3(cdiv(NP,256)), dim3(256), 0, stream, pidx, embp, out, NP);
}

// Round 7
// 1113.096 us; speedup vs baseline: 1.5784x; 1.0128x over previous
//
#include <hip/hip_runtime.h>
#include <math.h>

#define NN      50000      // N_NODES
#define BP      4096       // N_PAIRS_MAP
#define NE      500000     // N_EDGES
#define NP      1000000    // N_SCORE_PAIRS
#define FEAT    300
#define KP      320        // FEAT padded to multiple of 32
#define HID     128
#define HEADS   3
#define OUTC    10
#define HC1     (HEADS*HID)   // 384
#define NEG_SLOPE 0.2f

static inline int cdiv(int a, int b) { return (a + b - 1) / b; }

using bfrag = __attribute__((ext_vector_type(8))) short;
using ffrag = __attribute__((ext_vector_type(4))) float;

__device__ inline float leaky(float x) { return x > 0.f ? x : NEG_SLOPE * x; }
__device__ inline unsigned short bf16_rne(float f) {
    unsigned u = __float_as_uint(f);
    unsigned r = u + 0x7FFFu + ((u >> 16) & 1u);
    return (unsigned short)(r >> 16);
}
__device__ inline float bf16f(unsigned short h) { return __uint_as_float(((unsigned)h) << 16); }

__global__ void fill_f32(float* p, float v, long n) {
    long i = (long)blockIdx.x * blockDim.x + threadIdx.x;
    if (i < n) p[i] = v;
}

// fp32 [M][K] -> bf16 hi/lo [M][Kp], zero-padded k tail
__global__ void conv_pad(const float* __restrict__ in, unsigned short* __restrict__ H,
                         unsigned short* __restrict__ L, long M, int K, int Kp) {
    long idx = (long)blockIdx.x * blockDim.x + threadIdx.x;
    long total = M * Kp;
    if (idx >= total) return;
    int k = (int)(idx % Kp);
    long row = idx / Kp;
    float f = (k < K) ? in[row * K + k] : 0.f;
    unsigned short h = bf16_rne(f);
    H[idx] = h;
    L[idx] = bf16_rne(f - bf16f(h));
}
// fp32 [K][N] row-major -> bf16 hi/lo [N][Kp] (transposed, padded)
__global__ void convT_pad(const float* __restrict__ in, unsigned short* __restrict__ H,
                          unsigned short* __restrict__ L, int K, int N, int Kp) {
    long idx = (long)blockIdx.x * blockDim.x + threadIdx.x;
    long total = (long)N * Kp;
    if (idx >= total) return;
    int k = (int)(idx % Kp);
    long n = idx / Kp;
    float f = (k < K) ? in[(long)k * N + n] : 0.f;
    unsigned short h = bf16_rne(f);
    H[idx] = h;
    L[idx] = bf16_rne(f - bf16f(h));
}

// ================== split-bf16 MFMA GEMM ==================
// C = A@B^T with A[M][lda] hi/lo bf16 (k-contig, zero-padded) and B[N][ldb] hi/lo.
// MODE: 0 = fp32 out (scale, bias?, addsrc?), 1 = bf16 hi/lo out (+bias),
//       2 = transposed bf16 hi/lo out (+bias), 3 = split-K fp32 partials
template <int MODE>
__global__ __launch_bounds__(256) void gemm_bf(
    const unsigned short* __restrict__ Ah, const unsigned short* __restrict__ Al, int lda,
    const unsigned short* __restrict__ Bh, const unsigned short* __restrict__ Bl, int ldb,
    const float* __restrict__ bias, const float* __restrict__ addsrc,
    float* __restrict__ C0, unsigned short* __restrict__ H0, unsigned short* __restrict__ L0,
    int M, int N, int K, float scale, int KC, int ldo)
{
    __shared__ __align__(16) unsigned short Ahs[4][64][8], Als[4][64][8];
    __shared__ __align__(16) unsigned short Bhs[4][64][8], Bls[4][64][8];
    int t = threadIdx.x, w = t >> 6, l = t & 63, lrow = l & 15, lq = l >> 4;
    int rowBase = blockIdx.y * 64, colBase = blockIdx.x * 64;
    int Kr = (K + 31) & ~31;
    int kbeg = (MODE == 3) ? blockIdx.z * KC : 0;
    int kend = (MODE == 3) ? min(Kr, kbeg + KC) : Kr;

    int arow = min(rowBase + l, M - 1);
    int brow = min(colBase + l, N - 1);
    const unsigned short* ga_h = Ah + (long)arow * lda + w * 8;
    const unsigned short* ga_l = Al + (long)arow * lda + w * 8;
    const unsigned short* gb_h = Bh + (long)brow * ldb + w * 8;
    const unsigned short* gb_l = Bl + (long)brow * ldb + w * 8;

    ffrag acc[4] = {{0.f,0.f,0.f,0.f},{0.f,0.f,0.f,0.f},{0.f,0.f,0.f,0.f},{0.f,0.f,0.f,0.f}};

    for (int k0 = kbeg; k0 < kend; k0 += 32) {
        *(uint4*)&Ahs[w][l][0] = *(const uint4*)(ga_h + k0);
        *(uint4*)&Als[w][l][0] = *(const uint4*)(ga_l + k0);
        *(uint4*)&Bhs[w][l][0] = *(const uint4*)(gb_h + k0);
        *(uint4*)&Bls[w][l][0] = *(const uint4*)(gb_l + k0);
        __syncthreads();
        bfrag ah  = *(const bfrag*)&Ahs[lq][w * 16 + lrow][0];
        bfrag alo = *(const bfrag*)&Als[lq][w * 16 + lrow][0];
#pragma unroll
        for (int ct = 0; ct < 4; ct++) {
            bfrag bh = *(const bfrag*)&Bhs[lq][ct * 16 + lrow][0];
            bfrag bl = *(const bfrag*)&Bls[lq][ct * 16 + lrow][0];
            acc[ct] = __builtin_amdgcn_mfma_f32_16x16x32_bf16(ah,  bh, acc[ct], 0, 0, 0);
            acc[ct] = __builtin_amdgcn_mfma_f32_16x16x32_bf16(ah,  bl, acc[ct], 0, 0, 0);
            acc[ct] = __builtin_amdgcn_mfma_f32_16x16x32_bf16(alo, bh, acc[ct], 0, 0, 0);
        }
        __syncthreads();
    }

    // C/D layout: col = lane&15, row = quad*4 + reg
#pragma unroll
    for (int ct = 0; ct < 4; ct++) {
        int gc = colBase + ct * 16 + lrow;
        if (gc >= N) continue;
#pragma unroll
        for (int r = 0; r < 4; r++) {
            int gr = rowBase + w * 16 + lq * 4 + r;
            if (gr >= M) continue;
            float v = acc[ct][r];
            if (MODE == 3) {
                C0[(long)blockIdx.z * M * N + (long)gr * N + gc] = v;
            } else if (MODE == 0) {
                float o = v * scale;
                if (bias) o += bias[gc];
                if (addsrc) o += addsrc[(long)gr * ldo + gc];
                C0[(long)gr * ldo + gc] = o;
            } else if (MODE == 1) {
                float o = v + bias[gc];
                unsigned short h = bf16_rne(o);
                H0[(long)gr * ldo + gc] = h;
                L0[(long)gr * ldo + gc] = bf16_rne(o - bf16f(h));
            } else {  // MODE 2: transposed store
                float o = v + bias[gc];
                unsigned short h = bf16_rne(o);
                H0[(long)gc * ldo + gr] = h;
                L0[(long)gc * ldo + gr] = bf16_rne(o - bf16f(h));
            }
        }
    }
}

// ---------- softmax rows of S -> bf16 hi/lo ----------
__global__ __launch_bounds__(256) void softmax_hl(const float* __restrict__ S,
                                                  unsigned short* __restrict__ SH,
                                                  unsigned short* __restrict__ SL) {
    int row = blockIdx.x, tid = threadIdx.x;
    const float* p = S + (long)row * BP;
    float ev[16];
    __shared__ float red[256];
    float m = -1e30f;
#pragma unroll
    for (int i = 0; i < 16; i++) { float v = p[tid + i * 256]; ev[i] = v; m = fmaxf(m, v); }
    red[tid] = m; __syncthreads();
    for (int s = 128; s > 0; s >>= 1) { if (tid < s) red[tid] = fmaxf(red[tid], red[tid + s]); __syncthreads(); }
    m = red[0]; __syncthreads();
    float sum = 0.f;
#pragma unroll
    for (int i = 0; i < 16; i++) { float e = expf(ev[i] - m); ev[i] = e; sum += e; }
    red[tid] = sum; __syncthreads();
    for (int s = 128; s > 0; s >>= 1) { if (tid < s) red[tid] += red[tid + s]; __syncthreads(); }
    float inv = 1.0f / red[0];
#pragma unroll
    for (int i = 0; i < 16; i++) {
        float e = ev[i] * inv;
        unsigned short h = bf16_rne(e);
        long o = (long)row * BP + tid + i * 256;
        SH[o] = h;
        SL[o] = bf16_rne(e - bf16f(h));
    }
}

// ---------- split-K reduce + residual -> attn bf16 hi/lo ----------
__global__ void splitk_reduce_hl(const float* __restrict__ part, const float* __restrict__ resid,
                                 unsigned short* __restrict__ H, unsigned short* __restrict__ L,
                                 int Mr, int Nc, int Kp2, int sk) {
    long idx = (long)blockIdx.x * blockDim.x + threadIdx.x;
    long total = (long)Mr * Kp2;
    if (idx >= total) return;
    int c = (int)(idx % Kp2);
    long row = idx / Kp2;
    float s = 0.f;
    if (c < Nc) {
        long base = row * Nc + c;
        for (int z = 0; z < sk; z++) s += part[(long)z * Mr * Nc + base];
        s += resid[base];
    }
    unsigned short h = bf16_rne(s);
    H[idx] = h;
    L[idx] = bf16_rne(s - bf16f(h));
}

// ---------- scatter (last write wins) ----------
__global__ void scatter_init(int* last, const int* __restrict__ com, int B) {
    int i = blockIdx.x * blockDim.x + threadIdx.x;
    if (i < B) last[com[i]] = -1;
}
__global__ void scatter_max(int* last, const int* __restrict__ com, int B) {
    int i = blockIdx.x * blockDim.x + threadIdx.x;
    if (i < B) atomicMax(&last[com[i]], i);
}
__global__ void scatter_write(const int* __restrict__ last, const int* __restrict__ com,
                              const float* __restrict__ fused, float* __restrict__ x, int B, int D) {
    int i = blockIdx.x;
    int node = com[i];
    if (last[node] != i) return;
    for (int c = threadIdx.x; c < D; c += blockDim.x)
        x[(long)node * D + c] = fused[(long)i * D + c];
}

// ---------- GAT per-node attention coefficients ----------
__global__ void node_attn_coef(const float* __restrict__ h, const float* __restrict__ a_src,
                               const float* __restrict__ a_dst, float* __restrict__ es,
                               float* __restrict__ ed, int N, int H, int C) {
    int idx = blockIdx.x * blockDim.x + threadIdx.x;
    if (idx >= N * H) return;
    int n = idx / H, hh = idx % H;
    const float* hp = h + (long)n * H * C + (long)hh * C;
    const float* as = a_src + hh * C;
    const float* ad = a_dst + hh * C;
    float s = 0.f, d = 0.f;
    for (int c = 0; c < C; c++) { float v = hp[c]; s += v * as[c]; d += v * ad[c]; }
    es[idx] = s; ed[idx] = d;
}

// ================== CSR build ==================
__global__ void deg_init(int* deg, int n) {
    int i = blockIdx.x * blockDim.x + threadIdx.x;
    if (i < n) deg[i] = 1;
}
__global__ void deg_count(const int* __restrict__ dst, int* deg, int E) {
    int e = blockIdx.x * blockDim.x + threadIdx.x;
    if (e < E) atomicAdd(&deg[dst[e]], 1);
}
#define SCAN_BLOCK 1024
__global__ __launch_bounds__(SCAN_BLOCK) void scan_rowptr(const int* __restrict__ deg, int* __restrict__ rowptr, int n) {
    __shared__ int tmp[SCAN_BLOCK];
    __shared__ int carry;
    int tid = threadIdx.x;
    if (tid == 0) carry = 0;
    __syncthreads();
    for (int base = 0; base < n; base += SCAN_BLOCK) {
        int i = base + tid;
        int v = (i < n) ? deg[i] : 0;
        tmp[tid] = v; __syncthreads();
        for (int off = 1; off < SCAN_BLOCK; off <<= 1) {
            int t2 = (tid >= off) ? tmp[tid - off] : 0;
            __syncthreads();
            tmp[tid] += t2;
            __syncthreads();
        }
        int incl = tmp[tid];
        if (i < n) rowptr[i + 1] = carry + incl;
        __syncthreads();
        if (tid == SCAN_BLOCK - 1) carry += incl;
        __syncthreads();
    }
    if (tid == 0) rowptr[0] = 0;
}
__global__ void copy_i32(const int* __restrict__ a, int* __restrict__ b, int n) {
    int i = blockIdx.x * blockDim.x + threadIdx.x;
    if (i < n) b[i] = a[i];
}
__global__ void csr_fill(const int* __restrict__ src, const int* __restrict__ dst,
                         int* cursor, int* __restrict__ csr_src, int E) {
    int e = blockIdx.x * blockDim.x + threadIdx.x;
    if (e >= E) return;
    int slot = atomicAdd(&cursor[dst[e]], 1);
    csr_src[slot] = src[e];
}
__global__ void csr_fill_loops(int* cursor, int* __restrict__ csr_src, int n) {
    int i = blockIdx.x * blockDim.x + threadIdx.x;
    if (i >= n) return;
    int slot = atomicAdd(&cursor[i], 1);
    csr_src[slot] = i;
}

// ---------- segment max + denom + per-slot alpha, gather over CSR ----------
// H==3: alpha laid out float4 per slot (x,y,z = heads). H==1: float per slot.
template <int H>
__global__ void csr_maxden_alpha(const int* __restrict__ rowptr, const int* __restrict__ csr_src,
                                 const float* __restrict__ es, const float* __restrict__ ed,
                                 float* __restrict__ alpha, int N) {
    int idx = blockIdx.x * blockDim.x + threadIdx.x;
    if (idx >= N * H) return;
    int d = idx / H, h = idx - d * H;
    float edv = ed[idx];
    int b = rowptr[d], e = rowptr[d + 1];
    float mm = -1e30f;
    for (int s0 = b; s0 < e; s0++) {
        int s = csr_src[s0];
        mm = fmaxf(mm, leaky(es[s * H + h] + edv));
    }
    float dn = 0.f;
    for (int s0 = b; s0 < e; s0++) {
        int s = csr_src[s0];
        dn += expf(leaky(es[s * H + h] + edv) - mm);
    }
    float inv = 1.f / (dn + 1e-16f);
    for (int s0 = b; s0 < e; s0++) {
        int s = csr_src[s0];
        float al = expf(leaky(es[s * H + h] + edv) - mm) * inv;
        if (H == 3) alpha[(long)s0 * 4 + h] = al;
        else        alpha[s0] = al;
    }
}

// ---------- layer-1 aggregate (precomputed alpha) + bias + ELU + (row @ W2) ----------
__global__ __launch_bounds__(128) void csr_agg1_fused(
    const int* __restrict__ rowptr, const int* __restrict__ csr_src,
    const float4* __restrict__ alpha,
    const float* __restrict__ h1, const float* __restrict__ b1,
    const float* __restrict__ W2, float* __restrict__ h2, int N)
{
    int d = blockIdx.x;
    int t = threadIdx.x;
    __shared__ float row[HC1];
    __shared__ float part[128][OUTC + 1];

    int b = rowptr[d], e = rowptr[d + 1];
    float a0 = 0.f, a1 = 0.f, a2 = 0.f;
    for (int s0 = b; s0 < e; s0++) {
        int s = csr_src[s0];
        float4 al = alpha[s0];
        const float* hp = h1 + (long)s * HC1;
        a0 = fmaf(hp[t],       al.x, a0);
        a1 = fmaf(hp[t + 128], al.y, a1);
        a2 = fmaf(hp[t + 256], al.z, a2);
    }
    float v;
    v = a0 + b1[t];       row[t]       = v > 0.f ? v : expf(v) - 1.f;
    v = a1 + b1[t + 128]; row[t + 128] = v > 0.f ? v : expf(v) - 1.f;
    v = a2 + b1[t + 256]; row[t + 256] = v > 0.f ? v : expf(v) - 1.f;
    __syncthreads();

    float pc[OUTC];
#pragma unroll
    for (int c = 0; c < OUTC; c++) pc[c] = 0.f;
    for (int k = t; k < HC1; k += 128) {
        float rv = row[k];
        const float* wp = W2 + (long)k * OUTC;
#pragma unroll
        for (int c = 0; c < OUTC; c++) pc[c] = fmaf(rv, wp[c], pc[c]);
    }
#pragma unroll
    for (int c = 0; c < OUTC; c++) part[t][c] = pc[c];
    __syncthreads();
    for (int off = 64; off > 0; off >>= 1) {
        if (t < off) {
#pragma unroll
            for (int c = 0; c < OUTC; c++) part[t][c] += part[t + off][c];
        }
        __syncthreads();
    }
    if (t < OUTC) h2[(long)d * OUTC + t] = part[0][t];
}

// ---------- layer-2 aggregate (precomputed alpha) + bias ----------
__global__ void csr_agg2(const int* __restrict__ rowptr, const int* __restrict__ csr_src,
                         const float* __restrict__ alpha,
                         const float* __restrict__ h2, const float* __restrict__ b2,
                         float* __restrict__ emb, int N)
{
    int idx = blockIdx.x * blockDim.x + threadIdx.x;
    if (idx >= N * OUTC) return;
    int d = idx / OUTC, c = idx - d * OUTC;
    int b = rowptr[d], e = rowptr[d + 1];
    float acc = 0.f;
    for (int s0 = b; s0 < e; s0++) {
        int s = csr_src[s0];
        acc = fmaf(h2[(long)s * OUTC + c], alpha[s0], acc);
    }
    emb[idx] = acc + b2[c];
}

// ---------- pair scores ----------
__global__ void pair_score(const int* __restrict__ pairs, const float* __restrict__ emb,
                           float* __restrict__ out, int P) {
    int p = blockIdx.x * blockDim.x + threadIdx.x;
    if (p >= P) return;
    int i0 = pairs[2 * p], i1 = pairs[2 * p + 1];
    const float* a = emb + (long)i0 * OUTC;
    const float* b = emb + (long)i1 * OUTC;
    float s = 0.f;
#pragma unroll
    for (int c = 0; c < OUTC; c++) s += a[c] * b[c];
    out[p] = s;
}

extern "C" void kernel_launch(void* const* d_in, const int* in_sizes, int n_in,
                              void* d_out, int out_size, void* d_ws, size_t ws_size,
                              hipStream_t stream) {
    const float* fsub = (const float*)d_in[0];
    const float* fcom = (const float*)d_in[1];
    float*       x    = (float*)d_in[2];
    const int*   com  = (const int*)d_in[3];
    const int*   ei   = (const int*)d_in[4];
    const int*   pidx = (const int*)d_in[5];
    const float* Wq = (const float*)d_in[6];  const float* bq = (const float*)d_in[7];
    const float* Wk = (const float*)d_in[8];  const float* bk = (const float*)d_in[9];
    const float* Wv = (const float*)d_in[10]; const float* bv = (const float*)d_in[11];
    const float* Wf = (const float*)d_in[12]; const float* bf = (const float*)d_in[13];
    const float* W1 = (const float*)d_in[14];
    const float* as1 = (const float*)d_in[15]; const float* ad1 = (const float*)d_in[16];
    const float* b1 = (const float*)d_in[17];
    const float* W2 = (const float*)d_in[18];
    const float* as2 = (const float*)d_in[19]; const float* ad2 = (const float*)d_in[20];
    const float* b2 = (const float*)d_in[21];
    float* out = (float*)d_out;

    const int* src = ei;
    const int* dst = ei + NE;

    typedef unsigned short u16;
    char* ws = (char*)d_ws;
    // ---- layout (overlays documented per lifetime) ----
    float* S     = (float*)(ws + 0);            // 67,108,864  (dead after softmax)
    u16*   SH    = (u16*)(ws + 67108864);       // 33,554,432  (dead after S@v)
    u16*   SL    = (u16*)(ws + 100663296);      // 33,554,432
    u16*   fsubH = (u16*)(ws + 134217728);      // dead after q proj
    u16*   fsubL = (u16*)(ws + 136839168);
    u16*   fcomH = (u16*)(ws + 139460608);      // dead after k,v proj
    u16*   fcomL = (u16*)(ws + 142082048);
    u16*   qH    = (u16*)(ws + 144703488);      // dead after S gemm
    u16*   qL    = (u16*)(ws + 147324928);
    u16*   kH    = (u16*)(ws + 149946368);
    u16*   kL    = (u16*)(ws + 152567808);
    u16*   vTH   = (u16*)(ws + 155189248);      // dead after S@v
    u16*   vTL   = (u16*)(ws + 157646848);
    u16*   attnH = (u16*)(ws + 160104448);      // dead after fus gemm
    u16*   attnL = (u16*)(ws + 162725888);
    u16*   WqTH  = (u16*)(ws + 165347328);
    u16*   WqTL  = (u16*)(ws + 165539328);
    u16*   WkTH  = (u16*)(ws + 165731328);
    u16*   WkTL  = (u16*)(ws + 165923328);
    u16*   WvTH  = (u16*)(ws + 166115328);
    u16*   WvTL  = (u16*)(ws + 166307328);
    u16*   WfTH  = (u16*)(ws + 166499328);
    u16*   WfTL  = (u16*)(ws + 166691328);
    u16*   W1TH  = (u16*)(ws + 166883328);
    u16*   W1TL  = (u16*)(ws + 167129088);
    float* fus   = (float*)(ws + 167374848);    // alive until scatter
    float* es1   = (float*)(ws + 172290048);
    float* ed1   = (float*)(ws + 172890048);
    float* es2   = (float*)(ws + 174690048);
    float* ed2   = (float*)(ws + 174890048);
    float* h2    = (float*)(ws + 175490048);
    float* embp  = (float*)(ws + 177490048);
    int*   last  = (int*)(ws + 179490048);
    int*   deg   = (int*)(ws + 179690048);
    int*   curs  = (int*)(ws + 179890048);
    int*   rowp  = (int*)(ws + 180090048);
    int*   csrc  = (int*)(ws + 180290064);      // ends ~182.5 MB
    // overlays (disjoint in time):
    float* part   = (float*)(ws + 0);           // over dead S (S@v phase)
    float* h1     = (float*)(ws + 0);           // over dead S/SH (GAT phase)
    u16*   xH     = (u16*)(ws + 76800000);      // over dead SH/SL
    u16*   xL     = (u16*)(ws + 108800000);
    float* alpha1 = (float*)(ws + 134217728);   // 550000*16 = 8.8 MB over dead fsubH/L/fcomH (GAT phase)
    float* alpha2 = (float*)(ws + 144703488);   // 550000*4  = 2.2 MB over dead qH (GAT phase)

    const float inv_sqrt_d = 1.0f / sqrtf((float)FEAT);

    // ===== 0. conversions =====
    hipLaunchKernelGGL(convT_pad, dim3(cdiv(FEAT*KP,256)), dim3(256), 0, stream, Wq, WqTH, WqTL, FEAT, FEAT, KP);
    hipLaunchKernelGGL(convT_pad, dim3(cdiv(FEAT*KP,256)), dim3(256), 0, stream, Wk, WkTH, WkTL, FEAT, FEAT, KP);
    hipLaunchKernelGGL(convT_pad, dim3(cdiv(FEAT*KP,256)), dim3(256), 0, stream, Wv, WvTH, WvTL, FEAT, FEAT, KP);
    hipLaunchKernelGGL(convT_pad, dim3(cdiv(FEAT*KP,256)), dim3(256), 0, stream, Wf, WfTH, WfTL, FEAT, FEAT, KP);
    hipLaunchKernelGGL(convT_pad, dim3(cdiv(HC1*KP,256)),  dim3(256), 0, stream, W1, W1TH, W1TL, FEAT, HC1, KP);
    hipLaunchKernelGGL(conv_pad,  dim3(cdiv(BP*KP,256)),   dim3(256), 0, stream, fsub, fsubH, fsubL, BP, FEAT, KP);
    hipLaunchKernelGGL(conv_pad,  dim3(cdiv(BP*KP,256)),   dim3(256), 0, stream, fcom, fcomH, fcomL, BP, FEAT, KP);
    // zero q/k hi+lo pad columns (region is contiguous: qH..kL = 10,485,760 B)
    hipLaunchKernelGGL(fill_f32, dim3(cdiv(10485760/4,256)), dim3(256), 0, stream, (float*)qH, 0.f, (long)(10485760/4));

    // ===== 1. cross attention =====
    hipLaunchKernelGGL((gemm_bf<1>), dim3(cdiv(FEAT,64), cdiv(BP,64)), dim3(256), 0, stream,
                       fsubH, fsubL, KP, WqTH, WqTL, KP, bq, nullptr, nullptr, qH, qL,
                       BP, FEAT, FEAT, 1.0f, 0, KP);
    hipLaunchKernelGGL((gemm_bf<1>), dim3(cdiv(FEAT,64), cdiv(BP,64)), dim3(256), 0, stream,
                       fcomH, fcomL, KP, WkTH, WkTL, KP, bk, nullptr, nullptr, kH, kL,
                       BP, FEAT, FEAT, 1.0f, 0, KP);
    hipLaunchKernelGGL((gemm_bf<2>), dim3(cdiv(FEAT,64), cdiv(BP,64)), dim3(256), 0, stream,
                       fcomH, fcomL, KP, WvTH, WvTL, KP, bv, nullptr, nullptr, vTH, vTL,
                       BP, FEAT, FEAT, 1.0f, 0, BP);
    hipLaunchKernelGGL((gemm_bf<0>), dim3(cdiv(BP,64), cdiv(BP,64)), dim3(256), 0, stream,
                       qH, qL, KP, kH, kL, KP, nullptr, nullptr, S, nullptr, nullptr,
                       BP, BP, FEAT, inv_sqrt_d, 0, BP);
    hipLaunchKernelGGL(softmax_hl, dim3(BP), dim3(256), 0, stream, S, SH, SL);
    hipLaunchKernelGGL((gemm_bf<3>), dim3(cdiv(FEAT,64), cdiv(BP,64), 8), dim3(256), 0, stream,
                       SH, SL, BP, vTH, vTL, BP, nullptr, nullptr, part, nullptr, nullptr,
                       BP, FEAT, BP, 1.0f, 512, 0);
    hipLaunchKernelGGL(splitk_reduce_hl, dim3(cdiv(BP*KP,256)), dim3(256), 0, stream,
                       part, fsub, attnH, attnL, BP, FEAT, KP, 8);
    hipLaunchKernelGGL((gemm_bf<0>), dim3(cdiv(FEAT,64), cdiv(BP,64)), dim3(256), 0, stream,
                       attnH, attnL, KP, WfTH, WfTL, KP, bf, nullptr, fus, nullptr, nullptr,
                       BP, FEAT, FEAT, 1.0f, 0, FEAT);

    // ===== 2. scatter fused into x (last write wins) =====
    hipLaunchKernelGGL(scatter_init, dim3(cdiv(BP,256)), dim3(256), 0, stream, last, com, BP);
    hipLaunchKernelGGL(scatter_max,  dim3(cdiv(BP,256)), dim3(256), 0, stream, last, com, BP);
    hipLaunchKernelGGL(scatter_write, dim3(BP), dim3(128), 0, stream, last, com, fus, x, BP, FEAT);

    // ===== 3. convert x, CSR build =====
    hipLaunchKernelGGL(conv_pad, dim3(cdiv((long)NN*KP,256)), dim3(256), 0, stream, x, xH, xL, NN, FEAT, KP);
    hipLaunchKernelGGL(deg_init,  dim3(cdiv(NN,256)), dim3(256), 0, stream, deg, NN);
    hipLaunchKernelGGL(deg_count, dim3(cdiv(NE,256)), dim3(256), 0, stream, dst, deg, NE);
    hipLaunchKernelGGL(scan_rowptr, dim3(1), dim3(SCAN_BLOCK), 0, stream, deg, rowp, NN);
    hipLaunchKernelGGL(copy_i32, dim3(cdiv(NN,256)), dim3(256), 0, stream, rowp, curs, NN);
    hipLaunchKernelGGL(csr_fill, dim3(cdiv(NE,256)), dim3(256), 0, stream, src, dst, curs, csrc, NE);
    hipLaunchKernelGGL(csr_fill_loops, dim3(cdiv(NN,256)), dim3(256), 0, stream, curs, csrc, NN);

    // ===== 4. GAT layer 1 =====
    hipLaunchKernelGGL((gemm_bf<0>), dim3(cdiv(HC1,64), cdiv(NN,64)), dim3(256), 0, stream,
                       xH, xL, KP, W1TH, W1TL, KP, nullptr, nullptr, h1, nullptr, nullptr,
                       NN, HC1, FEAT, 1.0f, 0, HC1);
    hipLaunchKernelGGL(node_attn_coef, dim3(cdiv(NN*HEADS,256)), dim3(256), 0, stream,
                       h1, as1, ad1, es1, ed1, NN, HEADS, HID);
    hipLaunchKernelGGL((csr_maxden_alpha<HEADS>), dim3(cdiv(NN*HEADS,256)), dim3(256), 0, stream,
                       rowp, csrc, es1, ed1, alpha1, NN);
    hipLaunchKernelGGL(csr_agg1_fused, dim3(NN), dim3(128), 0, stream,
                       rowp, csrc, (const float4*)alpha1, h1, b1, W2, h2, NN);

    // ===== 5. GAT layer 2 =====
    hipLaunchKernelGGL(node_attn_coef, dim3(cdiv(NN,256)), dim3(256), 0, stream,
                       h2, as2, ad2, es2, ed2, NN, 1, OUTC);
    hipLaunchKernelGGL((csr_maxden_alpha<1>), dim3(cdiv(NN,256)), dim3(256), 0, stream,
                       rowp, csrc, es2, ed2, alpha2, NN);
    hipLaunchKernelGGL(csr_agg2, dim3(cdiv(NN*OUTC,256)), dim3(256), 0, stream,
                       rowp, csrc, alpha2, h2, b2, embp, NN);

    // ===== 6. pair scores =====
    hipLaunchKernelGGL(pair_score, dim3(cdiv(NP,256)), dim3(256), 0, stream, pidx, embp, out, NP);
}

// Round 8
// 998.586 us; speedup vs baseline: 1.7594x; 1.1147x over previous
//
#include <hip/hip_runtime.h>
#include <math.h>

#define NN      50000      // N_NODES
#define BP      4096       // N_PAIRS_MAP
#define NE      500000     // N_EDGES
#define NP      1000000    // N_SCORE_PAIRS
#define FEAT    300
#define KP      320        // FEAT padded to multiple of 32
#define HID     128
#define HEADS   3
#define OUTC    10
#define HC1     (HEADS*HID)   // 384
#define NEG_SLOPE 0.2f

static inline int cdiv(int a, int b) { return (a + b - 1) / b; }

using bfrag = __attribute__((ext_vector_type(8))) short;
using ffrag = __attribute__((ext_vector_type(4))) float;

__device__ inline float leaky(float x) { return x > 0.f ? x : NEG_SLOPE * x; }
__device__ inline unsigned short bf16_rne(float f) {
    unsigned u = __float_as_uint(f);
    unsigned r = u + 0x7FFFu + ((u >> 16) & 1u);
    return (unsigned short)(r >> 16);
}
__device__ inline float bf16f(unsigned short h) { return __uint_as_float(((unsigned)h) << 16); }

__global__ void fill_f32(float* p, float v, long n) {
    long i = (long)blockIdx.x * blockDim.x + threadIdx.x;
    if (i < n) p[i] = v;
}

// fp32 [M][K] -> bf16 hi/lo [M][Kp], zero-padded k tail
__global__ void conv_pad(const float* __restrict__ in, unsigned short* __restrict__ H,
                         unsigned short* __restrict__ L, long M, int K, int Kp) {
    long idx = (long)blockIdx.x * blockDim.x + threadIdx.x;
    long total = M * Kp;
    if (idx >= total) return;
    int k = (int)(idx % Kp);
    long row = idx / Kp;
    float f = (k < K) ? in[row * K + k] : 0.f;
    unsigned short h = bf16_rne(f);
    H[idx] = h;
    L[idx] = bf16_rne(f - bf16f(h));
}
// fp32 [K][N] row-major -> bf16 hi/lo [N][Kp] (transposed, padded)
__global__ void convT_pad(const float* __restrict__ in, unsigned short* __restrict__ H,
                          unsigned short* __restrict__ L, int K, int N, int Kp) {
    long idx = (long)blockIdx.x * blockDim.x + threadIdx.x;
    long total = (long)N * Kp;
    if (idx >= total) return;
    int k = (int)(idx % Kp);
    long n = idx / Kp;
    float f = (k < K) ? in[(long)k * N + n] : 0.f;
    unsigned short h = bf16_rne(f);
    H[idx] = h;
    L[idx] = bf16_rne(f - bf16f(h));
}

// ================== split-bf16 MFMA GEMM (64x64 tile) ==================
// MODE: 0 = fp32 out (scale, bias?, addsrc?), 1 = bf16 hi/lo out (+bias),
//       2 = transposed bf16 hi/lo out (+bias), 3 = split-K fp32 partials
template <int MODE>
__global__ __launch_bounds__(256) void gemm_bf(
    const unsigned short* __restrict__ Ah, const unsigned short* __restrict__ Al, int lda,
    const unsigned short* __restrict__ Bh, const unsigned short* __restrict__ Bl, int ldb,
    const float* __restrict__ bias, const float* __restrict__ addsrc,
    float* __restrict__ C0, unsigned short* __restrict__ H0, unsigned short* __restrict__ L0,
    int M, int N, int K, float scale, int KC, int ldo)
{
    __shared__ __align__(16) unsigned short Ahs[4][64][8], Als[4][64][8];
    __shared__ __align__(16) unsigned short Bhs[4][64][8], Bls[4][64][8];
    int t = threadIdx.x, w = t >> 6, l = t & 63, lrow = l & 15, lq = l >> 4;
    int rowBase = blockIdx.y * 64, colBase = blockIdx.x * 64;
    int Kr = (K + 31) & ~31;
    int kbeg = (MODE == 3) ? blockIdx.z * KC : 0;
    int kend = (MODE == 3) ? min(Kr, kbeg + KC) : Kr;

    int arow = min(rowBase + l, M - 1);
    int brow = min(colBase + l, N - 1);
    const unsigned short* ga_h = Ah + (long)arow * lda + w * 8;
    const unsigned short* ga_l = Al + (long)arow * lda + w * 8;
    const unsigned short* gb_h = Bh + (long)brow * ldb + w * 8;
    const unsigned short* gb_l = Bl + (long)brow * ldb + w * 8;

    ffrag acc[4] = {{0.f,0.f,0.f,0.f},{0.f,0.f,0.f,0.f},{0.f,0.f,0.f,0.f},{0.f,0.f,0.f,0.f}};

    for (int k0 = kbeg; k0 < kend; k0 += 32) {
        *(uint4*)&Ahs[w][l][0] = *(const uint4*)(ga_h + k0);
        *(uint4*)&Als[w][l][0] = *(const uint4*)(ga_l + k0);
        *(uint4*)&Bhs[w][l][0] = *(const uint4*)(gb_h + k0);
        *(uint4*)&Bls[w][l][0] = *(const uint4*)(gb_l + k0);
        __syncthreads();
        bfrag ah  = *(const bfrag*)&Ahs[lq][w * 16 + lrow][0];
        bfrag alo = *(const bfrag*)&Als[lq][w * 16 + lrow][0];
#pragma unroll
        for (int ct = 0; ct < 4; ct++) {
            bfrag bh = *(const bfrag*)&Bhs[lq][ct * 16 + lrow][0];
            bfrag bl = *(const bfrag*)&Bls[lq][ct * 16 + lrow][0];
            acc[ct] = __builtin_amdgcn_mfma_f32_16x16x32_bf16(ah,  bh, acc[ct], 0, 0, 0);
            acc[ct] = __builtin_amdgcn_mfma_f32_16x16x32_bf16(ah,  bl, acc[ct], 0, 0, 0);
            acc[ct] = __builtin_amdgcn_mfma_f32_16x16x32_bf16(alo, bh, acc[ct], 0, 0, 0);
        }
        __syncthreads();
    }

#pragma unroll
    for (int ct = 0; ct < 4; ct++) {
        int gc = colBase + ct * 16 + lrow;
        if (gc >= N) continue;
#pragma unroll
        for (int r = 0; r < 4; r++) {
            int gr = rowBase + w * 16 + lq * 4 + r;
            if (gr >= M) continue;
            float v = acc[ct][r];
            if (MODE == 3) {
                C0[(long)blockIdx.z * M * N + (long)gr * N + gc] = v;
            } else if (MODE == 0) {
                float o = v * scale;
                if (bias) o += bias[gc];
                if (addsrc) o += addsrc[(long)gr * ldo + gc];
                C0[(long)gr * ldo + gc] = o;
            } else if (MODE == 1) {
                float o = v + bias[gc];
                unsigned short h = bf16_rne(o);
                H0[(long)gr * ldo + gc] = h;
                L0[(long)gr * ldo + gc] = bf16_rne(o - bf16f(h));
            } else {
                float o = v + bias[gc];
                unsigned short h = bf16_rne(o);
                H0[(long)gc * ldo + gr] = h;
                L0[(long)gc * ldo + gr] = bf16_rne(o - bf16f(h));
            }
        }
    }
}

// ================== wide GEMM: 64 rows x full N=384 cols per block ==================
// For x@W1: A fetched exactly once from HBM; B (W1, 0.5 MB) stays L2-hot.
#define WCT 24   // 24 col-tiles of 16 = 384
__global__ __launch_bounds__(256) void gemm_wide(
    const unsigned short* __restrict__ Ah, const unsigned short* __restrict__ Al, int lda,
    const unsigned short* __restrict__ Bh, const unsigned short* __restrict__ Bl, int ldb,
    float* __restrict__ C0, int M, int K)
{
    __shared__ __align__(16) unsigned short Ahs[4][64][8], Als[4][64][8];
    __shared__ __align__(16) unsigned short Bhs[4][WCT * 16][8], Bls[4][WCT * 16][8];
    int t = threadIdx.x, w = t >> 6, l = t & 63, lrow = l & 15, lq = l >> 4;
    int rowBase = blockIdx.x * 64;
    int Kr = (K + 31) & ~31;

    int arow = min(rowBase + l, M - 1);
    const unsigned short* ga_h = Ah + (long)arow * lda + w * 8;
    const unsigned short* ga_l = Al + (long)arow * lda + w * 8;
    int bcol0 = t >> 2, bq = t & 3;   // B staging: col = bcol0 + 64*i, quad = bq

    ffrag acc[WCT];
#pragma unroll
    for (int i = 0; i < WCT; i++) acc[i] = ffrag{0.f, 0.f, 0.f, 0.f};

    for (int k0 = 0; k0 < Kr; k0 += 32) {
        *(uint4*)&Ahs[w][l][0] = *(const uint4*)(ga_h + k0);
        *(uint4*)&Als[w][l][0] = *(const uint4*)(ga_l + k0);
#pragma unroll
        for (int i = 0; i < 6; i++) {
            int col = bcol0 + 64 * i;
            const unsigned short* gb_h = Bh + (long)col * ldb + bq * 8 + k0;
            const unsigned short* gb_l = Bl + (long)col * ldb + bq * 8 + k0;
            *(uint4*)&Bhs[bq][col][0] = *(const uint4*)gb_h;
            *(uint4*)&Bls[bq][col][0] = *(const uint4*)gb_l;
        }
        __syncthreads();
        bfrag ah  = *(const bfrag*)&Ahs[lq][w * 16 + lrow][0];
        bfrag alo = *(const bfrag*)&Als[lq][w * 16 + lrow][0];
#pragma unroll
        for (int ct = 0; ct < WCT; ct++) {
            bfrag bh = *(const bfrag*)&Bhs[lq][ct * 16 + lrow][0];
            bfrag bl = *(const bfrag*)&Bls[lq][ct * 16 + lrow][0];
            acc[ct] = __builtin_amdgcn_mfma_f32_16x16x32_bf16(ah,  bh, acc[ct], 0, 0, 0);
            acc[ct] = __builtin_amdgcn_mfma_f32_16x16x32_bf16(ah,  bl, acc[ct], 0, 0, 0);
            acc[ct] = __builtin_amdgcn_mfma_f32_16x16x32_bf16(alo, bh, acc[ct], 0, 0, 0);
        }
        __syncthreads();
    }

#pragma unroll
    for (int ct = 0; ct < WCT; ct++) {
        int gc = ct * 16 + lrow;
#pragma unroll
        for (int r = 0; r < 4; r++) {
            int gr = rowBase + w * 16 + lq * 4 + r;
            if (gr >= M) continue;
            C0[(long)gr * (WCT * 16) + gc] = acc[ct][r];
        }
    }
}

// ---------- softmax rows of S -> bf16 hi/lo ----------
__global__ __launch_bounds__(256) void softmax_hl(const float* __restrict__ S,
                                                  unsigned short* __restrict__ SH,
                                                  unsigned short* __restrict__ SL) {
    int row = blockIdx.x, tid = threadIdx.x;
    const float* p = S + (long)row * BP;
    float ev[16];
    __shared__ float red[256];
    float m = -1e30f;
#pragma unroll
    for (int i = 0; i < 16; i++) { float v = p[tid + i * 256]; ev[i] = v; m = fmaxf(m, v); }
    red[tid] = m; __syncthreads();
    for (int s = 128; s > 0; s >>= 1) { if (tid < s) red[tid] = fmaxf(red[tid], red[tid + s]); __syncthreads(); }
    m = red[0]; __syncthreads();
    float sum = 0.f;
#pragma unroll
    for (int i = 0; i < 16; i++) { float e = expf(ev[i] - m); ev[i] = e; sum += e; }
    red[tid] = sum; __syncthreads();
    for (int s = 128; s > 0; s >>= 1) { if (tid < s) red[tid] += red[tid + s]; __syncthreads(); }
    float inv = 1.0f / red[0];
#pragma unroll
    for (int i = 0; i < 16; i++) {
        float e = ev[i] * inv;
        unsigned short h = bf16_rne(e);
        long o = (long)row * BP + tid + i * 256;
        SH[o] = h;
        SL[o] = bf16_rne(e - bf16f(h));
    }
}

// ---------- split-K reduce + residual -> attn bf16 hi/lo ----------
__global__ void splitk_reduce_hl(const float* __restrict__ part, const float* __restrict__ resid,
                                 unsigned short* __restrict__ H, unsigned short* __restrict__ L,
                                 int Mr, int Nc, int Kp2, int sk) {
    long idx = (long)blockIdx.x * blockDim.x + threadIdx.x;
    long total = (long)Mr * Kp2;
    if (idx >= total) return;
    int c = (int)(idx % Kp2);
    long row = idx / Kp2;
    float s = 0.f;
    if (c < Nc) {
        long base = row * Nc + c;
        for (int z = 0; z < sk; z++) s += part[(long)z * Mr * Nc + base];
        s += resid[base];
    }
    unsigned short h = bf16_rne(s);
    H[idx] = h;
    L[idx] = bf16_rne(s - bf16f(h));
}

// ---------- scatter (last write wins) ----------
__global__ void scatter_init(int* last, const int* __restrict__ com, int B) {
    int i = blockIdx.x * blockDim.x + threadIdx.x;
    if (i < B) last[com[i]] = -1;
}
__global__ void scatter_max(int* last, const int* __restrict__ com, int B) {
    int i = blockIdx.x * blockDim.x + threadIdx.x;
    if (i < B) atomicMax(&last[com[i]], i);
}
__global__ void scatter_write(const int* __restrict__ last, const int* __restrict__ com,
                              const float* __restrict__ fused, float* __restrict__ x, int B, int D) {
    int i = blockIdx.x;
    int node = com[i];
    if (last[node] != i) return;
    for (int c = threadIdx.x; c < D; c += blockDim.x)
        x[(long)node * D + c] = fused[(long)i * D + c];
}

// ---------- GAT per-node attention coefficients ----------
__global__ void node_attn_coef(const float* __restrict__ h, const float* __restrict__ a_src,
                               const float* __restrict__ a_dst, float* __restrict__ es,
                               float* __restrict__ ed, int N, int H, int C) {
    int idx = blockIdx.x * blockDim.x + threadIdx.x;
    if (idx >= N * H) return;
    int n = idx / H, hh = idx % H;
    const float* hp = h + (long)n * H * C + (long)hh * C;
    const float* as = a_src + hh * C;
    const float* ad = a_dst + hh * C;
    float s = 0.f, d = 0.f;
    for (int c = 0; c < C; c++) { float v = hp[c]; s += v * as[c]; d += v * ad[c]; }
    es[idx] = s; ed[idx] = d;
}

// ================== CSR build ==================
__global__ void deg_init(int* deg, int n) {
    int i = blockIdx.x * blockDim.x + threadIdx.x;
    if (i < n) deg[i] = 1;
}
__global__ void deg_count(const int* __restrict__ dst, int* deg, int E) {
    int e = blockIdx.x * blockDim.x + threadIdx.x;
    if (e < E) atomicAdd(&deg[dst[e]], 1);
}
// ---- multi-block exclusive scan: partials -> scan block sums -> final ----
__global__ void scan_part(const int* __restrict__ deg, int* __restrict__ bsum, int n) {
    __shared__ int red[256];
    int tid = threadIdx.x;
    int i = blockIdx.x * 256 + tid;
    red[tid] = (i < n) ? deg[i] : 0;
    __syncthreads();
    for (int s = 128; s > 0; s >>= 1) { if (tid < s) red[tid] += red[tid + s]; __syncthreads(); }
    if (tid == 0) bsum[blockIdx.x] = red[0];
}
__global__ __launch_bounds__(256) void scan_bsum(int* __restrict__ bsum, int nb) {
    __shared__ int tmp[256];
    int tid = threadIdx.x;
    int v = (tid < nb) ? bsum[tid] : 0;
    tmp[tid] = v; __syncthreads();
    for (int off = 1; off < 256; off <<= 1) {
        int t2 = (tid >= off) ? tmp[tid - off] : 0;
        __syncthreads();
        tmp[tid] += t2;
        __syncthreads();
    }
    if (tid < nb) bsum[tid] = tmp[tid];   // inclusive scan of block sums
}
__global__ void scan_final(const int* __restrict__ deg, const int* __restrict__ bsum,
                           int* __restrict__ rowptr, int n) {
    __shared__ int tmp[256];
    int tid = threadIdx.x;
    int b = blockIdx.x;
    int i = b * 256 + tid;
    int v = (i < n) ? deg[i] : 0;
    tmp[tid] = v; __syncthreads();
    for (int off = 1; off < 256; off <<= 1) {
        int t2 = (tid >= off) ? tmp[tid - off] : 0;
        __syncthreads();
        tmp[tid] += t2;
        __syncthreads();
    }
    int base = (b > 0) ? bsum[b - 1] : 0;
    if (i < n) rowptr[i + 1] = base + tmp[tid];
    if (b == 0 && tid == 0) rowptr[0] = 0;
}
__global__ void copy_i32(const int* __restrict__ a, int* __restrict__ b, int n) {
    int i = blockIdx.x * blockDim.x + threadIdx.x;
    if (i < n) b[i] = a[i];
}
__global__ void csr_fill(const int* __restrict__ src, const int* __restrict__ dst,
                         int* cursor, int* __restrict__ csr_src, int E) {
    int e = blockIdx.x * blockDim.x + threadIdx.x;
    if (e >= E) return;
    int slot = atomicAdd(&cursor[dst[e]], 1);
    csr_src[slot] = src[e];
}
__global__ void csr_fill_loops(int* cursor, int* __restrict__ csr_src, int n) {
    int i = blockIdx.x * blockDim.x + threadIdx.x;
    if (i >= n) return;
    int slot = atomicAdd(&cursor[i], 1);
    csr_src[slot] = i;
}

// ---------- segment max + denom + per-slot alpha ----------
template <int H>
__global__ void csr_maxden_alpha(const int* __restrict__ rowptr, const int* __restrict__ csr_src,
                                 const float* __restrict__ es, const float* __restrict__ ed,
                                 float* __restrict__ alpha, int N) {
    int idx = blockIdx.x * blockDim.x + threadIdx.x;
    if (idx >= N * H) return;
    int d = idx / H, h = idx - d * H;
    float edv = ed[idx];
    int b = rowptr[d], e = rowptr[d + 1];
    float mm = -1e30f;
    for (int s0 = b; s0 < e; s0++) {
        int s = csr_src[s0];
        mm = fmaxf(mm, leaky(es[s * H + h] + edv));
    }
    float dn = 0.f;
    for (int s0 = b; s0 < e; s0++) {
        int s = csr_src[s0];
        dn += expf(leaky(es[s * H + h] + edv) - mm);
    }
    float inv = 1.f / (dn + 1e-16f);
    for (int s0 = b; s0 < e; s0++) {
        int s = csr_src[s0];
        float al = expf(leaky(es[s * H + h] + edv) - mm) * inv;
        if (H == 3) alpha[(long)s0 * 4 + h] = al;
        else        alpha[s0] = al;
    }
}

// ---------- layer-1 aggregate + bias + ELU + (row @ W2) ----------
__global__ __launch_bounds__(128) void csr_agg1_fused(
    const int* __restrict__ rowptr, const int* __restrict__ csr_src,
    const float4* __restrict__ alpha,
    const float* __restrict__ h1, const float* __restrict__ b1,
    const float* __restrict__ W2, float* __restrict__ h2, int N)
{
    int d = blockIdx.x;
    int t = threadIdx.x;
    __shared__ float row[HC1];
    __shared__ float part[128][OUTC + 1];

    int b = rowptr[d], e = rowptr[d + 1];
    float a0 = 0.f, a1 = 0.f, a2 = 0.f;
    for (int s0 = b; s0 < e; s0++) {
        int s = csr_src[s0];
        float4 al = alpha[s0];
        const float* hp = h1 + (long)s * HC1;
        a0 = fmaf(hp[t],       al.x, a0);
        a1 = fmaf(hp[t + 128], al.y, a1);
        a2 = fmaf(hp[t + 256], al.z, a2);
    }
    float v;
    v = a0 + b1[t];       row[t]       = v > 0.f ? v : expf(v) - 1.f;
    v = a1 + b1[t + 128]; row[t + 128] = v > 0.f ? v : expf(v) - 1.f;
    v = a2 + b1[t + 256]; row[t + 256] = v > 0.f ? v : expf(v) - 1.f;
    __syncthreads();

    float pc[OUTC];
#pragma unroll
    for (int c = 0; c < OUTC; c++) pc[c] = 0.f;
    for (int k = t; k < HC1; k += 128) {
        float rv = row[k];
        const float* wp = W2 + (long)k * OUTC;
#pragma unroll
        for (int c = 0; c < OUTC; c++) pc[c] = fmaf(rv, wp[c], pc[c]);
    }
#pragma unroll
    for (int c = 0; c < OUTC; c++) part[t][c] = pc[c];
    __syncthreads();
    for (int off = 64; off > 0; off >>= 1) {
        if (t < off) {
#pragma unroll
            for (int c = 0; c < OUTC; c++) part[t][c] += part[t + off][c];
        }
        __syncthreads();
    }
    if (t < OUTC) h2[(long)d * OUTC + t] = part[0][t];
}

// ---------- layer-2 aggregate + bias ----------
__global__ void csr_agg2(const int* __restrict__ rowptr, const int* __restrict__ csr_src,
                         const float* __restrict__ alpha,
                         const float* __restrict__ h2, const float* __restrict__ b2,
                         float* __restrict__ emb, int N)
{
    int idx = blockIdx.x * blockDim.x + threadIdx.x;
    if (idx >= N * OUTC) return;
    int d = idx / OUTC, c = idx - d * OUTC;
    int b = rowptr[d], e = rowptr[d + 1];
    float acc = 0.f;
    for (int s0 = b; s0 < e; s0++) {
        int s = csr_src[s0];
        acc = fmaf(h2[(long)s * OUTC + c], alpha[s0], acc);
    }
    emb[idx] = acc + b2[c];
}

// ---------- pair scores ----------
__global__ void pair_score(const int* __restrict__ pairs, const float* __restrict__ emb,
                           float* __restrict__ out, int P) {
    int p = blockIdx.x * blockDim.x + threadIdx.x;
    if (p >= P) return;
    int i0 = pairs[2 * p], i1 = pairs[2 * p + 1];
    const float* a = emb + (long)i0 * OUTC;
    const float* b = emb + (long)i1 * OUTC;
    float s = 0.f;
#pragma unroll
    for (int c = 0; c < OUTC; c++) s += a[c] * b[c];
    out[p] = s;
}

extern "C" void kernel_launch(void* const* d_in, const int* in_sizes, int n_in,
                              void* d_out, int out_size, void* d_ws, size_t ws_size,
                              hipStream_t stream) {
    const float* fsub = (const float*)d_in[0];
    const float* fcom = (const float*)d_in[1];
    float*       x    = (float*)d_in[2];
    const int*   com  = (const int*)d_in[3];
    const int*   ei   = (const int*)d_in[4];
    const int*   pidx = (const int*)d_in[5];
    const float* Wq = (const float*)d_in[6];  const float* bq = (const float*)d_in[7];
    const float* Wk = (const float*)d_in[8];  const float* bk = (const float*)d_in[9];
    const float* Wv = (const float*)d_in[10]; const float* bv = (const float*)d_in[11];
    const float* Wf = (const float*)d_in[12]; const float* bf = (const float*)d_in[13];
    const float* W1 = (const float*)d_in[14];
    const float* as1 = (const float*)d_in[15]; const float* ad1 = (const float*)d_in[16];
    const float* b1 = (const float*)d_in[17];
    const float* W2 = (const float*)d_in[18];
    const float* as2 = (const float*)d_in[19]; const float* ad2 = (const float*)d_in[20];
    const float* b2 = (const float*)d_in[21];
    float* out = (float*)d_out;

    const int* src = ei;
    const int* dst = ei + NE;

    typedef unsigned short u16;
    char* ws = (char*)d_ws;
    float* S     = (float*)(ws + 0);            // dead after softmax
    u16*   SH    = (u16*)(ws + 67108864);       // dead after S@v
    u16*   SL    = (u16*)(ws + 100663296);
    u16*   fsubH = (u16*)(ws + 134217728);      // dead after q proj
    u16*   fsubL = (u16*)(ws + 136839168);
    u16*   fcomH = (u16*)(ws + 139460608);      // dead after k,v proj
    u16*   fcomL = (u16*)(ws + 142082048);
    u16*   qH    = (u16*)(ws + 144703488);      // dead after S gemm
    u16*   qL    = (u16*)(ws + 147324928);
    u16*   kH    = (u16*)(ws + 149946368);
    u16*   kL    = (u16*)(ws + 152567808);
    u16*   vTH   = (u16*)(ws + 155189248);      // dead after S@v
    u16*   vTL   = (u16*)(ws + 157646848);
    u16*   attnH = (u16*)(ws + 160104448);      // dead after fus gemm
    u16*   attnL = (u16*)(ws + 162725888);
    u16*   WqTH  = (u16*)(ws + 165347328);
    u16*   WqTL  = (u16*)(ws + 165539328);
    u16*   WkTH  = (u16*)(ws + 165731328);
    u16*   WkTL  = (u16*)(ws + 165923328);
    u16*   WvTH  = (u16*)(ws + 166115328);
    u16*   WvTL  = (u16*)(ws + 166307328);
    u16*   WfTH  = (u16*)(ws + 166499328);
    u16*   WfTL  = (u16*)(ws + 166691328);
    u16*   W1TH  = (u16*)(ws + 166883328);
    u16*   W1TL  = (u16*)(ws + 167129088);
    float* fus   = (float*)(ws + 167374848);    // alive until scatter
    float* es1   = (float*)(ws + 172290048);
    float* ed1   = (float*)(ws + 172890048);
    float* es2   = (float*)(ws + 174690048);
    float* ed2   = (float*)(ws + 174890048);
    float* h2    = (float*)(ws + 175490048);
    float* embp  = (float*)(ws + 177490048);
    int*   last  = (int*)(ws + 179490048);
    int*   deg   = (int*)(ws + 179690048);
    int*   curs  = (int*)(ws + 179890048);
    int*   rowp  = (int*)(ws + 180090048);
    int*   csrc  = (int*)(ws + 180290064);      // ends 182,490,064
    int*   bsum  = (int*)(ws + 182490112);      // 196 ints
    // overlays (disjoint in time):
    float* part   = (float*)(ws + 0);           // over dead S (S@v phase)
    float* h1     = (float*)(ws + 0);           // over dead S/SH (GAT phase)
    u16*   xH     = (u16*)(ws + 76800000);      // over dead SH/SL
    u16*   xL     = (u16*)(ws + 108800000);
    float* alpha1 = (float*)(ws + 134217728);   // over dead fsubH/L/fcomH (GAT phase)
    float* alpha2 = (float*)(ws + 144703488);   // over dead qH (GAT phase)

    const float inv_sqrt_d = 1.0f / sqrtf((float)FEAT);

    // ===== 0. conversions =====
    hipLaunchKernelGGL(convT_pad, dim3(cdiv(FEAT*KP,256)), dim3(256), 0, stream, Wq, WqTH, WqTL, FEAT, FEAT, KP);
    hipLaunchKernelGGL(convT_pad, dim3(cdiv(FEAT*KP,256)), dim3(256), 0, stream, Wk, WkTH, WkTL, FEAT, FEAT, KP);
    hipLaunchKernelGGL(convT_pad, dim3(cdiv(FEAT*KP,256)), dim3(256), 0, stream, Wv, WvTH, WvTL, FEAT, FEAT, KP);
    hipLaunchKernelGGL(convT_pad, dim3(cdiv(FEAT*KP,256)), dim3(256), 0, stream, Wf, WfTH, WfTL, FEAT, FEAT, KP);
    hipLaunchKernelGGL(convT_pad, dim3(cdiv(HC1*KP,256)),  dim3(256), 0, stream, W1, W1TH, W1TL, FEAT, HC1, KP);
    hipLaunchKernelGGL(conv_pad,  dim3(cdiv(BP*KP,256)),   dim3(256), 0, stream, fsub, fsubH, fsubL, BP, FEAT, KP);
    hipLaunchKernelGGL(conv_pad,  dim3(cdiv(BP*KP,256)),   dim3(256), 0, stream, fcom, fcomH, fcomL, BP, FEAT, KP);
    hipLaunchKernelGGL(fill_f32, dim3(cdiv(10485760/4,256)), dim3(256), 0, stream, (float*)qH, 0.f, (long)(10485760/4));

    // ===== 1. cross attention =====
    hipLaunchKernelGGL((gemm_bf<1>), dim3(cdiv(FEAT,64), cdiv(BP,64)), dim3(256), 0, stream,
                       fsubH, fsubL, KP, WqTH, WqTL, KP, bq, nullptr, nullptr, qH, qL,
                       BP, FEAT, FEAT, 1.0f, 0, KP);
    hipLaunchKernelGGL((gemm_bf<1>), dim3(cdiv(FEAT,64), cdiv(BP,64)), dim3(256), 0, stream,
                       fcomH, fcomL, KP, WkTH, WkTL, KP, bk, nullptr, nullptr, kH, kL,
                       BP, FEAT, FEAT, 1.0f, 0, KP);
    hipLaunchKernelGGL((gemm_bf<2>), dim3(cdiv(FEAT,64), cdiv(BP,64)), dim3(256), 0, stream,
                       fcomH, fcomL, KP, WvTH, WvTL, KP, bv, nullptr, nullptr, vTH, vTL,
                       BP, FEAT, FEAT, 1.0f, 0, BP);
    hipLaunchKernelGGL((gemm_bf<0>), dim3(cdiv(BP,64), cdiv(BP,64)), dim3(256), 0, stream,
                       qH, qL, KP, kH, kL, KP, nullptr, nullptr, S, nullptr, nullptr,
                       BP, BP, FEAT, inv_sqrt_d, 0, BP);
    hipLaunchKernelGGL(softmax_hl, dim3(BP), dim3(256), 0, stream, S, SH, SL);
    hipLaunchKernelGGL((gemm_bf<3>), dim3(cdiv(FEAT,64), cdiv(BP,64), 8), dim3(256), 0, stream,
                       SH, SL, BP, vTH, vTL, BP, nullptr, nullptr, part, nullptr, nullptr,
                       BP, FEAT, BP, 1.0f, 512, 0);
    hipLaunchKernelGGL(splitk_reduce_hl, dim3(cdiv(BP*KP,256)), dim3(256), 0, stream,
                       part, fsub, attnH, attnL, BP, FEAT, KP, 8);
    hipLaunchKernelGGL((gemm_bf<0>), dim3(cdiv(FEAT,64), cdiv(BP,64)), dim3(256), 0, stream,
                       attnH, attnL, KP, WfTH, WfTL, KP, bf, nullptr, fus, nullptr, nullptr,
                       BP, FEAT, FEAT, 1.0f, 0, FEAT);

    // ===== 2. scatter fused into x =====
    hipLaunchKernelGGL(scatter_init, dim3(cdiv(BP,256)), dim3(256), 0, stream, last, com, BP);
    hipLaunchKernelGGL(scatter_max,  dim3(cdiv(BP,256)), dim3(256), 0, stream, last, com, BP);
    hipLaunchKernelGGL(scatter_write, dim3(BP), dim3(128), 0, stream, last, com, fus, x, BP, FEAT);

    // ===== 3. convert x, CSR build =====
    hipLaunchKernelGGL(conv_pad, dim3(cdiv((long)NN*KP,256)), dim3(256), 0, stream, x, xH, xL, NN, FEAT, KP);
    hipLaunchKernelGGL(deg_init,  dim3(cdiv(NN,256)), dim3(256), 0, stream, deg, NN);
    hipLaunchKernelGGL(deg_count, dim3(cdiv(NE,256)), dim3(256), 0, stream, dst, deg, NE);
    {
        int nb = cdiv(NN, 256);   // 196
        hipLaunchKernelGGL(scan_part,  dim3(nb), dim3(256), 0, stream, deg, bsum, NN);
        hipLaunchKernelGGL(scan_bsum,  dim3(1),  dim3(256), 0, stream, bsum, nb);
        hipLaunchKernelGGL(scan_final, dim3(nb), dim3(256), 0, stream, deg, bsum, rowp, NN);
    }
    hipLaunchKernelGGL(copy_i32, dim3(cdiv(NN,256)), dim3(256), 0, stream, rowp, curs, NN);
    hipLaunchKernelGGL(csr_fill, dim3(cdiv(NE,256)), dim3(256), 0, stream, src, dst, curs, csrc, NE);
    hipLaunchKernelGGL(csr_fill_loops, dim3(cdiv(NN,256)), dim3(256), 0, stream, curs, csrc, NN);

    // ===== 4. GAT layer 1 =====
    hipLaunchKernelGGL(gemm_wide, dim3(cdiv(NN,64)), dim3(256), 0, stream,
                       xH, xL, KP, W1TH, W1TL, KP, h1, NN, FEAT);
    hipLaunchKernelGGL(node_attn_coef, dim3(cdiv(NN*HEADS,256)), dim3(256), 0, stream,
                       h1, as1, ad1, es1, ed1, NN, HEADS, HID);
    hipLaunchKernelGGL((csr_maxden_alpha<HEADS>), dim3(cdiv(NN*HEADS,256)), dim3(256), 0, stream,
                       rowp, csrc, es1, ed1, alpha1, NN);
    hipLaunchKernelGGL(csr_agg1_fused, dim3(NN), dim3(128), 0, stream,
                       rowp, csrc, (const float4*)alpha1, h1, b1, W2, h2, NN);

    // ===== 5. GAT layer 2 =====
    hipLaunchKernelGGL(node_attn_coef, dim3(cdiv(NN,256)), dim3(256), 0, stream,
                       h2, as2, ad2, es2, ed2, NN, 1, OUTC);
    hipLaunchKernelGGL((csr_maxden_alpha<1>), dim3(cdiv(NN,256)), dim3(256), 0, stream,
                       rowp, csrc, es2, ed2, alpha2, NN);
    hipLaunchKernelGGL(csr_agg2, dim3(cdiv(NN*OUTC,256)), dim3(256), 0, stream,
                       rowp, csrc, alpha2, h2, b2, embp, NN);

    // ===== 6. pair scores =====
    hipLaunchKernelGGL(pair_score, dim3(cdiv(NP,256)), dim3(256), 0, stream, pidx, embp, out, NP);
}

// Round 9
// 974.231 us; speedup vs baseline: 1.8034x; 1.0250x over previous
//
#include <hip/hip_runtime.h>
#include <math.h>

#define NN      50000      // N_NODES
#define BP      4096       // N_PAIRS_MAP
#define NE      500000     // N_EDGES
#define NP      1000000    // N_SCORE_PAIRS
#define FEAT    300
#define KP      320        // FEAT padded to multiple of 32
#define HID     128
#define HEADS   3
#define OUTC    10
#define HC1     (HEADS*HID)   // 384
#define NEG_SLOPE 0.2f

static inline int cdiv(int a, int b) { return (a + b - 1) / b; }

using bfrag = __attribute__((ext_vector_type(8))) short;
using ffrag = __attribute__((ext_vector_type(4))) float;

__device__ inline float leaky(float x) { return x > 0.f ? x : NEG_SLOPE * x; }
__device__ inline unsigned short bf16_rne(float f) {
    unsigned u = __float_as_uint(f);
    unsigned r = u + 0x7FFFu + ((u >> 16) & 1u);
    return (unsigned short)(r >> 16);
}
__device__ inline float bf16f(unsigned short h) { return __uint_as_float(((unsigned)h) << 16); }

__global__ void fill_f32(float* p, float v, long n) {
    long i = (long)blockIdx.x * blockDim.x + threadIdx.x;
    if (i < n) p[i] = v;
}

// fp32 [M][K] -> bf16 hi/lo [M][Kp], zero-padded k tail
__global__ void conv_pad(const float* __restrict__ in, unsigned short* __restrict__ H,
                         unsigned short* __restrict__ L, long M, int K, int Kp) {
    long idx = (long)blockIdx.x * blockDim.x + threadIdx.x;
    long total = M * Kp;
    if (idx >= total) return;
    int k = (int)(idx % Kp);
    long row = idx / Kp;
    float f = (k < K) ? in[row * K + k] : 0.f;
    unsigned short h = bf16_rne(f);
    H[idx] = h;
    L[idx] = bf16_rne(f - bf16f(h));
}
// fp32 [K][N] row-major -> bf16 hi/lo [N][Kp] (transposed, padded)
__global__ void convT_pad(const float* __restrict__ in, unsigned short* __restrict__ H,
                          unsigned short* __restrict__ L, int K, int N, int Kp) {
    long idx = (long)blockIdx.x * blockDim.x + threadIdx.x;
    long total = (long)N * Kp;
    if (idx >= total) return;
    int k = (int)(idx % Kp);
    long n = idx / Kp;
    float f = (k < K) ? in[(long)k * N + n] : 0.f;
    unsigned short h = bf16_rne(f);
    H[idx] = h;
    L[idx] = bf16_rne(f - bf16f(h));
}

// ================== split-bf16 MFMA GEMM (64x64 tile) ==================
// MODE: 0 = fp32 out (scale, bias?, addsrc?), 1 = bf16 hi/lo out (+bias),
//       2 = transposed bf16 hi/lo out (+bias)
template <int MODE>
__global__ __launch_bounds__(256) void gemm_bf(
    const unsigned short* __restrict__ Ah, const unsigned short* __restrict__ Al, int lda,
    const unsigned short* __restrict__ Bh, const unsigned short* __restrict__ Bl, int ldb,
    const float* __restrict__ bias, const float* __restrict__ addsrc,
    float* __restrict__ C0, unsigned short* __restrict__ H0, unsigned short* __restrict__ L0,
    int M, int N, int K, float scale, int ldo)
{
    __shared__ __align__(16) unsigned short Ahs[4][64][8], Als[4][64][8];
    __shared__ __align__(16) unsigned short Bhs[4][64][8], Bls[4][64][8];
    int t = threadIdx.x, w = t >> 6, l = t & 63, lrow = l & 15, lq = l >> 4;
    int rowBase = blockIdx.y * 64, colBase = blockIdx.x * 64;
    int Kr = (K + 31) & ~31;

    int arow = min(rowBase + l, M - 1);
    int brow = min(colBase + l, N - 1);
    const unsigned short* ga_h = Ah + (long)arow * lda + w * 8;
    const unsigned short* ga_l = Al + (long)arow * lda + w * 8;
    const unsigned short* gb_h = Bh + (long)brow * ldb + w * 8;
    const unsigned short* gb_l = Bl + (long)brow * ldb + w * 8;

    ffrag acc[4] = {{0.f,0.f,0.f,0.f},{0.f,0.f,0.f,0.f},{0.f,0.f,0.f,0.f},{0.f,0.f,0.f,0.f}};

    for (int k0 = 0; k0 < Kr; k0 += 32) {
        *(uint4*)&Ahs[w][l][0] = *(const uint4*)(ga_h + k0);
        *(uint4*)&Als[w][l][0] = *(const uint4*)(ga_l + k0);
        *(uint4*)&Bhs[w][l][0] = *(const uint4*)(gb_h + k0);
        *(uint4*)&Bls[w][l][0] = *(const uint4*)(gb_l + k0);
        __syncthreads();
        bfrag ah  = *(const bfrag*)&Ahs[lq][w * 16 + lrow][0];
        bfrag alo = *(const bfrag*)&Als[lq][w * 16 + lrow][0];
#pragma unroll
        for (int ct = 0; ct < 4; ct++) {
            bfrag bh = *(const bfrag*)&Bhs[lq][ct * 16 + lrow][0];
            bfrag bl = *(const bfrag*)&Bls[lq][ct * 16 + lrow][0];
            acc[ct] = __builtin_amdgcn_mfma_f32_16x16x32_bf16(ah,  bh, acc[ct], 0, 0, 0);
            acc[ct] = __builtin_amdgcn_mfma_f32_16x16x32_bf16(ah,  bl, acc[ct], 0, 0, 0);
            acc[ct] = __builtin_amdgcn_mfma_f32_16x16x32_bf16(alo, bh, acc[ct], 0, 0, 0);
        }
        __syncthreads();
    }

#pragma unroll
    for (int ct = 0; ct < 4; ct++) {
        int gc = colBase + ct * 16 + lrow;
        if (gc >= N) continue;
#pragma unroll
        for (int r = 0; r < 4; r++) {
            int gr = rowBase + w * 16 + lq * 4 + r;
            if (gr >= M) continue;
            float v = acc[ct][r];
            if (MODE == 0) {
                float o = v * scale;
                if (bias) o += bias[gc];
                if (addsrc) o += addsrc[(long)gr * ldo + gc];
                C0[(long)gr * ldo + gc] = o;
            } else if (MODE == 1) {
                float o = v + bias[gc];
                unsigned short h = bf16_rne(o);
                H0[(long)gr * ldo + gc] = h;
                L0[(long)gr * ldo + gc] = bf16_rne(o - bf16f(h));
            } else {
                float o = v + bias[gc];
                unsigned short h = bf16_rne(o);
                H0[(long)gc * ldo + gr] = h;
                L0[(long)gc * ldo + gr] = bf16_rne(o - bf16f(h));
            }
        }
    }
}

// ================== wide GEMM: 64 rows x WCT*16 cols per block ==================
// A fetched exactly once from HBM. SPLITK: blockIdx.y = z chunk, partials out.
template <int WCT, bool SPLITK>
__global__ __launch_bounds__(256) void gemm_wide(
    const unsigned short* __restrict__ Ah, const unsigned short* __restrict__ Al, int lda,
    const unsigned short* __restrict__ Bh, const unsigned short* __restrict__ Bl, int ldb,
    float* __restrict__ C0, int M, int N, int K, int KC)
{
    __shared__ __align__(16) unsigned short Ahs[4][64][8], Als[4][64][8];
    __shared__ __align__(16) unsigned short Bhs[4][WCT * 16][8], Bls[4][WCT * 16][8];
    int t = threadIdx.x, w = t >> 6, l = t & 63, lrow = l & 15, lq = l >> 4;
    int rowBase = blockIdx.x * 64;
    int Kr = (K + 31) & ~31;
    int kbeg = SPLITK ? blockIdx.y * KC : 0;
    int kend = SPLITK ? min(Kr, kbeg + KC) : Kr;

    int arow = min(rowBase + l, M - 1);
    const unsigned short* ga_h = Ah + (long)arow * lda + w * 8;
    const unsigned short* ga_l = Al + (long)arow * lda + w * 8;
    int bcol0 = t >> 2, bq = t & 3;

    ffrag acc[WCT];
#pragma unroll
    for (int i = 0; i < WCT; i++) acc[i] = ffrag{0.f, 0.f, 0.f, 0.f};

    for (int k0 = kbeg; k0 < kend; k0 += 32) {
        *(uint4*)&Ahs[w][l][0] = *(const uint4*)(ga_h + k0);
        *(uint4*)&Als[w][l][0] = *(const uint4*)(ga_l + k0);
#pragma unroll
        for (int i = 0; i < WCT * 16 / 64; i++) {
            int col = bcol0 + 64 * i;
            int bc = min(col, N - 1);
            const unsigned short* gb_h = Bh + (long)bc * ldb + bq * 8 + k0;
            const unsigned short* gb_l = Bl + (long)bc * ldb + bq * 8 + k0;
            *(uint4*)&Bhs[bq][col][0] = *(const uint4*)gb_h;
            *(uint4*)&Bls[bq][col][0] = *(const uint4*)gb_l;
        }
        __syncthreads();
        bfrag ah  = *(const bfrag*)&Ahs[lq][w * 16 + lrow][0];
        bfrag alo = *(const bfrag*)&Als[lq][w * 16 + lrow][0];
#pragma unroll
        for (int ct = 0; ct < WCT; ct++) {
            bfrag bh = *(const bfrag*)&Bhs[lq][ct * 16 + lrow][0];
            bfrag bl = *(const bfrag*)&Bls[lq][ct * 16 + lrow][0];
            acc[ct] = __builtin_amdgcn_mfma_f32_16x16x32_bf16(ah,  bh, acc[ct], 0, 0, 0);
            acc[ct] = __builtin_amdgcn_mfma_f32_16x16x32_bf16(ah,  bl, acc[ct], 0, 0, 0);
            acc[ct] = __builtin_amdgcn_mfma_f32_16x16x32_bf16(alo, bh, acc[ct], 0, 0, 0);
        }
        __syncthreads();
    }

    float* Cz = SPLITK ? (C0 + (long)blockIdx.y * M * N) : C0;
#pragma unroll
    for (int ct = 0; ct < WCT; ct++) {
        int gc = ct * 16 + lrow;
        if (gc >= N) continue;
#pragma unroll
        for (int r = 0; r < 4; r++) {
            int gr = rowBase + w * 16 + lq * 4 + r;
            if (gr >= M) continue;
            Cz[(long)gr * N + gc] = acc[ct][r];
        }
    }
}

// ---------- softmax rows of S -> bf16 hi/lo ----------
__global__ __launch_bounds__(256) void softmax_hl(const float* __restrict__ S,
                                                  unsigned short* __restrict__ SH,
                                                  unsigned short* __restrict__ SL) {
    int row = blockIdx.x, tid = threadIdx.x;
    const float* p = S + (long)row * BP;
    float ev[16];
    __shared__ float red[256];
    float m = -1e30f;
#pragma unroll
    for (int i = 0; i < 16; i++) { float v = p[tid + i * 256]; ev[i] = v; m = fmaxf(m, v); }
    red[tid] = m; __syncthreads();
    for (int s = 128; s > 0; s >>= 1) { if (tid < s) red[tid] = fmaxf(red[tid], red[tid + s]); __syncthreads(); }
    m = red[0]; __syncthreads();
    float sum = 0.f;
#pragma unroll
    for (int i = 0; i < 16; i++) { float e = expf(ev[i] - m); ev[i] = e; sum += e; }
    red[tid] = sum; __syncthreads();
    for (int s = 128; s > 0; s >>= 1) { if (tid < s) red[tid] += red[tid + s]; __syncthreads(); }
    float inv = 1.0f / red[0];
#pragma unroll
    for (int i = 0; i < 16; i++) {
        float e = ev[i] * inv;
        unsigned short h = bf16_rne(e);
        long o = (long)row * BP + tid + i * 256;
        SH[o] = h;
        SL[o] = bf16_rne(e - bf16f(h));
    }
}

// ---------- split-K reduce + residual -> attn bf16 hi/lo ----------
__global__ void splitk_reduce_hl(const float* __restrict__ part, const float* __restrict__ resid,
                                 unsigned short* __restrict__ H, unsigned short* __restrict__ L,
                                 int Mr, int Nc, int Kp2, int sk) {
    long idx = (long)blockIdx.x * blockDim.x + threadIdx.x;
    long total = (long)Mr * Kp2;
    if (idx >= total) return;
    int c = (int)(idx % Kp2);
    long row = idx / Kp2;
    float s = 0.f;
    if (c < Nc) {
        long base = row * Nc + c;
        for (int z = 0; z < sk; z++) s += part[(long)z * Mr * Nc + base];
        s += resid[base];
    }
    unsigned short h = bf16_rne(s);
    H[idx] = h;
    L[idx] = bf16_rne(s - bf16f(h));
}

// ---------- scatter (last write wins) ----------
__global__ void scatter_init(int* last, const int* __restrict__ com, int B) {
    int i = blockIdx.x * blockDim.x + threadIdx.x;
    if (i < B) last[com[i]] = -1;
}
__global__ void scatter_max(int* last, const int* __restrict__ com, int B) {
    int i = blockIdx.x * blockDim.x + threadIdx.x;
    if (i < B) atomicMax(&last[com[i]], i);
}
__global__ void scatter_write(const int* __restrict__ last, const int* __restrict__ com,
                              const float* __restrict__ fused, float* __restrict__ x, int B, int D) {
    int i = blockIdx.x;
    int node = com[i];
    if (last[node] != i) return;
    for (int c = threadIdx.x; c < D; c += blockDim.x)
        x[(long)node * D + c] = fused[(long)i * D + c];
}

// ---------- GAT per-node attention coefficients ----------
__global__ void node_attn_coef(const float* __restrict__ h, const float* __restrict__ a_src,
                               const float* __restrict__ a_dst, float* __restrict__ es,
                               float* __restrict__ ed, int N, int H, int C) {
    int idx = blockIdx.x * blockDim.x + threadIdx.x;
    if (idx >= N * H) return;
    int n = idx / H, hh = idx % H;
    const float* hp = h + (long)n * H * C + (long)hh * C;
    const float* as = a_src + hh * C;
    const float* ad = a_dst + hh * C;
    float s = 0.f, d = 0.f;
    for (int c = 0; c < C; c++) { float v = hp[c]; s += v * as[c]; d += v * ad[c]; }
    es[idx] = s; ed[idx] = d;
}

// ================== CSR build ==================
__global__ void deg_init(int* deg, int n) {
    int i = blockIdx.x * blockDim.x + threadIdx.x;
    if (i < n) deg[i] = 1;
}
__global__ void deg_count(const int* __restrict__ dst, int* deg, int E) {
    int e = blockIdx.x * blockDim.x + threadIdx.x;
    if (e < E) atomicAdd(&deg[dst[e]], 1);
}
__global__ void scan_part(const int* __restrict__ deg, int* __restrict__ bsum, int n) {
    __shared__ int red[256];
    int tid = threadIdx.x;
    int i = blockIdx.x * 256 + tid;
    red[tid] = (i < n) ? deg[i] : 0;
    __syncthreads();
    for (int s = 128; s > 0; s >>= 1) { if (tid < s) red[tid] += red[tid + s]; __syncthreads(); }
    if (tid == 0) bsum[blockIdx.x] = red[0];
}
__global__ __launch_bounds__(256) void scan_bsum(int* __restrict__ bsum, int nb) {
    __shared__ int tmp[256];
    int tid = threadIdx.x;
    int v = (tid < nb) ? bsum[tid] : 0;
    tmp[tid] = v; __syncthreads();
    for (int off = 1; off < 256; off <<= 1) {
        int t2 = (tid >= off) ? tmp[tid - off] : 0;
        __syncthreads();
        tmp[tid] += t2;
        __syncthreads();
    }
    if (tid < nb) bsum[tid] = tmp[tid];
}
__global__ void scan_final(const int* __restrict__ deg, const int* __restrict__ bsum,
                           int* __restrict__ rowptr, int n) {
    __shared__ int tmp[256];
    int tid = threadIdx.x;
    int b = blockIdx.x;
    int i = b * 256 + tid;
    int v = (i < n) ? deg[i] : 0;
    tmp[tid] = v; __syncthreads();
    for (int off = 1; off < 256; off <<= 1) {
        int t2 = (tid >= off) ? tmp[tid - off] : 0;
        __syncthreads();
        tmp[tid] += t2;
        __syncthreads();
    }
    int base = (b > 0) ? bsum[b - 1] : 0;
    if (i < n) rowptr[i + 1] = base + tmp[tid];
    if (b == 0 && tid == 0) rowptr[0] = 0;
}
__global__ void copy_i32(const int* __restrict__ a, int* __restrict__ b, int n) {
    int i = blockIdx.x * blockDim.x + threadIdx.x;
    if (i < n) b[i] = a[i];
}
__global__ void csr_fill(const int* __restrict__ src, const int* __restrict__ dst,
                         int* cursor, int* __restrict__ csr_src, int E) {
    int e = blockIdx.x * blockDim.x + threadIdx.x;
    if (e >= E) return;
    int slot = atomicAdd(&cursor[dst[e]], 1);
    csr_src[slot] = src[e];
}
__global__ void csr_fill_loops(int* cursor, int* __restrict__ csr_src, int n) {
    int i = blockIdx.x * blockDim.x + threadIdx.x;
    if (i >= n) return;
    int slot = atomicAdd(&cursor[i], 1);
    csr_src[slot] = i;
}

// ---------- segment max + denom + per-slot alpha ----------
template <int H>
__global__ void csr_maxden_alpha(const int* __restrict__ rowptr, const int* __restrict__ csr_src,
                                 const float* __restrict__ es, const float* __restrict__ ed,
                                 float* __restrict__ alpha, int N) {
    int idx = blockIdx.x * blockDim.x + threadIdx.x;
    if (idx >= N * H) return;
    int d = idx / H, h = idx - d * H;
    float edv = ed[idx];
    int b = rowptr[d], e = rowptr[d + 1];
    float mm = -1e30f;
    for (int s0 = b; s0 < e; s0++) {
        int s = csr_src[s0];
        mm = fmaxf(mm, leaky(es[s * H + h] + edv));
    }
    float dn = 0.f;
    for (int s0 = b; s0 < e; s0++) {
        int s = csr_src[s0];
        dn += expf(leaky(es[s * H + h] + edv) - mm);
    }
    float inv = 1.f / (dn + 1e-16f);
    for (int s0 = b; s0 < e; s0++) {
        int s = csr_src[s0];
        float al = expf(leaky(es[s * H + h] + edv) - mm) * inv;
        if (H == 3) alpha[(long)s0 * 4 + h] = al;
        else        alpha[s0] = al;
    }
}

// ---------- layer-1 aggregate + bias + ELU + (row @ W2) ----------
__global__ __launch_bounds__(128) void csr_agg1_fused(
    const int* __restrict__ rowptr, const int* __restrict__ csr_src,
    const float4* __restrict__ alpha,
    const float* __restrict__ h1, const float* __restrict__ b1,
    const float* __restrict__ W2, float* __restrict__ h2, int N)
{
    int d = blockIdx.x;
    int t = threadIdx.x;
    __shared__ float row[HC1];
    __shared__ float part[128][OUTC + 1];

    int b = rowptr[d], e = rowptr[d + 1];
    float a0 = 0.f, a1 = 0.f, a2 = 0.f;
    for (int s0 = b; s0 < e; s0++) {
        int s = csr_src[s0];
        float4 al = alpha[s0];
        const float* hp = h1 + (long)s * HC1;
        a0 = fmaf(hp[t],       al.x, a0);
        a1 = fmaf(hp[t + 128], al.y, a1);
        a2 = fmaf(hp[t + 256], al.z, a2);
    }
    float v;
    v = a0 + b1[t];       row[t]       = v > 0.f ? v : expf(v) - 1.f;
    v = a1 + b1[t + 128]; row[t + 128] = v > 0.f ? v : expf(v) - 1.f;
    v = a2 + b1[t + 256]; row[t + 256] = v > 0.f ? v : expf(v) - 1.f;
    __syncthreads();

    float pc[OUTC];
#pragma unroll
    for (int c = 0; c < OUTC; c++) pc[c] = 0.f;
    for (int k = t; k < HC1; k += 128) {
        float rv = row[k];
        const float* wp = W2 + (long)k * OUTC;
#pragma unroll
        for (int c = 0; c < OUTC; c++) pc[c] = fmaf(rv, wp[c], pc[c]);
    }
#pragma unroll
    for (int c = 0; c < OUTC; c++) part[t][c] = pc[c];
    __syncthreads();
    for (int off = 64; off > 0; off >>= 1) {
        if (t < off) {
#pragma unroll
            for (int c = 0; c < OUTC; c++) part[t][c] += part[t + off][c];
        }
        __syncthreads();
    }
    if (t < OUTC) h2[(long)d * OUTC + t] = part[0][t];
}

// ---------- layer-2 aggregate + bias ----------
__global__ void csr_agg2(const int* __restrict__ rowptr, const int* __restrict__ csr_src,
                         const float* __restrict__ alpha,
                         const float* __restrict__ h2, const float* __restrict__ b2,
                         float* __restrict__ emb, int N)
{
    int idx = blockIdx.x * blockDim.x + threadIdx.x;
    if (idx >= N * OUTC) return;
    int d = idx / OUTC, c = idx - d * OUTC;
    int b = rowptr[d], e = rowptr[d + 1];
    float acc = 0.f;
    for (int s0 = b; s0 < e; s0++) {
        int s = csr_src[s0];
        acc = fmaf(h2[(long)s * OUTC + c], alpha[s0], acc);
    }
    emb[idx] = acc + b2[c];
}

// ---------- pair scores ----------
__global__ void pair_score(const int* __restrict__ pairs, const float* __restrict__ emb,
                           float* __restrict__ out, int P) {
    int p = blockIdx.x * blockDim.x + threadIdx.x;
    if (p >= P) return;
    int i0 = pairs[2 * p], i1 = pairs[2 * p + 1];
    const float* a = emb + (long)i0 * OUTC;
    const float* b = emb + (long)i1 * OUTC;
    float s = 0.f;
#pragma unroll
    for (int c = 0; c < OUTC; c++) s += a[c] * b[c];
    out[p] = s;
}

extern "C" void kernel_launch(void* const* d_in, const int* in_sizes, int n_in,
                              void* d_out, int out_size, void* d_ws, size_t ws_size,
                              hipStream_t stream) {
    const float* fsub = (const float*)d_in[0];
    const float* fcom = (const float*)d_in[1];
    float*       x    = (float*)d_in[2];
    const int*   com  = (const int*)d_in[3];
    const int*   ei   = (const int*)d_in[4];
    const int*   pidx = (const int*)d_in[5];
    const float* Wq = (const float*)d_in[6];  const float* bq = (const float*)d_in[7];
    const float* Wk = (const float*)d_in[8];  const float* bk = (const float*)d_in[9];
    const float* Wv = (const float*)d_in[10]; const float* bv = (const float*)d_in[11];
    const float* Wf = (const float*)d_in[12]; const float* bf = (const float*)d_in[13];
    const float* W1 = (const float*)d_in[14];
    const float* as1 = (const float*)d_in[15]; const float* ad1 = (const float*)d_in[16];
    const float* b1 = (const float*)d_in[17];
    const float* W2 = (const float*)d_in[18];
    const float* as2 = (const float*)d_in[19]; const float* ad2 = (const float*)d_in[20];
    const float* b2 = (const float*)d_in[21];
    float* out = (float*)d_out;

    const int* src = ei;
    const int* dst = ei + NE;

    typedef unsigned short u16;
    char* ws = (char*)d_ws;
    float* S     = (float*)(ws + 0);            // dead after softmax
    u16*   SH    = (u16*)(ws + 67108864);       // dead after S@v
    u16*   SL    = (u16*)(ws + 100663296);
    u16*   fsubH = (u16*)(ws + 134217728);      // dead after q proj
    u16*   fsubL = (u16*)(ws + 136839168);
    u16*   fcomH = (u16*)(ws + 139460608);      // dead after k,v proj
    u16*   fcomL = (u16*)(ws + 142082048);
    u16*   qH    = (u16*)(ws + 144703488);      // dead after S gemm
    u16*   qL    = (u16*)(ws + 147324928);
    u16*   kH    = (u16*)(ws + 149946368);
    u16*   kL    = (u16*)(ws + 152567808);
    u16*   vTH   = (u16*)(ws + 155189248);      // dead after S@v
    u16*   vTL   = (u16*)(ws + 157646848);
    u16*   attnH = (u16*)(ws + 160104448);      // dead after fus gemm
    u16*   attnL = (u16*)(ws + 162725888);
    u16*   WqTH  = (u16*)(ws + 165347328);
    u16*   WqTL  = (u16*)(ws + 165539328);
    u16*   WkTH  = (u16*)(ws + 165731328);
    u16*   WkTL  = (u16*)(ws + 165923328);
    u16*   WvTH  = (u16*)(ws + 166115328);
    u16*   WvTL  = (u16*)(ws + 166307328);
    u16*   WfTH  = (u16*)(ws + 166499328);
    u16*   WfTL  = (u16*)(ws + 166691328);
    u16*   W1TH  = (u16*)(ws + 166883328);
    u16*   W1TL  = (u16*)(ws + 167129088);
    float* fus   = (float*)(ws + 167374848);    // alive until scatter
    float* es1   = (float*)(ws + 172290048);
    float* ed1   = (float*)(ws + 172890048);
    float* es2   = (float*)(ws + 174690048);
    float* ed2   = (float*)(ws + 174890048);
    float* h2    = (float*)(ws + 175490048);
    float* embp  = (float*)(ws + 177490048);
    int*   last  = (int*)(ws + 179490048);
    int*   deg   = (int*)(ws + 179690048);
    int*   curs  = (int*)(ws + 179890048);
    int*   rowp  = (int*)(ws + 180090048);
    int*   csrc  = (int*)(ws + 180290064);      // ends 182,490,064
    int*   bsum  = (int*)(ws + 182490112);      // 196 ints
    // overlays (disjoint in time):
    float* part   = (float*)(ws + 0);           // over dead S (S@v phase)
    float* h1     = (float*)(ws + 0);           // over dead S/SH (GAT phase)
    u16*   xH     = (u16*)(ws + 76800000);      // over dead SH/SL
    u16*   xL     = (u16*)(ws + 108800000);
    float* alpha1 = (float*)(ws + 134217728);   // over dead fsubH/L/fcomH (GAT phase)
    float* alpha2 = (float*)(ws + 144703488);   // over dead qH (GAT phase)

    const float inv_sqrt_d = 1.0f / sqrtf((float)FEAT);

    // ===== 0. conversions =====
    hipLaunchKernelGGL(convT_pad, dim3(cdiv(FEAT*KP,256)), dim3(256), 0, stream, Wq, WqTH, WqTL, FEAT, FEAT, KP);
    hipLaunchKernelGGL(convT_pad, dim3(cdiv(FEAT*KP,256)), dim3(256), 0, stream, Wk, WkTH, WkTL, FEAT, FEAT, KP);
    hipLaunchKernelGGL(convT_pad, dim3(cdiv(FEAT*KP,256)), dim3(256), 0, stream, Wv, WvTH, WvTL, FEAT, FEAT, KP);
    hipLaunchKernelGGL(convT_pad, dim3(cdiv(FEAT*KP,256)), dim3(256), 0, stream, Wf, WfTH, WfTL, FEAT, FEAT, KP);
    hipLaunchKernelGGL(convT_pad, dim3(cdiv(HC1*KP,256)),  dim3(256), 0, stream, W1, W1TH, W1TL, FEAT, HC1, KP);
    hipLaunchKernelGGL(conv_pad,  dim3(cdiv(BP*KP,256)),   dim3(256), 0, stream, fsub, fsubH, fsubL, BP, FEAT, KP);
    hipLaunchKernelGGL(conv_pad,  dim3(cdiv(BP*KP,256)),   dim3(256), 0, stream, fcom, fcomH, fcomL, BP, FEAT, KP);
    hipLaunchKernelGGL(fill_f32, dim3(cdiv(10485760/4,256)), dim3(256), 0, stream, (float*)qH, 0.f, (long)(10485760/4));

    // ===== 1. cross attention =====
    hipLaunchKernelGGL((gemm_bf<1>), dim3(cdiv(FEAT,64), cdiv(BP,64)), dim3(256), 0, stream,
                       fsubH, fsubL, KP, WqTH, WqTL, KP, bq, nullptr, nullptr, qH, qL,
                       BP, FEAT, FEAT, 1.0f, KP);
    hipLaunchKernelGGL((gemm_bf<1>), dim3(cdiv(FEAT,64), cdiv(BP,64)), dim3(256), 0, stream,
                       fcomH, fcomL, KP, WkTH, WkTL, KP, bk, nullptr, nullptr, kH, kL,
                       BP, FEAT, FEAT, 1.0f, KP);
    hipLaunchKernelGGL((gemm_bf<2>), dim3(cdiv(FEAT,64), cdiv(BP,64)), dim3(256), 0, stream,
                       fcomH, fcomL, KP, WvTH, WvTL, KP, bv, nullptr, nullptr, vTH, vTL,
                       BP, FEAT, FEAT, 1.0f, BP);
    hipLaunchKernelGGL((gemm_bf<0>), dim3(cdiv(BP,64), cdiv(BP,64)), dim3(256), 0, stream,
                       qH, qL, KP, kH, kL, KP, nullptr, nullptr, S, nullptr, nullptr,
                       BP, BP, FEAT, inv_sqrt_d, BP);
    hipLaunchKernelGGL(softmax_hl, dim3(BP), dim3(256), 0, stream, S, SH, SL);
    // part[z] = S_z @ v  — wide-N split-K: S fetched exactly once
    hipLaunchKernelGGL((gemm_wide<20, true>), dim3(cdiv(BP,64), 8), dim3(256), 0, stream,
                       SH, SL, BP, vTH, vTL, BP, part, BP, FEAT, BP, 512);
    hipLaunchKernelGGL(splitk_reduce_hl, dim3(cdiv(BP*KP,256)), dim3(256), 0, stream,
                       part, fsub, attnH, attnL, BP, FEAT, KP, 8);
    hipLaunchKernelGGL((gemm_bf<0>), dim3(cdiv(FEAT,64), cdiv(BP,64)), dim3(256), 0, stream,
                       attnH, attnL, KP, WfTH, WfTL, KP, bf, nullptr, fus, nullptr, nullptr,
                       BP, FEAT, FEAT, 1.0f, FEAT);

    // ===== 2. scatter fused into x =====
    hipLaunchKernelGGL(scatter_init, dim3(cdiv(BP,256)), dim3(256), 0, stream, last, com, BP);
    hipLaunchKernelGGL(scatter_max,  dim3(cdiv(BP,256)), dim3(256), 0, stream, last, com, BP);
    hipLaunchKernelGGL(scatter_write, dim3(BP), dim3(128), 0, stream, last, com, fus, x, BP, FEAT);

    // ===== 3. convert x, CSR build =====
    hipLaunchKernelGGL(conv_pad, dim3(cdiv((long)NN*KP,256)), dim3(256), 0, stream, x, xH, xL, NN, FEAT, KP);
    hipLaunchKernelGGL(deg_init,  dim3(cdiv(NN,256)), dim3(256), 0, stream, deg, NN);
    hipLaunchKernelGGL(deg_count, dim3(cdiv(NE,256)), dim3(256), 0, stream, dst, deg, NE);
    {
        int nb = cdiv(NN, 256);   // 196
        hipLaunchKernelGGL(scan_part,  dim3(nb), dim3(256), 0, stream, deg, bsum, NN);
        hipLaunchKernelGGL(scan_bsum,  dim3(1),  dim3(256), 0, stream, bsum, nb);
        hipLaunchKernelGGL(scan_final, dim3(nb), dim3(256), 0, stream, deg, bsum, rowp, NN);
    }
    hipLaunchKernelGGL(copy_i32, dim3(cdiv(NN,256)), dim3(256), 0, stream, rowp, curs, NN);
    hipLaunchKernelGGL(csr_fill, dim3(cdiv(NE,256)), dim3(256), 0, stream, src, dst, curs, csrc, NE);
    hipLaunchKernelGGL(csr_fill_loops, dim3(cdiv(NN,256)), dim3(256), 0, stream, curs, csrc, NN);

    // ===== 4. GAT layer 1 =====
    hipLaunchKernelGGL((gemm_wide<24, false>), dim3(cdiv(NN,64), 1), dim3(256), 0, stream,
                       xH, xL, KP, W1TH, W1TL, KP, h1, NN, HC1, FEAT, 0);
    hipLaunchKernelGGL(node_attn_coef, dim3(cdiv(NN*HEADS,256)), dim3(256), 0, stream,
                       h1, as1, ad1, es1, ed1, NN, HEADS, HID);
    hipLaunchKernelGGL((csr_maxden_alpha<HEADS>), dim3(cdiv(NN*HEADS,256)), dim3(256), 0, stream,
                       rowp, csrc, es1, ed1, alpha1, NN);
    hipLaunchKernelGGL(csr_agg1_fused, dim3(NN), dim3(128), 0, stream,
                       rowp, csrc, (const float4*)alpha1, h1, b1, W2, h2, NN);

    // ===== 5. GAT layer 2 =====
    hipLaunchKernelGGL(node_attn_coef, dim3(cdiv(NN,256)), dim3(256), 0, stream,
                       h2, as2, ad2, es2, ed2, NN, 1, OUTC);
    hipLaunchKernelGGL((csr_maxden_alpha<1>), dim3(cdiv(NN,256)), dim3(256), 0, stream,
                       rowp, csrc, es2, ed2, alpha2, NN);
    hipLaunchKernelGGL(csr_agg2, dim3(cdiv(NN*OUTC,256)), dim3(256), 0, stream,
                       rowp, csrc, alpha2, h2, b2, embp, NN);

    // ===== 6. pair scores =====
    hipLaunchKernelGGL(pair_score, dim3(cdiv(NP,256)), dim3(256), 0, stream, pidx, embp, out, NP);
}

// Round 10
// 965.295 us; speedup vs baseline: 1.8201x; 1.0093x over previous
//
#include <hip/hip_runtime.h>
#include <math.h>

#define NN      50000      // N_NODES
#define BP      4096       // N_PAIRS_MAP
#define NE      500000     // N_EDGES
#define NP      1000000    // N_SCORE_PAIRS
#define FEAT    300
#define KP      320        // FEAT padded to multiple of 32
#define HID     128
#define HEADS   3
#define OUTC    10
#define HC1     (HEADS*HID)   // 384
#define NEG_SLOPE 0.2f

static inline int cdiv(int a, int b) { return (a + b - 1) / b; }

using bfrag = __attribute__((ext_vector_type(8))) short;
using ffrag = __attribute__((ext_vector_type(4))) float;

__device__ inline float leaky(float x) { return x > 0.f ? x : NEG_SLOPE * x; }
__device__ inline unsigned short bf16_rne(float f) {
    unsigned u = __float_as_uint(f);
    unsigned r = u + 0x7FFFu + ((u >> 16) & 1u);
    return (unsigned short)(r >> 16);
}
__device__ inline float bf16f(unsigned short h) { return __uint_as_float(((unsigned)h) << 16); }

__global__ void fill_f32(float* p, float v, long n) {
    long i = (long)blockIdx.x * blockDim.x + threadIdx.x;
    if (i < n) p[i] = v;
}

// fp32 [M][K] -> bf16 hi/lo [M][Kp], zero-padded k tail
__global__ void conv_pad(const float* __restrict__ in, unsigned short* __restrict__ H,
                         unsigned short* __restrict__ L, long M, int K, int Kp) {
    long idx = (long)blockIdx.x * blockDim.x + threadIdx.x;
    long total = M * Kp;
    if (idx >= total) return;
    int k = (int)(idx % Kp);
    long row = idx / Kp;
    float f = (k < K) ? in[row * K + k] : 0.f;
    unsigned short h = bf16_rne(f);
    H[idx] = h;
    L[idx] = bf16_rne(f - bf16f(h));
}
// fp32 [K][N] row-major -> bf16 hi/lo [N][Kp] (transposed, padded)
__global__ void convT_pad(const float* __restrict__ in, unsigned short* __restrict__ H,
                          unsigned short* __restrict__ L, int K, int N, int Kp) {
    long idx = (long)blockIdx.x * blockDim.x + threadIdx.x;
    long total = (long)N * Kp;
    if (idx >= total) return;
    int k = (int)(idx % Kp);
    long n = idx / Kp;
    float f = (k < K) ? in[(long)k * N + n] : 0.f;
    unsigned short h = bf16_rne(f);
    H[idx] = h;
    L[idx] = bf16_rne(f - bf16f(h));
}

// ================== split-bf16 MFMA GEMM (64x64 tile) ==================
// MODE: 0 = fp32 out (scale, bias?, addsrc?), 1 = bf16 hi/lo out (+bias),
//       2 = transposed bf16 hi/lo out (+bias)
template <int MODE>
__global__ __launch_bounds__(256) void gemm_bf(
    const unsigned short* __restrict__ Ah, const unsigned short* __restrict__ Al, int lda,
    const unsigned short* __restrict__ Bh, const unsigned short* __restrict__ Bl, int ldb,
    const float* __restrict__ bias, const float* __restrict__ addsrc,
    float* __restrict__ C0, unsigned short* __restrict__ H0, unsigned short* __restrict__ L0,
    int M, int N, int K, float scale, int ldo)
{
    __shared__ __align__(16) unsigned short Ahs[4][64][8], Als[4][64][8];
    __shared__ __align__(16) unsigned short Bhs[4][64][8], Bls[4][64][8];
    int t = threadIdx.x, w = t >> 6, l = t & 63, lrow = l & 15, lq = l >> 4;
    int rowBase = blockIdx.y * 64, colBase = blockIdx.x * 64;
    int Kr = (K + 31) & ~31;

    int arow = min(rowBase + l, M - 1);
    int brow = min(colBase + l, N - 1);
    const unsigned short* ga_h = Ah + (long)arow * lda + w * 8;
    const unsigned short* ga_l = Al + (long)arow * lda + w * 8;
    const unsigned short* gb_h = Bh + (long)brow * ldb + w * 8;
    const unsigned short* gb_l = Bl + (long)brow * ldb + w * 8;

    ffrag acc[4] = {{0.f,0.f,0.f,0.f},{0.f,0.f,0.f,0.f},{0.f,0.f,0.f,0.f},{0.f,0.f,0.f,0.f}};

    for (int k0 = 0; k0 < Kr; k0 += 32) {
        *(uint4*)&Ahs[w][l][0] = *(const uint4*)(ga_h + k0);
        *(uint4*)&Als[w][l][0] = *(const uint4*)(ga_l + k0);
        *(uint4*)&Bhs[w][l][0] = *(const uint4*)(gb_h + k0);
        *(uint4*)&Bls[w][l][0] = *(const uint4*)(gb_l + k0);
        __syncthreads();
        bfrag ah  = *(const bfrag*)&Ahs[lq][w * 16 + lrow][0];
        bfrag alo = *(const bfrag*)&Als[lq][w * 16 + lrow][0];
#pragma unroll
        for (int ct = 0; ct < 4; ct++) {
            bfrag bh = *(const bfrag*)&Bhs[lq][ct * 16 + lrow][0];
            bfrag bl = *(const bfrag*)&Bls[lq][ct * 16 + lrow][0];
            acc[ct] = __builtin_amdgcn_mfma_f32_16x16x32_bf16(ah,  bh, acc[ct], 0, 0, 0);
            acc[ct] = __builtin_amdgcn_mfma_f32_16x16x32_bf16(ah,  bl, acc[ct], 0, 0, 0);
            acc[ct] = __builtin_amdgcn_mfma_f32_16x16x32_bf16(alo, bh, acc[ct], 0, 0, 0);
        }
        __syncthreads();
    }

#pragma unroll
    for (int ct = 0; ct < 4; ct++) {
        int gc = colBase + ct * 16 + lrow;
        if (gc >= N) continue;
#pragma unroll
        for (int r = 0; r < 4; r++) {
            int gr = rowBase + w * 16 + lq * 4 + r;
            if (gr >= M) continue;
            float v = acc[ct][r];
            if (MODE == 0) {
                float o = v * scale;
                if (bias) o += bias[gc];
                if (addsrc) o += addsrc[(long)gr * ldo + gc];
                C0[(long)gr * ldo + gc] = o;
            } else if (MODE == 1) {
                float o = v + bias[gc];
                unsigned short h = bf16_rne(o);
                H0[(long)gr * ldo + gc] = h;
                L0[(long)gr * ldo + gc] = bf16_rne(o - bf16f(h));
            } else {
                float o = v + bias[gc];
                unsigned short h = bf16_rne(o);
                H0[(long)gc * ldo + gr] = h;
                L0[(long)gc * ldo + gr] = bf16_rne(o - bf16f(h));
            }
        }
    }
}

// ================== wide GEMM: 64 rows x WCT*16 cols per block ==================
// Wave decomposition: wave w owns col-tiles [w*WCT/4,(w+1)*WCT/4) x ALL 4 row-strips.
// B staging contiguous per wave (conflict-free); 8 A + WCT/2 B frag reads per k-step.
template <int WCT, bool SPLITK>
__global__ __launch_bounds__(256) void gemm_wide(
    const unsigned short* __restrict__ Ah, const unsigned short* __restrict__ Al, int lda,
    const unsigned short* __restrict__ Bh, const unsigned short* __restrict__ Bl, int ldb,
    float* __restrict__ C0, int M, int N, int K, int KC)
{
    constexpr int CPW = WCT / 4;   // col-tiles per wave
    __shared__ __align__(16) unsigned short Ahs[4][64][8], Als[4][64][8];
    __shared__ __align__(16) unsigned short Bhs[4][WCT * 16][8], Bls[4][WCT * 16][8];
    int t = threadIdx.x, w = t >> 6, l = t & 63, lrow = l & 15, lq = l >> 4;
    int rowBase = blockIdx.x * 64;
    int Kr = (K + 31) & ~31;
    int kbeg = SPLITK ? blockIdx.y * KC : 0;
    int kend = SPLITK ? min(Kr, kbeg + KC) : Kr;

    int arow = min(rowBase + l, M - 1);
    const unsigned short* ga_h = Ah + (long)arow * lda + w * 8;
    const unsigned short* ga_l = Al + (long)arow * lda + w * 8;

    ffrag acc[4][CPW];
#pragma unroll
    for (int r = 0; r < 4; r++)
#pragma unroll
        for (int c = 0; c < CPW; c++) acc[r][c] = ffrag{0.f, 0.f, 0.f, 0.f};

    for (int k0 = kbeg; k0 < kend; k0 += 32) {
        *(uint4*)&Ahs[w][l][0] = *(const uint4*)(ga_h + k0);
        *(uint4*)&Als[w][l][0] = *(const uint4*)(ga_l + k0);
#pragma unroll
        for (int i = 0; i < WCT * 16 / 64; i++) {
            int col = l + 64 * i;                    // wave-contiguous -> conflict-free
            int bc = min(col, N - 1);
            *(uint4*)&Bhs[w][col][0] = *(const uint4*)(Bh + (long)bc * ldb + w * 8 + k0);
            *(uint4*)&Bls[w][col][0] = *(const uint4*)(Bl + (long)bc * ldb + w * 8 + k0);
        }
        __syncthreads();
        bfrag ar[4], alr[4];
#pragma unroll
        for (int r = 0; r < 4; r++) {
            ar[r]  = *(const bfrag*)&Ahs[lq][r * 16 + lrow][0];
            alr[r] = *(const bfrag*)&Als[lq][r * 16 + lrow][0];
        }
#pragma unroll
        for (int ct = 0; ct < CPW; ct++) {
            int c = (w * CPW + ct) * 16 + lrow;
            bfrag bh = *(const bfrag*)&Bhs[lq][c][0];
            bfrag bl = *(const bfrag*)&Bls[lq][c][0];
#pragma unroll
            for (int r = 0; r < 4; r++) {
                acc[r][ct] = __builtin_amdgcn_mfma_f32_16x16x32_bf16(ar[r],  bh, acc[r][ct], 0, 0, 0);
                acc[r][ct] = __builtin_amdgcn_mfma_f32_16x16x32_bf16(ar[r],  bl, acc[r][ct], 0, 0, 0);
                acc[r][ct] = __builtin_amdgcn_mfma_f32_16x16x32_bf16(alr[r], bh, acc[r][ct], 0, 0, 0);
            }
        }
        __syncthreads();
    }

    float* Cz = SPLITK ? (C0 + (long)blockIdx.y * M * N) : C0;
#pragma unroll
    for (int ct = 0; ct < CPW; ct++) {
        int gc = (w * CPW + ct) * 16 + lrow;
        if (gc >= N) continue;
#pragma unroll
        for (int rs = 0; rs < 4; rs++) {
#pragma unroll
            for (int r = 0; r < 4; r++) {
                int gr = rowBase + rs * 16 + lq * 4 + r;
                if (gr >= M) continue;
                Cz[(long)gr * N + gc] = acc[rs][ct][r];
            }
        }
    }
}

// ---------- softmax rows of S -> bf16 hi/lo ----------
__global__ __launch_bounds__(256) void softmax_hl(const float* __restrict__ S,
                                                  unsigned short* __restrict__ SH,
                                                  unsigned short* __restrict__ SL) {
    int row = blockIdx.x, tid = threadIdx.x;
    const float* p = S + (long)row * BP;
    float ev[16];
    __shared__ float red[256];
    float m = -1e30f;
#pragma unroll
    for (int i = 0; i < 16; i++) { float v = p[tid + i * 256]; ev[i] = v; m = fmaxf(m, v); }
    red[tid] = m; __syncthreads();
    for (int s = 128; s > 0; s >>= 1) { if (tid < s) red[tid] = fmaxf(red[tid], red[tid + s]); __syncthreads(); }
    m = red[0]; __syncthreads();
    float sum = 0.f;
#pragma unroll
    for (int i = 0; i < 16; i++) { float e = expf(ev[i] - m); ev[i] = e; sum += e; }
    red[tid] = sum; __syncthreads();
    for (int s = 128; s > 0; s >>= 1) { if (tid < s) red[tid] += red[tid + s]; __syncthreads(); }
    float inv = 1.0f / red[0];
#pragma unroll
    for (int i = 0; i < 16; i++) {
        float e = ev[i] * inv;
        unsigned short h = bf16_rne(e);
        long o = (long)row * BP + tid + i * 256;
        SH[o] = h;
        SL[o] = bf16_rne(e - bf16f(h));
    }
}

// ---------- split-K reduce + residual -> attn bf16 hi/lo ----------
__global__ void splitk_reduce_hl(const float* __restrict__ part, const float* __restrict__ resid,
                                 unsigned short* __restrict__ H, unsigned short* __restrict__ L,
                                 int Mr, int Nc, int Kp2, int sk) {
    long idx = (long)blockIdx.x * blockDim.x + threadIdx.x;
    long total = (long)Mr * Kp2;
    if (idx >= total) return;
    int c = (int)(idx % Kp2);
    long row = idx / Kp2;
    float s = 0.f;
    if (c < Nc) {
        long base = row * Nc + c;
        for (int z = 0; z < sk; z++) s += part[(long)z * Mr * Nc + base];
        s += resid[base];
    }
    unsigned short h = bf16_rne(s);
    H[idx] = h;
    L[idx] = bf16_rne(s - bf16f(h));
}

// ---------- scatter (last write wins) ----------
__global__ void scatter_init(int* last, const int* __restrict__ com, int B) {
    int i = blockIdx.x * blockDim.x + threadIdx.x;
    if (i < B) last[com[i]] = -1;
}
__global__ void scatter_max(int* last, const int* __restrict__ com, int B) {
    int i = blockIdx.x * blockDim.x + threadIdx.x;
    if (i < B) atomicMax(&last[com[i]], i);
}
__global__ void scatter_write(const int* __restrict__ last, const int* __restrict__ com,
                              const float* __restrict__ fused, float* __restrict__ x, int B, int D) {
    int i = blockIdx.x;
    int node = com[i];
    if (last[node] != i) return;
    for (int c = threadIdx.x; c < D; c += blockDim.x)
        x[(long)node * D + c] = fused[(long)i * D + c];
}

// ---------- GAT per-node attention coefficients ----------
__global__ void node_attn_coef(const float* __restrict__ h, const float* __restrict__ a_src,
                               const float* __restrict__ a_dst, float* __restrict__ es,
                               float* __restrict__ ed, int N, int H, int C) {
    int idx = blockIdx.x * blockDim.x + threadIdx.x;
    if (idx >= N * H) return;
    int n = idx / H, hh = idx % H;
    const float* hp = h + (long)n * H * C + (long)hh * C;
    const float* as = a_src + hh * C;
    const float* ad = a_dst + hh * C;
    float s = 0.f, d = 0.f;
    for (int c = 0; c < C; c++) { float v = hp[c]; s += v * as[c]; d += v * ad[c]; }
    es[idx] = s; ed[idx] = d;
}

// ================== CSR build ==================
__global__ void deg_init(int* deg, int n) {
    int i = blockIdx.x * blockDim.x + threadIdx.x;
    if (i < n) deg[i] = 1;
}
__global__ void deg_count(const int* __restrict__ dst, int* deg, int E) {
    int e = blockIdx.x * blockDim.x + threadIdx.x;
    if (e < E) atomicAdd(&deg[dst[e]], 1);
}
__global__ void scan_part(const int* __restrict__ deg, int* __restrict__ bsum, int n) {
    __shared__ int red[256];
    int tid = threadIdx.x;
    int i = blockIdx.x * 256 + tid;
    red[tid] = (i < n) ? deg[i] : 0;
    __syncthreads();
    for (int s = 128; s > 0; s >>= 1) { if (tid < s) red[tid] += red[tid + s]; __syncthreads(); }
    if (tid == 0) bsum[blockIdx.x] = red[0];
}
__global__ __launch_bounds__(256) void scan_bsum(int* __restrict__ bsum, int nb) {
    __shared__ int tmp[256];
    int tid = threadIdx.x;
    int v = (tid < nb) ? bsum[tid] : 0;
    tmp[tid] = v; __syncthreads();
    for (int off = 1; off < 256; off <<= 1) {
        int t2 = (tid >= off) ? tmp[tid - off] : 0;
        __syncthreads();
        tmp[tid] += t2;
        __syncthreads();
    }
    if (tid < nb) bsum[tid] = tmp[tid];
}
__global__ void scan_final(const int* __restrict__ deg, const int* __restrict__ bsum,
                           int* __restrict__ rowptr, int n) {
    __shared__ int tmp[256];
    int tid = threadIdx.x;
    int b = blockIdx.x;
    int i = b * 256 + tid;
    int v = (i < n) ? deg[i] : 0;
    tmp[tid] = v; __syncthreads();
    for (int off = 1; off < 256; off <<= 1) {
        int t2 = (tid >= off) ? tmp[tid - off] : 0;
        __syncthreads();
        tmp[tid] += t2;
        __syncthreads();
    }
    int base = (b > 0) ? bsum[b - 1] : 0;
    if (i < n) rowptr[i + 1] = base + tmp[tid];
    if (b == 0 && tid == 0) rowptr[0] = 0;
}
__global__ void copy_i32(const int* __restrict__ a, int* __restrict__ b, int n) {
    int i = blockIdx.x * blockDim.x + threadIdx.x;
    if (i < n) b[i] = a[i];
}
__global__ void csr_fill(const int* __restrict__ src, const int* __restrict__ dst,
                         int* cursor, int* __restrict__ csr_src, int E) {
    int e = blockIdx.x * blockDim.x + threadIdx.x;
    if (e >= E) return;
    int slot = atomicAdd(&cursor[dst[e]], 1);
    csr_src[slot] = src[e];
}
__global__ void csr_fill_loops(int* cursor, int* __restrict__ csr_src, int n) {
    int i = blockIdx.x * blockDim.x + threadIdx.x;
    if (i >= n) return;
    int slot = atomicAdd(&cursor[i], 1);
    csr_src[slot] = i;
}

// ---------- segment max + denom + per-slot alpha ----------
template <int H>
__global__ void csr_maxden_alpha(const int* __restrict__ rowptr, const int* __restrict__ csr_src,
                                 const float* __restrict__ es, const float* __restrict__ ed,
                                 float* __restrict__ alpha, int N) {
    int idx = blockIdx.x * blockDim.x + threadIdx.x;
    if (idx >= N * H) return;
    int d = idx / H, h = idx - d * H;
    float edv = ed[idx];
    int b = rowptr[d], e = rowptr[d + 1];
    float mm = -1e30f;
    for (int s0 = b; s0 < e; s0++) {
        int s = csr_src[s0];
        mm = fmaxf(mm, leaky(es[s * H + h] + edv));
    }
    float dn = 0.f;
    for (int s0 = b; s0 < e; s0++) {
        int s = csr_src[s0];
        dn += expf(leaky(es[s * H + h] + edv) - mm);
    }
    float inv = 1.f / (dn + 1e-16f);
    for (int s0 = b; s0 < e; s0++) {
        int s = csr_src[s0];
        float al = expf(leaky(es[s * H + h] + edv) - mm) * inv;
        if (H == 3) alpha[(long)s0 * 4 + h] = al;
        else        alpha[s0] = al;
    }
}

// ---------- layer-1 aggregate + bias + ELU + (row @ W2) ----------
__global__ __launch_bounds__(128) void csr_agg1_fused(
    const int* __restrict__ rowptr, const int* __restrict__ csr_src,
    const float4* __restrict__ alpha,
    const float* __restrict__ h1, const float* __restrict__ b1,
    const float* __restrict__ W2, float* __restrict__ h2, int N)
{
    int d = blockIdx.x;
    int t = threadIdx.x;
    __shared__ float row[HC1];
    __shared__ float part[128][OUTC + 1];

    int b = rowptr[d], e = rowptr[d + 1];
    float a0 = 0.f, a1 = 0.f, a2 = 0.f;
    for (int s0 = b; s0 < e; s0++) {
        int s = csr_src[s0];
        float4 al = alpha[s0];
        const float* hp = h1 + (long)s * HC1;
        a0 = fmaf(hp[t],       al.x, a0);
        a1 = fmaf(hp[t + 128], al.y, a1);
        a2 = fmaf(hp[t + 256], al.z, a2);
    }
    float v;
    v = a0 + b1[t];       row[t]       = v > 0.f ? v : expf(v) - 1.f;
    v = a1 + b1[t + 128]; row[t + 128] = v > 0.f ? v : expf(v) - 1.f;
    v = a2 + b1[t + 256]; row[t + 256] = v > 0.f ? v : expf(v) - 1.f;
    __syncthreads();

    float pc[OUTC];
#pragma unroll
    for (int c = 0; c < OUTC; c++) pc[c] = 0.f;
    for (int k = t; k < HC1; k += 128) {
        float rv = row[k];
        const float* wp = W2 + (long)k * OUTC;
#pragma unroll
        for (int c = 0; c < OUTC; c++) pc[c] = fmaf(rv, wp[c], pc[c]);
    }
#pragma unroll
    for (int c = 0; c < OUTC; c++) part[t][c] = pc[c];
    __syncthreads();
    for (int off = 64; off > 0; off >>= 1) {
        if (t < off) {
#pragma unroll
            for (int c = 0; c < OUTC; c++) part[t][c] += part[t + off][c];
        }
        __syncthreads();
    }
    if (t < OUTC) h2[(long)d * OUTC + t] = part[0][t];
}

// ---------- layer-2 aggregate + bias ----------
__global__ void csr_agg2(const int* __restrict__ rowptr, const int* __restrict__ csr_src,
                         const float* __restrict__ alpha,
                         const float* __restrict__ h2, const float* __restrict__ b2,
                         float* __restrict__ emb, int N)
{
    int idx = blockIdx.x * blockDim.x + threadIdx.x;
    if (idx >= N * OUTC) return;
    int d = idx / OUTC, c = idx - d * OUTC;
    int b = rowptr[d], e = rowptr[d + 1];
    float acc = 0.f;
    for (int s0 = b; s0 < e; s0++) {
        int s = csr_src[s0];
        acc = fmaf(h2[(long)s * OUTC + c], alpha[s0], acc);
    }
    emb[idx] = acc + b2[c];
}

// ---------- pair scores ----------
__global__ void pair_score(const int* __restrict__ pairs, const float* __restrict__ emb,
                           float* __restrict__ out, int P) {
    int p = blockIdx.x * blockDim.x + threadIdx.x;
    if (p >= P) return;
    int i0 = pairs[2 * p], i1 = pairs[2 * p + 1];
    const float* a = emb + (long)i0 * OUTC;
    const float* b = emb + (long)i1 * OUTC;
    float s = 0.f;
#pragma unroll
    for (int c = 0; c < OUTC; c++) s += a[c] * b[c];
    out[p] = s;
}

extern "C" void kernel_launch(void* const* d_in, const int* in_sizes, int n_in,
                              void* d_out, int out_size, void* d_ws, size_t ws_size,
                              hipStream_t stream) {
    const float* fsub = (const float*)d_in[0];
    const float* fcom = (const float*)d_in[1];
    float*       x    = (float*)d_in[2];
    const int*   com  = (const int*)d_in[3];
    const int*   ei   = (const int*)d_in[4];
    const int*   pidx = (const int*)d_in[5];
    const float* Wq = (const float*)d_in[6];  const float* bq = (const float*)d_in[7];
    const float* Wk = (const float*)d_in[8];  const float* bk = (const float*)d_in[9];
    const float* Wv = (const float*)d_in[10]; const float* bv = (const float*)d_in[11];
    const float* Wf = (const float*)d_in[12]; const float* bf = (const float*)d_in[13];
    const float* W1 = (const float*)d_in[14];
    const float* as1 = (const float*)d_in[15]; const float* ad1 = (const float*)d_in[16];
    const float* b1 = (const float*)d_in[17];
    const float* W2 = (const float*)d_in[18];
    const float* as2 = (const float*)d_in[19]; const float* ad2 = (const float*)d_in[20];
    const float* b2 = (const float*)d_in[21];
    float* out = (float*)d_out;

    const int* src = ei;
    const int* dst = ei + NE;

    typedef unsigned short u16;
    char* ws = (char*)d_ws;
    float* S     = (float*)(ws + 0);            // dead after softmax
    u16*   SH    = (u16*)(ws + 67108864);       // dead after S@v
    u16*   SL    = (u16*)(ws + 100663296);
    u16*   fsubH = (u16*)(ws + 134217728);      // dead after q proj
    u16*   fsubL = (u16*)(ws + 136839168);
    u16*   fcomH = (u16*)(ws + 139460608);      // dead after k,v proj
    u16*   fcomL = (u16*)(ws + 142082048);
    u16*   qH    = (u16*)(ws + 144703488);      // dead after S gemm
    u16*   qL    = (u16*)(ws + 147324928);
    u16*   kH    = (u16*)(ws + 149946368);
    u16*   kL    = (u16*)(ws + 152567808);
    u16*   vTH   = (u16*)(ws + 155189248);      // dead after S@v
    u16*   vTL   = (u16*)(ws + 157646848);
    u16*   attnH = (u16*)(ws + 160104448);      // dead after fus gemm
    u16*   attnL = (u16*)(ws + 162725888);
    u16*   WqTH  = (u16*)(ws + 165347328);
    u16*   WqTL  = (u16*)(ws + 165539328);
    u16*   WkTH  = (u16*)(ws + 165731328);
    u16*   WkTL  = (u16*)(ws + 165923328);
    u16*   WvTH  = (u16*)(ws + 166115328);
    u16*   WvTL  = (u16*)(ws + 166307328);
    u16*   WfTH  = (u16*)(ws + 166499328);
    u16*   WfTL  = (u16*)(ws + 166691328);
    u16*   W1TH  = (u16*)(ws + 166883328);
    u16*   W1TL  = (u16*)(ws + 167129088);
    float* fus   = (float*)(ws + 167374848);    // alive until scatter
    float* es1   = (float*)(ws + 172290048);
    float* ed1   = (float*)(ws + 172890048);
    float* es2   = (float*)(ws + 174690048);
    float* ed2   = (float*)(ws + 174890048);
    float* h2    = (float*)(ws + 175490048);
    float* embp  = (float*)(ws + 177490048);
    int*   last  = (int*)(ws + 179490048);
    int*   deg   = (int*)(ws + 179690048);
    int*   curs  = (int*)(ws + 179890048);
    int*   rowp  = (int*)(ws + 180090048);
    int*   csrc  = (int*)(ws + 180290064);      // ends 182,490,064
    int*   bsum  = (int*)(ws + 182490112);      // 196 ints
    // overlays (disjoint in time):
    float* part   = (float*)(ws + 0);           // over dead S (S@v phase)
    float* h1     = (float*)(ws + 0);           // over dead S/SH (GAT phase)
    u16*   xH     = (u16*)(ws + 76800000);      // over dead SH/SL
    u16*   xL     = (u16*)(ws + 108800000);
    float* alpha1 = (float*)(ws + 134217728);   // over dead fsubH/L/fcomH (GAT phase)
    float* alpha2 = (float*)(ws + 144703488);   // over dead qH (GAT phase)

    const float inv_sqrt_d = 1.0f / sqrtf((float)FEAT);

    // ===== 0. conversions =====
    hipLaunchKernelGGL(convT_pad, dim3(cdiv(FEAT*KP,256)), dim3(256), 0, stream, Wq, WqTH, WqTL, FEAT, FEAT, KP);
    hipLaunchKernelGGL(convT_pad, dim3(cdiv(FEAT*KP,256)), dim3(256), 0, stream, Wk, WkTH, WkTL, FEAT, FEAT, KP);
    hipLaunchKernelGGL(convT_pad, dim3(cdiv(FEAT*KP,256)), dim3(256), 0, stream, Wv, WvTH, WvTL, FEAT, FEAT, KP);
    hipLaunchKernelGGL(convT_pad, dim3(cdiv(FEAT*KP,256)), dim3(256), 0, stream, Wf, WfTH, WfTL, FEAT, FEAT, KP);
    hipLaunchKernelGGL(convT_pad, dim3(cdiv(HC1*KP,256)),  dim3(256), 0, stream, W1, W1TH, W1TL, FEAT, HC1, KP);
    hipLaunchKernelGGL(conv_pad,  dim3(cdiv(BP*KP,256)),   dim3(256), 0, stream, fsub, fsubH, fsubL, BP, FEAT, KP);
    hipLaunchKernelGGL(conv_pad,  dim3(cdiv(BP*KP,256)),   dim3(256), 0, stream, fcom, fcomH, fcomL, BP, FEAT, KP);
    hipLaunchKernelGGL(fill_f32, dim3(cdiv(10485760/4,256)), dim3(256), 0, stream, (float*)qH, 0.f, (long)(10485760/4));

    // ===== 1. cross attention =====
    hipLaunchKernelGGL((gemm_bf<1>), dim3(cdiv(FEAT,64), cdiv(BP,64)), dim3(256), 0, stream,
                       fsubH, fsubL, KP, WqTH, WqTL, KP, bq, nullptr, nullptr, qH, qL,
                       BP, FEAT, FEAT, 1.0f, KP);
    hipLaunchKernelGGL((gemm_bf<1>), dim3(cdiv(FEAT,64), cdiv(BP,64)), dim3(256), 0, stream,
                       fcomH, fcomL, KP, WkTH, WkTL, KP, bk, nullptr, nullptr, kH, kL,
                       BP, FEAT, FEAT, 1.0f, KP);
    hipLaunchKernelGGL((gemm_bf<2>), dim3(cdiv(FEAT,64), cdiv(BP,64)), dim3(256), 0, stream,
                       fcomH, fcomL, KP, WvTH, WvTL, KP, bv, nullptr, nullptr, vTH, vTL,
                       BP, FEAT, FEAT, 1.0f, BP);
    hipLaunchKernelGGL((gemm_bf<0>), dim3(cdiv(BP,64), cdiv(BP,64)), dim3(256), 0, stream,
                       qH, qL, KP, kH, kL, KP, nullptr, nullptr, S, nullptr, nullptr,
                       BP, BP, FEAT, inv_sqrt_d, BP);
    hipLaunchKernelGGL(softmax_hl, dim3(BP), dim3(256), 0, stream, S, SH, SL);
    // part[z] = S_z @ v  — wide-N split-K: S fetched exactly once
    hipLaunchKernelGGL((gemm_wide<20, true>), dim3(cdiv(BP,64), 8), dim3(256), 0, stream,
                       SH, SL, BP, vTH, vTL, BP, part, BP, FEAT, BP, 512);
    hipLaunchKernelGGL(splitk_reduce_hl, dim3(cdiv(BP*KP,256)), dim3(256), 0, stream,
                       part, fsub, attnH, attnL, BP, FEAT, KP, 8);
    hipLaunchKernelGGL((gemm_bf<0>), dim3(cdiv(FEAT,64), cdiv(BP,64)), dim3(256), 0, stream,
                       attnH, attnL, KP, WfTH, WfTL, KP, bf, nullptr, fus, nullptr, nullptr,
                       BP, FEAT, FEAT, 1.0f, FEAT);

    // ===== 2. scatter fused into x =====
    hipLaunchKernelGGL(scatter_init, dim3(cdiv(BP,256)), dim3(256), 0, stream, last, com, BP);
    hipLaunchKernelGGL(scatter_max,  dim3(cdiv(BP,256)), dim3(256), 0, stream, last, com, BP);
    hipLaunchKernelGGL(scatter_write, dim3(BP), dim3(128), 0, stream, last, com, fus, x, BP, FEAT);

    // ===== 3. convert x, CSR build =====
    hipLaunchKernelGGL(conv_pad, dim3(cdiv((long)NN*KP,256)), dim3(256), 0, stream, x, xH, xL, NN, FEAT, KP);
    hipLaunchKernelGGL(deg_init,  dim3(cdiv(NN,256)), dim3(256), 0, stream, deg, NN);
    hipLaunchKernelGGL(deg_count, dim3(cdiv(NE,256)), dim3(256), 0, stream, dst, deg, NE);
    {
        int nb = cdiv(NN, 256);   // 196
        hipLaunchKernelGGL(scan_part,  dim3(nb), dim3(256), 0, stream, deg, bsum, NN);
        hipLaunchKernelGGL(scan_bsum,  dim3(1),  dim3(256), 0, stream, bsum, nb);
        hipLaunchKernelGGL(scan_final, dim3(nb), dim3(256), 0, stream, deg, bsum, rowp, NN);
    }
    hipLaunchKernelGGL(copy_i32, dim3(cdiv(NN,256)), dim3(256), 0, stream, rowp, curs, NN);
    hipLaunchKernelGGL(csr_fill, dim3(cdiv(NE,256)), dim3(256), 0, stream, src, dst, curs, csrc, NE);
    hipLaunchKernelGGL(csr_fill_loops, dim3(cdiv(NN,256)), dim3(256), 0, stream, curs, csrc, NN);

    // ===== 4. GAT layer 1 =====
    hipLaunchKernelGGL((gemm_wide<24, false>), dim3(cdiv(NN,64), 1), dim3(256), 0, stream,
                       xH, xL, KP, W1TH, W1TL, KP, h1, NN, HC1, FEAT, 0);
    hipLaunchKernelGGL(node_attn_coef, dim3(cdiv(NN*HEADS,256)), dim3(256), 0, stream,
                       h1, as1, ad1, es1, ed1, NN, HEADS, HID);
    hipLaunchKernelGGL((csr_maxden_alpha<HEADS>), dim3(cdiv(NN*HEADS,256)), dim3(256), 0, stream,
                       rowp, csrc, es1, ed1, alpha1, NN);
    hipLaunchKernelGGL(csr_agg1_fused, dim3(NN), dim3(128), 0, stream,
                       rowp, csrc, (const float4*)alpha1, h1, b1, W2, h2, NN);

    // ===== 5. GAT layer 2 =====
    hipLaunchKernelGGL(node_attn_coef, dim3(cdiv(NN,256)), dim3(256), 0, stream,
                       h2, as2, ad2, es2, ed2, NN, 1, OUTC);
    hipLaunchKernelGGL((csr_maxden_alpha<1>), dim3(cdiv(NN,256)), dim3(256), 0, stream,
                       rowp, csrc, es2, ed2, alpha2, NN);
    hipLaunchKernelGGL(csr_agg2, dim3(cdiv(NN*OUTC,256)), dim3(256), 0, stream,
                       rowp, csrc, alpha2, h2, b2, embp, NN);

    // ===== 6. pair scores =====
    hipLaunchKernelGGL(pair_score, dim3(cdiv(NP,256)), dim3(256), 0, stream, pidx, embp, out, NP);
}

// Round 11
// 956.685 us; speedup vs baseline: 1.8365x; 1.0090x over previous
//
#include <hip/hip_runtime.h>
#include <math.h>

#define NN      50000      // N_NODES
#define BP      4096       // N_PAIRS_MAP
#define NE      500000     // N_EDGES
#define NP      1000000    // N_SCORE_PAIRS
#define FEAT    300
#define KP      320        // FEAT padded to multiple of 32
#define HID     128
#define HEADS   3
#define OUTC    10
#define HC1     (HEADS*HID)   // 384
#define NEG_SLOPE 0.2f

static inline int cdiv(int a, int b) { return (a + b - 1) / b; }

using bfrag = __attribute__((ext_vector_type(8))) short;
using ffrag = __attribute__((ext_vector_type(4))) float;

__device__ inline float leaky(float x) { return x > 0.f ? x : NEG_SLOPE * x; }
__device__ inline unsigned short bf16_rne(float f) {
    unsigned u = __float_as_uint(f);
    unsigned r = u + 0x7FFFu + ((u >> 16) & 1u);
    return (unsigned short)(r >> 16);
}
__device__ inline float bf16f(unsigned short h) { return __uint_as_float(((unsigned)h) << 16); }

__global__ void fill_f32(float* p, float v, long n) {
    long i = (long)blockIdx.x * blockDim.x + threadIdx.x;
    if (i < n) p[i] = v;
}

// fp32 [M][K] -> bf16 hi/lo [M][Kp], zero-padded k tail
__global__ void conv_pad(const float* __restrict__ in, unsigned short* __restrict__ H,
                         unsigned short* __restrict__ L, long M, int K, int Kp) {
    long idx = (long)blockIdx.x * blockDim.x + threadIdx.x;
    long total = M * Kp;
    if (idx >= total) return;
    int k = (int)(idx % Kp);
    long row = idx / Kp;
    float f = (k < K) ? in[row * K + k] : 0.f;
    unsigned short h = bf16_rne(f);
    H[idx] = h;
    L[idx] = bf16_rne(f - bf16f(h));
}
// fp32 [K][N] row-major -> bf16 hi/lo [N][Kp] (transposed, padded)
__global__ void convT_pad(const float* __restrict__ in, unsigned short* __restrict__ H,
                          unsigned short* __restrict__ L, int K, int N, int Kp) {
    long idx = (long)blockIdx.x * blockDim.x + threadIdx.x;
    long total = (long)N * Kp;
    if (idx >= total) return;
    int k = (int)(idx % Kp);
    long n = idx / Kp;
    float f = (k < K) ? in[(long)k * N + n] : 0.f;
    unsigned short h = bf16_rne(f);
    H[idx] = h;
    L[idx] = bf16_rne(f - bf16f(h));
}

// ================== split-bf16 MFMA GEMM (64x64 tile, LDS-staged) ==================
// MODE: 0 = fp32 out (scale, bias?, addsrc?), 1 = bf16 hi/lo out (+bias),
//       2 = transposed bf16 hi/lo out (+bias)
template <int MODE>
__global__ __launch_bounds__(256) void gemm_bf(
    const unsigned short* __restrict__ Ah, const unsigned short* __restrict__ Al, int lda,
    const unsigned short* __restrict__ Bh, const unsigned short* __restrict__ Bl, int ldb,
    const float* __restrict__ bias, const float* __restrict__ addsrc,
    float* __restrict__ C0, unsigned short* __restrict__ H0, unsigned short* __restrict__ L0,
    int M, int N, int K, float scale, int ldo)
{
    __shared__ __align__(16) unsigned short Ahs[4][64][8], Als[4][64][8];
    __shared__ __align__(16) unsigned short Bhs[4][64][8], Bls[4][64][8];
    int t = threadIdx.x, w = t >> 6, l = t & 63, lrow = l & 15, lq = l >> 4;
    int rowBase = blockIdx.y * 64, colBase = blockIdx.x * 64;
    int Kr = (K + 31) & ~31;

    int arow = min(rowBase + l, M - 1);
    int brow = min(colBase + l, N - 1);
    const unsigned short* ga_h = Ah + (long)arow * lda + w * 8;
    const unsigned short* ga_l = Al + (long)arow * lda + w * 8;
    const unsigned short* gb_h = Bh + (long)brow * ldb + w * 8;
    const unsigned short* gb_l = Bl + (long)brow * ldb + w * 8;

    ffrag acc[4] = {{0.f,0.f,0.f,0.f},{0.f,0.f,0.f,0.f},{0.f,0.f,0.f,0.f},{0.f,0.f,0.f,0.f}};

    for (int k0 = 0; k0 < Kr; k0 += 32) {
        *(uint4*)&Ahs[w][l][0] = *(const uint4*)(ga_h + k0);
        *(uint4*)&Als[w][l][0] = *(const uint4*)(ga_l + k0);
        *(uint4*)&Bhs[w][l][0] = *(const uint4*)(gb_h + k0);
        *(uint4*)&Bls[w][l][0] = *(const uint4*)(gb_l + k0);
        __syncthreads();
        bfrag ah  = *(const bfrag*)&Ahs[lq][w * 16 + lrow][0];
        bfrag alo = *(const bfrag*)&Als[lq][w * 16 + lrow][0];
#pragma unroll
        for (int ct = 0; ct < 4; ct++) {
            bfrag bh = *(const bfrag*)&Bhs[lq][ct * 16 + lrow][0];
            bfrag bl = *(const bfrag*)&Bls[lq][ct * 16 + lrow][0];
            acc[ct] = __builtin_amdgcn_mfma_f32_16x16x32_bf16(ah,  bh, acc[ct], 0, 0, 0);
            acc[ct] = __builtin_amdgcn_mfma_f32_16x16x32_bf16(ah,  bl, acc[ct], 0, 0, 0);
            acc[ct] = __builtin_amdgcn_mfma_f32_16x16x32_bf16(alo, bh, acc[ct], 0, 0, 0);
        }
        __syncthreads();
    }

#pragma unroll
    for (int ct = 0; ct < 4; ct++) {
        int gc = colBase + ct * 16 + lrow;
        if (gc >= N) continue;
#pragma unroll
        for (int r = 0; r < 4; r++) {
            int gr = rowBase + w * 16 + lq * 4 + r;
            if (gr >= M) continue;
            float v = acc[ct][r];
            if (MODE == 0) {
                float o = v * scale;
                if (bias) o += bias[gc];
                if (addsrc) o += addsrc[(long)gr * ldo + gc];
                C0[(long)gr * ldo + gc] = o;
            } else if (MODE == 1) {
                float o = v + bias[gc];
                unsigned short h = bf16_rne(o);
                H0[(long)gr * ldo + gc] = h;
                L0[(long)gr * ldo + gc] = bf16_rne(o - bf16f(h));
            } else {
                float o = v + bias[gc];
                unsigned short h = bf16_rne(o);
                H0[(long)gc * ldo + gr] = h;
                L0[(long)gc * ldo + gr] = bf16_rne(o - bf16f(h));
            }
        }
    }
}

// ================== direct-frag GEMM: no LDS, no barriers ==================
// MFMA fragments loaded straight from global (A[m][k], B[n][k] k-contiguous ->
// one bfrag load = 16 fully-used 64B lines). Wave w owns col-tiles
// [w*CPW,(w+1)*CPW) x all 4 row-strips of the 64-row block. dAl/dBl are the
// element offsets from the hi buffer to the lo buffer.
template <int CPW, bool SPLITK>
__global__ __launch_bounds__(256) void gemm_direct(
    const unsigned short* __restrict__ Ah, long dAl, int lda,
    const unsigned short* __restrict__ Bh, long dBl, int ldb,
    float* __restrict__ C0, int M, int N, int K, int KC)
{
    int t = threadIdx.x, w = t >> 6, l = t & 63, lrow = l & 15, lq = l >> 4;
    int rowBase = blockIdx.x * 64;
    int Kr = (K + 31) & ~31;
    int kbeg = SPLITK ? blockIdx.y * KC : 0;
    int kend = SPLITK ? min(Kr, kbeg + KC) : Kr;

    const unsigned short* pa[4];
#pragma unroll
    for (int rs = 0; rs < 4; rs++) {
        int row = min(rowBase + rs * 16 + lrow, M - 1);
        pa[rs] = Ah + (long)row * lda + lq * 8;
    }
    const unsigned short* pb[CPW];
#pragma unroll
    for (int ct = 0; ct < CPW; ct++) {
        int col = min((w * CPW + ct) * 16 + lrow, N - 1);
        pb[ct] = Bh + (long)col * ldb + lq * 8;
    }

    ffrag acc[4][CPW];
#pragma unroll
    for (int rs = 0; rs < 4; rs++)
#pragma unroll
        for (int ct = 0; ct < CPW; ct++) acc[rs][ct] = ffrag{0.f, 0.f, 0.f, 0.f};

    for (int k0 = kbeg; k0 < kend; k0 += 32) {
        bfrag ah[4], al4[4];
#pragma unroll
        for (int rs = 0; rs < 4; rs++) {
            ah[rs]  = *(const bfrag*)(pa[rs] + k0);
            al4[rs] = *(const bfrag*)(pa[rs] + k0 + dAl);
        }
#pragma unroll
        for (int ct = 0; ct < CPW; ct++) {
            bfrag bh = *(const bfrag*)(pb[ct] + k0);
            bfrag bl = *(const bfrag*)(pb[ct] + k0 + dBl);
#pragma unroll
            for (int rs = 0; rs < 4; rs++) {
                acc[rs][ct] = __builtin_amdgcn_mfma_f32_16x16x32_bf16(ah[rs],  bh, acc[rs][ct], 0, 0, 0);
                acc[rs][ct] = __builtin_amdgcn_mfma_f32_16x16x32_bf16(ah[rs],  bl, acc[rs][ct], 0, 0, 0);
                acc[rs][ct] = __builtin_amdgcn_mfma_f32_16x16x32_bf16(al4[rs], bh, acc[rs][ct], 0, 0, 0);
            }
        }
    }

    float* Cz = SPLITK ? (C0 + (long)blockIdx.y * M * N) : C0;
#pragma unroll
    for (int ct = 0; ct < CPW; ct++) {
        int gc = (w * CPW + ct) * 16 + lrow;
        if (gc >= N) continue;
#pragma unroll
        for (int rs = 0; rs < 4; rs++) {
#pragma unroll
            for (int r = 0; r < 4; r++) {
                int gr = rowBase + rs * 16 + lq * 4 + r;
                if (gr >= M) continue;
                Cz[(long)gr * N + gc] = acc[rs][ct][r];
            }
        }
    }
}

// ---------- softmax rows of S -> bf16 hi/lo ----------
__global__ __launch_bounds__(256) void softmax_hl(const float* __restrict__ S,
                                                  unsigned short* __restrict__ SH,
                                                  unsigned short* __restrict__ SL) {
    int row = blockIdx.x, tid = threadIdx.x;
    const float* p = S + (long)row * BP;
    float ev[16];
    __shared__ float red[256];
    float m = -1e30f;
#pragma unroll
    for (int i = 0; i < 16; i++) { float v = p[tid + i * 256]; ev[i] = v; m = fmaxf(m, v); }
    red[tid] = m; __syncthreads();
    for (int s = 128; s > 0; s >>= 1) { if (tid < s) red[tid] = fmaxf(red[tid], red[tid + s]); __syncthreads(); }
    m = red[0]; __syncthreads();
    float sum = 0.f;
#pragma unroll
    for (int i = 0; i < 16; i++) { float e = expf(ev[i] - m); ev[i] = e; sum += e; }
    red[tid] = sum; __syncthreads();
    for (int s = 128; s > 0; s >>= 1) { if (tid < s) red[tid] += red[tid + s]; __syncthreads(); }
    float inv = 1.0f / red[0];
#pragma unroll
    for (int i = 0; i < 16; i++) {
        float e = ev[i] * inv;
        unsigned short h = bf16_rne(e);
        long o = (long)row * BP + tid + i * 256;
        SH[o] = h;
        SL[o] = bf16_rne(e - bf16f(h));
    }
}

// ---------- split-K reduce + residual -> attn bf16 hi/lo ----------
__global__ void splitk_reduce_hl(const float* __restrict__ part, const float* __restrict__ resid,
                                 unsigned short* __restrict__ H, unsigned short* __restrict__ L,
                                 int Mr, int Nc, int Kp2, int sk) {
    long idx = (long)blockIdx.x * blockDim.x + threadIdx.x;
    long total = (long)Mr * Kp2;
    if (idx >= total) return;
    int c = (int)(idx % Kp2);
    long row = idx / Kp2;
    float s = 0.f;
    if (c < Nc) {
        long base = row * Nc + c;
        for (int z = 0; z < sk; z++) s += part[(long)z * Mr * Nc + base];
        s += resid[base];
    }
    unsigned short h = bf16_rne(s);
    H[idx] = h;
    L[idx] = bf16_rne(s - bf16f(h));
}

// ---------- scatter (last write wins) ----------
__global__ void scatter_init(int* last, const int* __restrict__ com, int B) {
    int i = blockIdx.x * blockDim.x + threadIdx.x;
    if (i < B) last[com[i]] = -1;
}
__global__ void scatter_max(int* last, const int* __restrict__ com, int B) {
    int i = blockIdx.x * blockDim.x + threadIdx.x;
    if (i < B) atomicMax(&last[com[i]], i);
}
__global__ void scatter_write(const int* __restrict__ last, const int* __restrict__ com,
                              const float* __restrict__ fused, float* __restrict__ x, int B, int D) {
    int i = blockIdx.x;
    int node = com[i];
    if (last[node] != i) return;
    for (int c = threadIdx.x; c < D; c += blockDim.x)
        x[(long)node * D + c] = fused[(long)i * D + c];
}

// ---------- GAT per-node attention coefficients ----------
__global__ void node_attn_coef(const float* __restrict__ h, const float* __restrict__ a_src,
                               const float* __restrict__ a_dst, float* __restrict__ es,
                               float* __restrict__ ed, int N, int H, int C) {
    int idx = blockIdx.x * blockDim.x + threadIdx.x;
    if (idx >= N * H) return;
    int n = idx / H, hh = idx % H;
    const float* hp = h + (long)n * H * C + (long)hh * C;
    const float* as = a_src + hh * C;
    const float* ad = a_dst + hh * C;
    float s = 0.f, d = 0.f;
    for (int c = 0; c < C; c++) { float v = hp[c]; s += v * as[c]; d += v * ad[c]; }
    es[idx] = s; ed[idx] = d;
}

// ================== CSR build ==================
__global__ void deg_init(int* deg, int n) {
    int i = blockIdx.x * blockDim.x + threadIdx.x;
    if (i < n) deg[i] = 1;
}
__global__ void deg_count(const int* __restrict__ dst, int* deg, int E) {
    int e = blockIdx.x * blockDim.x + threadIdx.x;
    if (e < E) atomicAdd(&deg[dst[e]], 1);
}
__global__ void scan_part(const int* __restrict__ deg, int* __restrict__ bsum, int n) {
    __shared__ int red[256];
    int tid = threadIdx.x;
    int i = blockIdx.x * 256 + tid;
    red[tid] = (i < n) ? deg[i] : 0;
    __syncthreads();
    for (int s = 128; s > 0; s >>= 1) { if (tid < s) red[tid] += red[tid + s]; __syncthreads(); }
    if (tid == 0) bsum[blockIdx.x] = red[0];
}
__global__ __launch_bounds__(256) void scan_bsum(int* __restrict__ bsum, int nb) {
    __shared__ int tmp[256];
    int tid = threadIdx.x;
    int v = (tid < nb) ? bsum[tid] : 0;
    tmp[tid] = v; __syncthreads();
    for (int off = 1; off < 256; off <<= 1) {
        int t2 = (tid >= off) ? tmp[tid - off] : 0;
        __syncthreads();
        tmp[tid] += t2;
        __syncthreads();
    }
    if (tid < nb) bsum[tid] = tmp[tid];
}
__global__ void scan_final(const int* __restrict__ deg, const int* __restrict__ bsum,
                           int* __restrict__ rowptr, int n) {
    __shared__ int tmp[256];
    int tid = threadIdx.x;
    int b = blockIdx.x;
    int i = b * 256 + tid;
    int v = (i < n) ? deg[i] : 0;
    tmp[tid] = v; __syncthreads();
    for (int off = 1; off < 256; off <<= 1) {
        int t2 = (tid >= off) ? tmp[tid - off] : 0;
        __syncthreads();
        tmp[tid] += t2;
        __syncthreads();
    }
    int base = (b > 0) ? bsum[b - 1] : 0;
    if (i < n) rowptr[i + 1] = base + tmp[tid];
    if (b == 0 && tid == 0) rowptr[0] = 0;
}
__global__ void copy_i32(const int* __restrict__ a, int* __restrict__ b, int n) {
    int i = blockIdx.x * blockDim.x + threadIdx.x;
    if (i < n) b[i] = a[i];
}
__global__ void csr_fill(const int* __restrict__ src, const int* __restrict__ dst,
                         int* cursor, int* __restrict__ csr_src, int E) {
    int e = blockIdx.x * blockDim.x + threadIdx.x;
    if (e >= E) return;
    int slot = atomicAdd(&cursor[dst[e]], 1);
    csr_src[slot] = src[e];
}
__global__ void csr_fill_loops(int* cursor, int* __restrict__ csr_src, int n) {
    int i = blockIdx.x * blockDim.x + threadIdx.x;
    if (i >= n) return;
    int slot = atomicAdd(&cursor[i], 1);
    csr_src[slot] = i;
}

// ---------- segment max + denom + per-slot alpha ----------
template <int H>
__global__ void csr_maxden_alpha(const int* __restrict__ rowptr, const int* __restrict__ csr_src,
                                 const float* __restrict__ es, const float* __restrict__ ed,
                                 float* __restrict__ alpha, int N) {
    int idx = blockIdx.x * blockDim.x + threadIdx.x;
    if (idx >= N * H) return;
    int d = idx / H, h = idx - d * H;
    float edv = ed[idx];
    int b = rowptr[d], e = rowptr[d + 1];
    float mm = -1e30f;
    for (int s0 = b; s0 < e; s0++) {
        int s = csr_src[s0];
        mm = fmaxf(mm, leaky(es[s * H + h] + edv));
    }
    float dn = 0.f;
    for (int s0 = b; s0 < e; s0++) {
        int s = csr_src[s0];
        dn += expf(leaky(es[s * H + h] + edv) - mm);
    }
    float inv = 1.f / (dn + 1e-16f);
    for (int s0 = b; s0 < e; s0++) {
        int s = csr_src[s0];
        float al = expf(leaky(es[s * H + h] + edv) - mm) * inv;
        if (H == 3) alpha[(long)s0 * 4 + h] = al;
        else        alpha[s0] = al;
    }
}

// ---------- layer-1 aggregate + bias + ELU + (row @ W2) ----------
__global__ __launch_bounds__(128) void csr_agg1_fused(
    const int* __restrict__ rowptr, const int* __restrict__ csr_src,
    const float4* __restrict__ alpha,
    const float* __restrict__ h1, const float* __restrict__ b1,
    const float* __restrict__ W2, float* __restrict__ h2, int N)
{
    int d = blockIdx.x;
    int t = threadIdx.x;
    __shared__ float row[HC1];
    __shared__ float part[128][OUTC + 1];

    int b = rowptr[d], e = rowptr[d + 1];
    float a0 = 0.f, a1 = 0.f, a2 = 0.f;
    for (int s0 = b; s0 < e; s0++) {
        int s = csr_src[s0];
        float4 al = alpha[s0];
        const float* hp = h1 + (long)s * HC1;
        a0 = fmaf(hp[t],       al.x, a0);
        a1 = fmaf(hp[t + 128], al.y, a1);
        a2 = fmaf(hp[t + 256], al.z, a2);
    }
    float v;
    v = a0 + b1[t];       row[t]       = v > 0.f ? v : expf(v) - 1.f;
    v = a1 + b1[t + 128]; row[t + 128] = v > 0.f ? v : expf(v) - 1.f;
    v = a2 + b1[t + 256]; row[t + 256] = v > 0.f ? v : expf(v) - 1.f;
    __syncthreads();

    float pc[OUTC];
#pragma unroll
    for (int c = 0; c < OUTC; c++) pc[c] = 0.f;
    for (int k = t; k < HC1; k += 128) {
        float rv = row[k];
        const float* wp = W2 + (long)k * OUTC;
#pragma unroll
        for (int c = 0; c < OUTC; c++) pc[c] = fmaf(rv, wp[c], pc[c]);
    }
#pragma unroll
    for (int c = 0; c < OUTC; c++) part[t][c] = pc[c];
    __syncthreads();
    for (int off = 64; off > 0; off >>= 1) {
        if (t < off) {
#pragma unroll
            for (int c = 0; c < OUTC; c++) part[t][c] += part[t + off][c];
        }
        __syncthreads();
    }
    if (t < OUTC) h2[(long)d * OUTC + t] = part[0][t];
}

// ---------- layer-2 aggregate + bias ----------
__global__ void csr_agg2(const int* __restrict__ rowptr, const int* __restrict__ csr_src,
                         const float* __restrict__ alpha,
                         const float* __restrict__ h2, const float* __restrict__ b2,
                         float* __restrict__ emb, int N)
{
    int idx = blockIdx.x * blockDim.x + threadIdx.x;
    if (idx >= N * OUTC) return;
    int d = idx / OUTC, c = idx - d * OUTC;
    int b = rowptr[d], e = rowptr[d + 1];
    float acc = 0.f;
    for (int s0 = b; s0 < e; s0++) {
        int s = csr_src[s0];
        acc = fmaf(h2[(long)s * OUTC + c], alpha[s0], acc);
    }
    emb[idx] = acc + b2[c];
}

// ---------- pair scores ----------
__global__ void pair_score(const int* __restrict__ pairs, const float* __restrict__ emb,
                           float* __restrict__ out, int P) {
    int p = blockIdx.x * blockDim.x + threadIdx.x;
    if (p >= P) return;
    int i0 = pairs[2 * p], i1 = pairs[2 * p + 1];
    const float* a = emb + (long)i0 * OUTC;
    const float* b = emb + (long)i1 * OUTC;
    float s = 0.f;
#pragma unroll
    for (int c = 0; c < OUTC; c++) s += a[c] * b[c];
    out[p] = s;
}

extern "C" void kernel_launch(void* const* d_in, const int* in_sizes, int n_in,
                              void* d_out, int out_size, void* d_ws, size_t ws_size,
                              hipStream_t stream) {
    const float* fsub = (const float*)d_in[0];
    const float* fcom = (const float*)d_in[1];
    float*       x    = (float*)d_in[2];
    const int*   com  = (const int*)d_in[3];
    const int*   ei   = (const int*)d_in[4];
    const int*   pidx = (const int*)d_in[5];
    const float* Wq = (const float*)d_in[6];  const float* bq = (const float*)d_in[7];
    const float* Wk = (const float*)d_in[8];  const float* bk = (const float*)d_in[9];
    const float* Wv = (const float*)d_in[10]; const float* bv = (const float*)d_in[11];
    const float* Wf = (const float*)d_in[12]; const float* bf = (const float*)d_in[13];
    const float* W1 = (const float*)d_in[14];
    const float* as1 = (const float*)d_in[15]; const float* ad1 = (const float*)d_in[16];
    const float* b1 = (const float*)d_in[17];
    const float* W2 = (const float*)d_in[18];
    const float* as2 = (const float*)d_in[19]; const float* ad2 = (const float*)d_in[20];
    const float* b2 = (const float*)d_in[21];
    float* out = (float*)d_out;

    const int* src = ei;
    const int* dst = ei + NE;

    typedef unsigned short u16;
    char* ws = (char*)d_ws;
    float* S     = (float*)(ws + 0);            // dead after softmax
    u16*   SH    = (u16*)(ws + 67108864);       // dead after S@v
    u16*   SL    = (u16*)(ws + 100663296);
    u16*   fsubH = (u16*)(ws + 134217728);      // dead after q proj
    u16*   fsubL = (u16*)(ws + 136839168);
    u16*   fcomH = (u16*)(ws + 139460608);      // dead after k,v proj
    u16*   fcomL = (u16*)(ws + 142082048);
    u16*   qH    = (u16*)(ws + 144703488);      // dead after S gemm
    u16*   qL    = (u16*)(ws + 147324928);
    u16*   kH    = (u16*)(ws + 149946368);
    u16*   kL    = (u16*)(ws + 152567808);
    u16*   vTH   = (u16*)(ws + 155189248);      // dead after S@v
    u16*   vTL   = (u16*)(ws + 157646848);
    u16*   attnH = (u16*)(ws + 160104448);      // dead after fus gemm
    u16*   attnL = (u16*)(ws + 162725888);
    u16*   WqTH  = (u16*)(ws + 165347328);
    u16*   WqTL  = (u16*)(ws + 165539328);
    u16*   WkTH  = (u16*)(ws + 165731328);
    u16*   WkTL  = (u16*)(ws + 165923328);
    u16*   WvTH  = (u16*)(ws + 166115328);
    u16*   WvTL  = (u16*)(ws + 166307328);
    u16*   WfTH  = (u16*)(ws + 166499328);
    u16*   WfTL  = (u16*)(ws + 166691328);
    u16*   W1TH  = (u16*)(ws + 166883328);
    u16*   W1TL  = (u16*)(ws + 167129088);
    float* fus   = (float*)(ws + 167374848);    // alive until scatter
    float* es1   = (float*)(ws + 172290048);
    float* ed1   = (float*)(ws + 172890048);
    float* es2   = (float*)(ws + 174690048);
    float* ed2   = (float*)(ws + 174890048);
    float* h2    = (float*)(ws + 175490048);
    float* embp  = (float*)(ws + 177490048);
    int*   last  = (int*)(ws + 179490048);
    int*   deg   = (int*)(ws + 179690048);
    int*   curs  = (int*)(ws + 179890048);
    int*   rowp  = (int*)(ws + 180090048);
    int*   csrc  = (int*)(ws + 180290064);      // ends 182,490,064
    int*   bsum  = (int*)(ws + 182490112);      // 196 ints
    // overlays (disjoint in time):
    float* part   = (float*)(ws + 0);           // over dead S (S@v phase)
    float* h1     = (float*)(ws + 0);           // over dead S/SH (GAT phase)
    u16*   xH     = (u16*)(ws + 76800000);      // over dead SH/SL
    u16*   xL     = (u16*)(ws + 108800000);
    float* alpha1 = (float*)(ws + 134217728);   // over dead fsubH/L/fcomH (GAT phase)
    float* alpha2 = (float*)(ws + 144703488);   // over dead qH (GAT phase)

    const float inv_sqrt_d = 1.0f / sqrtf((float)FEAT);

    // ===== 0. conversions =====
    hipLaunchKernelGGL(convT_pad, dim3(cdiv(FEAT*KP,256)), dim3(256), 0, stream, Wq, WqTH, WqTL, FEAT, FEAT, KP);
    hipLaunchKernelGGL(convT_pad, dim3(cdiv(FEAT*KP,256)), dim3(256), 0, stream, Wk, WkTH, WkTL, FEAT, FEAT, KP);
    hipLaunchKernelGGL(convT_pad, dim3(cdiv(FEAT*KP,256)), dim3(256), 0, stream, Wv, WvTH, WvTL, FEAT, FEAT, KP);
    hipLaunchKernelGGL(convT_pad, dim3(cdiv(FEAT*KP,256)), dim3(256), 0, stream, Wf, WfTH, WfTL, FEAT, FEAT, KP);
    hipLaunchKernelGGL(convT_pad, dim3(cdiv(HC1*KP,256)),  dim3(256), 0, stream, W1, W1TH, W1TL, FEAT, HC1, KP);
    hipLaunchKernelGGL(conv_pad,  dim3(cdiv(BP*KP,256)),   dim3(256), 0, stream, fsub, fsubH, fsubL, BP, FEAT, KP);
    hipLaunchKernelGGL(conv_pad,  dim3(cdiv(BP*KP,256)),   dim3(256), 0, stream, fcom, fcomH, fcomL, BP, FEAT, KP);
    hipLaunchKernelGGL(fill_f32, dim3(cdiv(10485760/4,256)), dim3(256), 0, stream, (float*)qH, 0.f, (long)(10485760/4));

    // ===== 1. cross attention =====
    hipLaunchKernelGGL((gemm_bf<1>), dim3(cdiv(FEAT,64), cdiv(BP,64)), dim3(256), 0, stream,
                       fsubH, fsubL, KP, WqTH, WqTL, KP, bq, nullptr, nullptr, qH, qL,
                       BP, FEAT, FEAT, 1.0f, KP);
    hipLaunchKernelGGL((gemm_bf<1>), dim3(cdiv(FEAT,64), cdiv(BP,64)), dim3(256), 0, stream,
                       fcomH, fcomL, KP, WkTH, WkTL, KP, bk, nullptr, nullptr, kH, kL,
                       BP, FEAT, FEAT, 1.0f, KP);
    hipLaunchKernelGGL((gemm_bf<2>), dim3(cdiv(FEAT,64), cdiv(BP,64)), dim3(256), 0, stream,
                       fcomH, fcomL, KP, WvTH, WvTL, KP, bv, nullptr, nullptr, vTH, vTL,
                       BP, FEAT, FEAT, 1.0f, BP);
    hipLaunchKernelGGL((gemm_bf<0>), dim3(cdiv(BP,64), cdiv(BP,64)), dim3(256), 0, stream,
                       qH, qL, KP, kH, kL, KP, nullptr, nullptr, S, nullptr, nullptr,
                       BP, BP, FEAT, inv_sqrt_d, BP);
    hipLaunchKernelGGL(softmax_hl, dim3(BP), dim3(256), 0, stream, S, SH, SL);
    // part[z] = S_z @ v  — direct-frag split-K (no LDS, no barriers)
    hipLaunchKernelGGL((gemm_direct<5, true>), dim3(cdiv(BP,64), 8), dim3(256), 0, stream,
                       SH, (long)(SL - SH), BP, vTH, (long)(vTL - vTH), BP,
                       part, BP, FEAT, BP, 512);
    hipLaunchKernelGGL(splitk_reduce_hl, dim3(cdiv(BP*KP,256)), dim3(256), 0, stream,
                       part, fsub, attnH, attnL, BP, FEAT, KP, 8);
    hipLaunchKernelGGL((gemm_bf<0>), dim3(cdiv(FEAT,64), cdiv(BP,64)), dim3(256), 0, stream,
                       attnH, attnL, KP, WfTH, WfTL, KP, bf, nullptr, fus, nullptr, nullptr,
                       BP, FEAT, FEAT, 1.0f, FEAT);

    // ===== 2. scatter fused into x =====
    hipLaunchKernelGGL(scatter_init, dim3(cdiv(BP,256)), dim3(256), 0, stream, last, com, BP);
    hipLaunchKernelGGL(scatter_max,  dim3(cdiv(BP,256)), dim3(256), 0, stream, last, com, BP);
    hipLaunchKernelGGL(scatter_write, dim3(BP), dim3(128), 0, stream, last, com, fus, x, BP, FEAT);

    // ===== 3. convert x, CSR build =====
    hipLaunchKernelGGL(conv_pad, dim3(cdiv((long)NN*KP,256)), dim3(256), 0, stream, x, xH, xL, NN, FEAT, KP);
    hipLaunchKernelGGL(deg_init,  dim3(cdiv(NN,256)), dim3(256), 0, stream, deg, NN);
    hipLaunchKernelGGL(deg_count, dim3(cdiv(NE,256)), dim3(256), 0, stream, dst, deg, NE);
    {
        int nb = cdiv(NN, 256);   // 196
        hipLaunchKernelGGL(scan_part,  dim3(nb), dim3(256), 0, stream, deg, bsum, NN);
        hipLaunchKernelGGL(scan_bsum,  dim3(1),  dim3(256), 0, stream, bsum, nb);
        hipLaunchKernelGGL(scan_final, dim3(nb), dim3(256), 0, stream, deg, bsum, rowp, NN);
    }
    hipLaunchKernelGGL(copy_i32, dim3(cdiv(NN,256)), dim3(256), 0, stream, rowp, curs, NN);
    hipLaunchKernelGGL(csr_fill, dim3(cdiv(NE,256)), dim3(256), 0, stream, src, dst, curs, csrc, NE);
    hipLaunchKernelGGL(csr_fill_loops, dim3(cdiv(NN,256)), dim3(256), 0, stream, curs, csrc, NN);

    // ===== 4. GAT layer 1 =====
    hipLaunchKernelGGL((gemm_direct<6, false>), dim3(cdiv(NN,64), 1), dim3(256), 0, stream,
                       xH, (long)(xL - xH), KP, W1TH, (long)(W1TL - W1TH), KP,
                       h1, NN, HC1, FEAT, 0);
    hipLaunchKernelGGL(node_attn_coef, dim3(cdiv(NN*HEADS,256)), dim3(256), 0, stream,
                       h1, as1, ad1, es1, ed1, NN, HEADS, HID);
    hipLaunchKernelGGL((csr_maxden_alpha<HEADS>), dim3(cdiv(NN*HEADS,256)), dim3(256), 0, stream,
                       rowp, csrc, es1, ed1, alpha1, NN);
    hipLaunchKernelGGL(csr_agg1_fused, dim3(NN), dim3(128), 0, stream,
                       rowp, csrc, (const float4*)alpha1, h1, b1, W2, h2, NN);

    // ===== 5. GAT layer 2 =====
    hipLaunchKernelGGL(node_attn_coef, dim3(cdiv(NN,256)), dim3(256), 0, stream,
                       h2, as2, ad2, es2, ed2, NN, 1, OUTC);
    hipLaunchKernelGGL((csr_maxden_alpha<1>), dim3(cdiv(NN,256)), dim3(256), 0, stream,
                       rowp, csrc, es2, ed2, alpha2, NN);
    hipLaunchKernelGGL(csr_agg2, dim3(cdiv(NN*OUTC,256)), dim3(256), 0, stream,
                       rowp, csrc, alpha2, h2, b2, embp, NN);

    // ===== 6. pair scores =====
    hipLaunchKernelGGL(pair_score, dim3(cdiv(NP,256)), dim3(256), 0, stream, pidx, embp, out, NP);
}